// Round 1
// 241.956 us; speedup vs baseline: 1.0777x; 1.0777x over previous
//
#include <hip/hip_runtime.h>
#include <hip/hip_bf16.h>

typedef short bf16x8 __attribute__((ext_vector_type(8)));
typedef float f32x4 __attribute__((ext_vector_type(4)));

constexpr int CN = 256, NV = 4096, KTOP = 512;

static __device__ __forceinline__ unsigned short f2bf(float f) {
  __hip_bfloat16 h = __float2bfloat16(f);
  return *(unsigned short*)&h;
}
static __device__ __forceinline__ unsigned pack2(float a, float b) {
  return (unsigned)f2bf(a) | ((unsigned)f2bf(b) << 16);
}
static __device__ __forceinline__ float bf2f(unsigned short u) {
  return __uint_as_float(((unsigned)u) << 16);
}
// truncated-bf16 pack: lo16 = bf16(a), hi16 = bf16(b)  (2 VALU, no cvt)
static __device__ __forceinline__ unsigned packtrunc(float a, float b) {
  return (__float_as_uint(a) >> 16) | (__float_as_uint(b) & 0xFFFF0000u);
}

// ---------------------------------------------------------------- K0: transpose-cast f32 (c,n) -> bf16 (n,c)
// z = 0,1: x_kv batches; z = 2,3: x_q batches (merged launch)
__global__ void __launch_bounds__(256) k_tcast2(const float* __restrict__ srcA,
                                                const float* __restrict__ srcB,
                                                unsigned short* __restrict__ dstA,
                                                unsigned short* __restrict__ dstB) {
  __shared__ float tile[64 * 65];
  int z = blockIdx.z, b = z & 1;
  const float* s = (z < 2 ? srcA : srcB) + (size_t)b * CN * NV;
  unsigned short* d = (z < 2 ? dstA : dstB) + (size_t)b * NV * 256;
  int c0 = blockIdx.y * 64, n0 = blockIdx.x * 64;
  int t = threadIdx.x;
  for (int i = 0; i < 16; ++i) {
    int id = i * 256 + t, c = id >> 6, n = id & 63;
    tile[c * 65 + n] = s[(size_t)(c0 + c) * NV + n0 + n];
  }
  __syncthreads();
  int n = t & 63, part = t >> 6;
  unsigned w[8];
#pragma unroll
  for (int k = 0; k < 8; ++k)
    w[k] = pack2(tile[(part * 16 + 2 * k) * 65 + n], tile[(part * 16 + 2 * k + 1) * 65 + n]);
  uint4* p = (uint4*)&d[(size_t)(n0 + n) * 256 + c0 + part * 16];
  p[0] = make_uint4(w[0], w[1], w[2], w[3]);
  p[1] = make_uint4(w[4], w[5], w[6], w[7]);
}

// ---------------------------------------------------------------- K0b: weight prep -> bf16 (j, c) layouts
__global__ void __launch_bounds__(256) k_wprep(const float* __restrict__ wkv,
                                               const float* __restrict__ wq,
                                               const float* __restrict__ wproj,
                                               const float* __restrict__ wpw,
                                               unsigned short* __restrict__ wv_t,
                                               unsigned short* __restrict__ wq_t,
                                               unsigned short* __restrict__ wcat) {
  __shared__ float tile[64 * 65];
  int role = blockIdx.z;
  int j0 = blockIdx.x * 64, c0 = blockIdx.y * 64;
  int t = threadIdx.x;
  if (role == 3) {  // wpw (j,c) straight cast into wcat cols 256..512
    int j = t >> 2, part = t & 3;
    const float* s = &wpw[(size_t)(j0 + j) * 256 + c0 + part * 16];
    unsigned w[8];
#pragma unroll
    for (int k = 0; k < 8; ++k) w[k] = pack2(s[2 * k], s[2 * k + 1]);
    uint4* p = (uint4*)&wcat[(size_t)(j0 + j) * 512 + 256 + c0 + part * 16];
    p[0] = make_uint4(w[0], w[1], w[2], w[3]);
    p[1] = make_uint4(w[4], w[5], w[6], w[7]);
    return;
  }
  const float* src; int srcLD, srcOff; unsigned short* dst; int dstLD;
  if (role == 0)      { src = wkv;   srcLD = 512; srcOff = 256; dst = wv_t; dstLD = 256; }
  else if (role == 1) { src = wq;    srcLD = 256; srcOff = 0;   dst = wq_t; dstLD = 256; }
  else                { src = wproj; srcLD = 256; srcOff = 0;   dst = wcat; dstLD = 512; }
  for (int i = 0; i < 16; ++i) {
    int id = i * 256 + t, c = id >> 6, j = id & 63;
    tile[c * 65 + j] = src[(size_t)(c0 + c) * srcLD + srcOff + j0 + j];
  }
  __syncthreads();
  int j = t & 63, part = t >> 6;
  unsigned w[8];
#pragma unroll
  for (int k = 0; k < 8; ++k)
    w[k] = pack2(tile[(part * 16 + 2 * k) * 65 + j], tile[(part * 16 + 2 * k + 1) * 65 + j]);
  uint4* p = (uint4*)&dst[(size_t)(j0 + j) * dstLD + c0 + part * 16];
  p[0] = make_uint4(w[0], w[1], w[2], w[3]);
  p[1] = make_uint4(w[4], w[5], w[6], w[7]);
}

// ---------------------------------------------------------------- K1: channel mean/max
__global__ void __launch_bounds__(256) k_reduce(const float* __restrict__ xkv,
                                                float* __restrict__ avgmx) {
  __shared__ float ssum[256], smax[256];
  int blk = blockIdx.x;
  int b = blk >> 7, n0 = (blk & 127) * 32;
  int t = threadIdx.x, cg = t >> 5, nl = t & 31;
  int n = n0 + nl;
  const float* p = xkv + (size_t)b * CN * NV + (size_t)cg * 32 * NV + n;
  float s = 0.f, m = -1e30f;
  for (int i = 0; i < 32; ++i) {
    float v = p[(size_t)i * NV];
    s += v; m = fmaxf(m, v);
  }
  ssum[t] = s; smax[t] = m;
  __syncthreads();
  if (cg == 0) {
    for (int g = 1; g < 8; ++g) { s += ssum[g * 32 + nl]; m = fmaxf(m, smax[g * 32 + nl]); }
    avgmx[(b * 2 + 0) * NV + n] = s * (1.0f / 256.0f);
    avgmx[(b * 2 + 1) * NV + n] = m;
  }
}

// ---------------------------------------------------------------- K2: 7x7x7 conv + sigmoid
__global__ void __launch_bounds__(256) k_spa(const float* __restrict__ avgmx,
                                             const float* __restrict__ wspa,
                                             float* __restrict__ scores) {
  __shared__ float vol[2 * 4096];
  __shared__ float ws[686];
  int b = blockIdx.x >> 5, chunk = blockIdx.x & 31;
  int tid = threadIdx.x;
  for (int t = tid; t < 8192; t += 256) vol[t] = avgmx[b * 8192 + t];
  for (int t = tid; t < 686; t += 256) ws[t] = wspa[t];
  __syncthreads();
  int ci = tid & 1;
  int n = chunk * 128 + (tid >> 1);
  int d = n >> 8, h = (n >> 4) & 15, w = n & 15;
  const float* vb = vol + ci * 4096;
  const float* wb = ws + ci * 343;
  float acc = 0.f;
  for (int kd = 0; kd < 7; ++kd) {
    int zd = d - 3 + kd; if ((unsigned)zd >= 16u) continue;
    for (int kh = 0; kh < 7; ++kh) {
      int zh = h - 3 + kh; if ((unsigned)zh >= 16u) continue;
      const float* row = vb + zd * 256 + zh * 16;
      const float* wr = wb + kd * 49 + kh * 7;
#pragma unroll
      for (int kw = 0; kw < 7; ++kw) {
        int zw = w - 3 + kw;
        if ((unsigned)zw < 16u) acc += row[zw] * wr[kw];
      }
    }
  }
  acc += __shfl_xor(acc, 1);
  if (ci == 0) scores[b * NV + n] = 1.0f / (1.0f + expf(-acc));
}

// ---------------------------------------------------------------- K3: top-512 radix-select (wave-scan, fewer barriers)
__global__ void __launch_bounds__(1024) k_topk(const float* __restrict__ scores,
                                               int* __restrict__ idx) {
  __shared__ unsigned sv[4096];
  __shared__ int sB;
  __shared__ unsigned sSub, scnt;
  __shared__ unsigned hist[256];
  __shared__ int wsum[16];
  int b = blockIdx.x, tid = threadIdx.x;
  for (int t = tid; t < 4096; t += 1024) sv[t] = __float_as_uint(scores[b * NV + t]);
  if (tid == 0) scnt = 0;
  unsigned prefix = 0;
  int r = 512;
  for (int shift = 24; shift >= 0; shift -= 8) {
    if (tid < 256) hist[tid] = 0;
    __syncthreads();
    unsigned maskhi = (shift == 24) ? 0u : (0xFFFFFFFFu << (shift + 8));
    for (int i = 0; i < 4; ++i) {
      unsigned v = sv[tid + i * 1024];
      if ((v & maskhi) == prefix) atomicAdd(&hist[(v >> shift) & 255], 1u);
    }
    __syncthreads();
    if (tid < 64) {  // single wave: 4 bins/lane, shfl suffix scan, no barriers
      int lane = tid;
      unsigned h0 = hist[lane * 4 + 0], h1 = hist[lane * 4 + 1];
      unsigned h2 = hist[lane * 4 + 2], h3 = hist[lane * 4 + 3];
      unsigned s = h0 + h1 + h2 + h3;
      for (int off = 1; off < 64; off <<= 1) {
        unsigned y = __shfl_down(s, off);
        if (lane + off < 64) s += y;
      }
      unsigned tail = __shfl_down(s, 1);
      if (lane == 63) tail = 0;
      unsigned s3 = tail + h3, s2 = s3 + h2, s1 = s2 + h1, s0 = s1 + h0;
      unsigned sx[5] = {s0, s1, s2, s3, tail};
#pragma unroll
      for (int i = 0; i < 4; ++i)
        if (sx[i] >= (unsigned)r && sx[i + 1] < (unsigned)r) { sB = lane * 4 + i; sSub = sx[i + 1]; }
    }
    __syncthreads();
    prefix |= ((unsigned)sB) << shift;
    r -= (int)sSub;
    __syncthreads();
  }
  unsigned vstar = prefix;
  for (int i = 0; i < 4; ++i) {
    int t = tid * 4 + i;
    if (sv[t] > vstar) { unsigned p = atomicAdd(&scnt, 1u); idx[b * KTOP + p] = t; }
  }
  __syncthreads();
  int base = (int)scnt;
  int loc = 0;
  for (int i = 0; i < 4; ++i) loc += (sv[tid * 4 + i] == vstar);
  int lane = tid & 63, w = tid >> 6;
  int x = loc;
  for (int off = 1; off < 64; off <<= 1) {
    int y = __shfl_up(x, off);
    if (lane >= off) x += y;
  }
  if (lane == 63) wsum[w] = x;
  __syncthreads();
  int wbase = 0;
  for (int i = 0; i < w; ++i) wbase += wsum[i];
  int excl = wbase + x - loc;
  for (int i = 0; i < 4; ++i) {
    int t = tid * 4 + i;
    if (sv[t] == vstar) {
      if (excl < r) idx[b * KTOP + base + excl] = t;
      ++excl;
    }
  }
}

// ---------------------------------------------------------------- K4: fused V+Q projection, MFMA bf16 -> bf16 outs
__global__ void __launch_bounds__(256) k_qv(const unsigned short* __restrict__ xkv_t,
                                            const unsigned short* __restrict__ xq_t,
                                            const unsigned short* __restrict__ wv_t,
                                            const unsigned short* __restrict__ wq_t,
                                            const float* __restrict__ bkv,
                                            const float* __restrict__ bq,
                                            unsigned short* __restrict__ v_nc,
                                            unsigned short* __restrict__ qh) {
  __shared__ unsigned short Als[128 * 40];
  __shared__ unsigned short Bls[128 * 40];
  int role = blockIdx.z;
  int b = role & 1;
  bool isQ = role >= 2;
  const unsigned short* A = isQ ? wq_t : wv_t;                              // (j=256, c=256)
  const unsigned short* B = (isQ ? xq_t : xkv_t) + (size_t)b * NV * 256;    // (n, c)
  const float* bias = isQ ? bq : (bkv + 256);
  int n0 = blockIdx.x * 128, j0 = blockIdx.y * 128;
  int t = threadIdx.x;
  int wave = t >> 6, lane = t & 63;
  int l15 = lane & 15, q = lane >> 4, q8 = q * 8;
  int wj = (wave >> 1) * 64, wn = (wave & 1) * 64;
  f32x4 acc[4][4] = {};
  int ar = t >> 1, ah = t & 1;
  for (int c0 = 0; c0 < 256; c0 += 32) {
    __syncthreads();
    {
      const unsigned short* sa = &A[(size_t)(j0 + ar) * 256 + c0 + ah * 16];
      *(uint4*)&Als[ar * 40 + ah * 16]     = *(const uint4*)&sa[0];
      *(uint4*)&Als[ar * 40 + ah * 16 + 8] = *(const uint4*)&sa[8];
      const unsigned short* sb = &B[(size_t)(n0 + ar) * 256 + c0 + ah * 16];
      *(uint4*)&Bls[ar * 40 + ah * 16]     = *(const uint4*)&sb[0];
      *(uint4*)&Bls[ar * 40 + ah * 16 + 8] = *(const uint4*)&sb[8];
    }
    __syncthreads();
    bf16x8 af[4], bf[4];
#pragma unroll
    for (int mt = 0; mt < 4; ++mt)
      af[mt] = *(const bf16x8*)&Als[(wj + mt * 16 + l15) * 40 + q8];
#pragma unroll
    for (int nt = 0; nt < 4; ++nt)
      bf[nt] = *(const bf16x8*)&Bls[(wn + nt * 16 + l15) * 40 + q8];
#pragma unroll
    for (int mt = 0; mt < 4; ++mt)
#pragma unroll
      for (int nt = 0; nt < 4; ++nt)
        acc[mt][nt] = __builtin_amdgcn_mfma_f32_16x16x32_bf16(af[mt], bf[nt], acc[mt][nt], 0, 0, 0);
  }
#pragma unroll
  for (int mt = 0; mt < 4; ++mt) {
    int jb = j0 + wj + mt * 16 + q * 4;          // 4 consecutive j
    float4 b4 = *(const float4*)&bias[jb];
#pragma unroll
    for (int nt = 0; nt < 4; ++nt) {
      int n = n0 + wn + nt * 16 + l15;
      float v0 = acc[mt][nt][0] + b4.x;
      float v1 = acc[mt][nt][1] + b4.y;
      float v2 = acc[mt][nt][2] + b4.z;
      float v3 = acc[mt][nt][3] + b4.w;
      uint2 pk = make_uint2(pack2(v0, v1), pack2(v2, v3));
      if (isQ) {
        int h = jb >> 3, d0 = jb & 7;            // jb%4==0 -> within one head
        *(uint2*)&qh[((size_t)(b * 32 + h) * NV + n) * 8 + d0] = pk;
      } else {
        *(uint2*)&v_nc[((size_t)b * NV + n) * 256 + jb] = pk;
      }
    }
  }
}

// ---------------------------------------------------------------- K5: gathered K projection (f32 compute, bf16 scaled out)
__global__ void k_projg(const float* __restrict__ X, const float* __restrict__ W, int ldw,
                        const float* __restrict__ bias, const int* __restrict__ map,
                        unsigned short* __restrict__ kg) {
  __shared__ float Xs[32 * 33];
  __shared__ float Ws[32 * 64];
  __shared__ int nmap[32];
  const float kscale = 0.35355339059327373f * 1.4426950408889634f;  // 1/sqrt(8)*log2(e)
  int m0 = blockIdx.x * 32, j0 = blockIdx.y * 64, b = blockIdx.z;
  int tid = threadIdx.x;
  if (tid < 32) nmap[tid] = map[b * KTOP + m0 + tid];
  int mm = tid >> 3, tj = (tid & 7) * 8;
  float acc[8] = {};
  const float* Xb = X + (size_t)b * CN * NV;
  for (int c0 = 0; c0 < 256; c0 += 32) {
    __syncthreads();
    for (int t = tid; t < 1024; t += 256) {
      int cc = t >> 5, mmm = t & 31;
      Xs[cc * 33 + mmm] = Xb[(size_t)(c0 + cc) * NV + nmap[mmm]];
    }
    for (int t = tid; t < 2048; t += 256) {
      int cc = t >> 6, jj = t & 63;
      Ws[cc * 64 + jj] = W[(size_t)(c0 + cc) * ldw + j0 + jj];
    }
    __syncthreads();
    for (int cc = 0; cc < 32; ++cc) {
      float xv = Xs[cc * 33 + mm];
      float4 w0 = *(const float4*)&Ws[cc * 64 + tj];
      float4 w1 = *(const float4*)&Ws[cc * 64 + tj + 4];
      acc[0] += xv * w0.x; acc[1] += xv * w0.y; acc[2] += xv * w0.z; acc[3] += xv * w0.w;
      acc[4] += xv * w1.x; acc[5] += xv * w1.y; acc[6] += xv * w1.z; acc[7] += xv * w1.w;
    }
  }
  int m = m0 + mm, j = j0 + tj;
  float s[8];
#pragma unroll
  for (int jj = 0; jj < 8; ++jj) s[jj] = (acc[jj] + bias[j + jj]) * kscale;
  unsigned short* outp = kg + ((size_t)(b * 32 + (j >> 3)) * KTOP + m) * 8;
  *(uint4*)outp = make_uint4(pack2(s[0], s[1]), pack2(s[2], s[3]),
                             pack2(s[4], s[5]), pack2(s[6], s[7]));
}

// ---------------------------------------------------------------- K5b: build V^T (+ones row) per bh
// Keys within each 32-group are stored PERMUTED to match the PV A-fragment
// k-slot order produced by the swapped-QK layout in k_fattn:
//   slot s (=quad*8+j) holds key kappa = (j<4) ? quad*4+j : 16+quad*4+(j-4)
// Inverse (key ka -> slot s):
//   ka<16 : s = (ka>>2)*8 + (ka&3)
//   ka>=16: s = ((ka-16)>>2)*8 + (ka&3) + 4
__global__ void __launch_bounds__(256) k_vt(const unsigned short* __restrict__ v_nc,
                                            const int* __restrict__ idx,
                                            unsigned short* __restrict__ vt) {
  int bh = blockIdx.x;
  int b = bh >> 5, h = bh & 31;
  int t = threadIdx.x;
  unsigned short* dst = vt + (size_t)bh * 16 * 512;
  for (int i = t; i < 512; i += 256) dst[8 * 512 + i] = 0x3F80;       // 1.0 bf16 (perm-invariant)
  for (int i = t; i < 512 * 7; i += 256) dst[9 * 512 + i] = 0;
  const int* ib = idx + b * KTOP;
  for (int kk = t; kk < 512; kk += 256) {
    uint4 v = *(const uint4*)&v_nc[((size_t)b * NV + ib[kk]) * 256 + h * 8];
    unsigned short tmp[8];
    *(uint4*)tmp = v;
    int kc = kk >> 5, ka = kk & 31;
    int s = (ka < 16) ? ((ka >> 2) * 8 + (ka & 3))
                      : (((ka - 16) >> 2) * 8 + (ka & 3) + 4);
    int col = kc * 32 + s;
#pragma unroll
    for (int d = 0; d < 8; ++d) dst[d * 512 + col] = tmp[d];
  }
}

// ---------------------------------------------------------------- K6: MFMA flash attention, swapped-QK, LDS-free
// round-13: compute mfma(K,Q) so P lands lane-local in the exact PV A-frag
// layout (lane l15 = query row, k-slots = keys via kappa; V^T pre-permuted in
// k_vt). Removes the P LDS round-trip (8 ds_write_u16 + ds_read_b128 / 32 keys)
// and the serial QK->LDS->PV chain. 32 queries/wave (2 tiles) amortizes K loads.
__global__ void __launch_bounds__(256) k_fattn(const unsigned short* __restrict__ qh,
                                               const unsigned short* __restrict__ kg,
                                               const unsigned short* __restrict__ vt,
                                               unsigned short* __restrict__ aoydw) {
  int bh = blockIdx.x;
  int b = bh >> 5, h = bh & 31;
  int t = threadIdx.x, wave = t >> 6, lane = t & 63;
  int l15 = lane & 15, quad = lane >> 4;
  int n0 = blockIdx.y * 128 + wave * 32;       // 32 queries per wave
  bf16x8 q0 = {}, q1 = {};                     // B-operand: n=query, k=dim (quad 0 only)
  if (quad == 0) {
    q0 = *(const bf16x8*)&qh[((size_t)bh * NV + n0 + l15) * 8];
    q1 = *(const bf16x8*)&qh[((size_t)bh * NV + n0 + 16 + l15) * 8];
  }
  const unsigned short* kbase = kg + (size_t)bh * KTOP * 8;
  const unsigned short* vbase = vt + (size_t)bh * 16 * 512;
  f32x4 acc0 = {0.f, 0.f, 0.f, 0.f}, acc1 = {0.f, 0.f, 0.f, 0.f};
  bf16x8 kA0 = {}, kA1 = {};                   // A-operand: m=key, k=dim (quad 0 only)
  if (quad == 0) {
    kA0 = *(const bf16x8*)&kbase[(size_t)l15 * 8];
    kA1 = *(const bf16x8*)&kbase[(size_t)(16 + l15) * 8];
  }
  for (int kc = 0; kc < 16; ++kc) {            // 32 keys per iteration
    bf16x8 nA0 = {}, nA1 = {};                 // prefetch next K chunk
    if (quad == 0 && kc < 15) {
      nA0 = *(const bf16x8*)&kbase[(size_t)(kc * 32 + 32 + l15) * 8];
      nA1 = *(const bf16x8*)&kbase[(size_t)(kc * 32 + 48 + l15) * 8];
    }
    bf16x8 bV = *(const bf16x8*)&vbase[(size_t)l15 * 512 + kc * 32 + quad * 8];
    f32x4 z = {0.f, 0.f, 0.f, 0.f};
    // D: col=query=l15, row=key=quad*4+r  -> P already in PV A-frag layout
    f32x4 s00 = __builtin_amdgcn_mfma_f32_16x16x32_bf16(kA0, q0, z, 0, 0, 0);
    f32x4 s01 = __builtin_amdgcn_mfma_f32_16x16x32_bf16(kA1, q0, z, 0, 0, 0);
    f32x4 s10 = __builtin_amdgcn_mfma_f32_16x16x32_bf16(kA0, q1, z, 0, 0, 0);
    f32x4 s11 = __builtin_amdgcn_mfma_f32_16x16x32_bf16(kA1, q1, z, 0, 0, 0);
    uint4 P0, P1;
    P0.x = packtrunc(__builtin_amdgcn_exp2f(s00[0]), __builtin_amdgcn_exp2f(s00[1]));
    P0.y = packtrunc(__builtin_amdgcn_exp2f(s00[2]), __builtin_amdgcn_exp2f(s00[3]));
    P0.z = packtrunc(__builtin_amdgcn_exp2f(s01[0]), __builtin_amdgcn_exp2f(s01[1]));
    P0.w = packtrunc(__builtin_amdgcn_exp2f(s01[2]), __builtin_amdgcn_exp2f(s01[3]));
    P1.x = packtrunc(__builtin_amdgcn_exp2f(s10[0]), __builtin_amdgcn_exp2f(s10[1]));
    P1.y = packtrunc(__builtin_amdgcn_exp2f(s10[2]), __builtin_amdgcn_exp2f(s10[3]));
    P1.z = packtrunc(__builtin_amdgcn_exp2f(s11[0]), __builtin_amdgcn_exp2f(s11[1]));
    P1.w = packtrunc(__builtin_amdgcn_exp2f(s11[2]), __builtin_amdgcn_exp2f(s11[3]));
    acc0 = __builtin_amdgcn_mfma_f32_16x16x32_bf16(*(bf16x8*)&P0, bV, acc0, 0, 0, 0);
    acc1 = __builtin_amdgcn_mfma_f32_16x16x32_bf16(*(bf16x8*)&P1, bV, acc1, 0, 0, 0);
    kA0 = nA0; kA1 = nA1;
  }
#pragma unroll
  for (int tq = 0; tq < 2; ++tq) {
    f32x4 a = tq ? acc1 : acc0;
#pragma unroll
    for (int r = 0; r < 4; ++r) {
      float se = __shfl(a[r], quad * 16 + 8);  // denominator from ones-row col (l15=8)
      float o = a[r] * (1.0f / se);
      if (l15 < 8) {
        int n = n0 + tq * 16 + quad * 4 + r;
        aoydw[((size_t)b * NV + n) * 512 + h * 8 + l15] = f2bf(o);
      }
    }
  }
}

// ---------------------------------------------------------------- K7: depthwise conv, v_nc (n,c) bf16 -> aoydw cols 256+
__global__ void __launch_bounds__(256) k_dw(const unsigned short* __restrict__ v_nc,
                                            const float* __restrict__ wdw,
                                            const float* __restrict__ bdw,
                                            unsigned short* __restrict__ aoydw) {
  int c = threadIdx.x;
  int b = blockIdx.y;
  float wr[27];
#pragma unroll
  for (int i = 0; i < 27; ++i) wr[i] = wdw[c * 27 + i];
  float bias = bdw[c];
  const unsigned short* src = v_nc + (size_t)b * NV * 256 + c;
  unsigned short* dst = aoydw + (size_t)b * NV * 512 + 256 + c;
  int n = blockIdx.x * 4;                    // 4 consecutive n (same h-row) share taps
  int d = n >> 8, h = (n >> 4) & 15, w = n & 15;
  float a0 = bias, a1 = bias, a2 = bias, a3 = bias;
#pragma unroll
  for (int kd = 0; kd < 3; ++kd) {
    int zd = d - 1 + kd; bool okd = (unsigned)zd < 16u;
#pragma unroll
    for (int kh = 0; kh < 3; ++kh) {
      int zh = h - 1 + kh; bool okh = okd && ((unsigned)zh < 16u);
      int rowb = zd * 256 + zh * 16;
      float v[6];
#pragma unroll
      for (int i = 0; i < 6; ++i) {
        int zw = w - 1 + i;
        bool ok = okh && ((unsigned)zw < 16u);   // wave-uniform mask
        v[i] = ok ? bf2f(src[(size_t)(rowb + zw) * 256]) : 0.f;
      }
      const float* wp = &wr[kd * 9 + kh * 3];
      a0 = fmaf(v[0], wp[0], fmaf(v[1], wp[1], fmaf(v[2], wp[2], a0)));
      a1 = fmaf(v[1], wp[0], fmaf(v[2], wp[1], fmaf(v[3], wp[2], a1)));
      a2 = fmaf(v[2], wp[0], fmaf(v[3], wp[1], fmaf(v[4], wp[2], a2)));
      a3 = fmaf(v[3], wp[0], fmaf(v[4], wp[1], fmaf(v[5], wp[2], a3)));
    }
  }
  dst[(size_t)(n + 0) * 512] = f2bf(a0);
  dst[(size_t)(n + 1) * 512] = f2bf(a1);
  dst[(size_t)(n + 2) * 512] = f2bf(a2);
  dst[(size_t)(n + 3) * 512] = f2bf(a3);
}

// ---------------------------------------------------------------- K8: final GEMM K=512, MFMA bf16
__global__ void __launch_bounds__(256) k_final(const unsigned short* __restrict__ aoydw,
                                               const unsigned short* __restrict__ wcat,
                                               const float* __restrict__ bproj,
                                               const float* __restrict__ bpw,
                                               float* __restrict__ out) {
  __shared__ unsigned short Als[64 * 40];
  __shared__ unsigned short Bls[128 * 40];
  int n0 = blockIdx.x * 64, j0 = blockIdx.y * 128, b = blockIdx.z;
  int t = threadIdx.x;
  int wave = t >> 6, lane = t & 63;
  int l15 = lane & 15, q = lane >> 4, q8 = q * 8;
  int wn = (wave >> 1) * 32, wjj = (wave & 1) * 64;
  f32x4 acc[2][4] = {};
  const unsigned short* Abase = aoydw + (size_t)b * NV * 512;
  int ar = t >> 2, aq = t & 3;
  int br = t >> 1, bhh = t & 1;
  for (int c0 = 0; c0 < 512; c0 += 32) {
    __syncthreads();
    *(uint4*)&Als[ar * 40 + aq * 8] =
        *(const uint4*)&Abase[(size_t)(n0 + ar) * 512 + c0 + aq * 8];
    const unsigned short* sb = &wcat[(size_t)(j0 + br) * 512 + c0 + bhh * 16];
    *(uint4*)&Bls[br * 40 + bhh * 16]     = *(const uint4*)&sb[0];
    *(uint4*)&Bls[br * 40 + bhh * 16 + 8] = *(const uint4*)&sb[8];
    __syncthreads();
    bf16x8 af[2], bf[4];
#pragma unroll
    for (int mt = 0; mt < 2; ++mt)
      af[mt] = *(const bf16x8*)&Als[(wn + mt * 16 + l15) * 40 + q8];
#pragma unroll
    for (int nt = 0; nt < 4; ++nt)
      bf[nt] = *(const bf16x8*)&Bls[(wjj + nt * 16 + l15) * 40 + q8];
#pragma unroll
    for (int mt = 0; mt < 2; ++mt)
#pragma unroll
      for (int nt = 0; nt < 4; ++nt)
        acc[mt][nt] = __builtin_amdgcn_mfma_f32_16x16x32_bf16(af[mt], bf[nt], acc[mt][nt], 0, 0, 0);
  }
#pragma unroll
  for (int nt = 0; nt < 4; ++nt) {
    int j = j0 + wjj + nt * 16 + l15;
    float bl = bproj[j] + bpw[j];
#pragma unroll
    for (int mt = 0; mt < 2; ++mt) {
      int n = n0 + wn + mt * 16 + q * 4;
      float4 r = make_float4(acc[mt][nt][0] + bl, acc[mt][nt][1] + bl,
                             acc[mt][nt][2] + bl, acc[mt][nt][3] + bl);
      *(float4*)&out[(size_t)(b * 256 + j) * NV + n] = r;
    }
  }
}

// ---------------------------------------------------------------- launch
extern "C" void kernel_launch(void* const* d_in, const int* in_sizes, int n_in,
                              void* d_out, int out_size, void* d_ws, size_t ws_size,
                              hipStream_t stream) {
  const float* x_kv   = (const float*)d_in[0];
  const float* x_q    = (const float*)d_in[1];
  const float* w_spa  = (const float*)d_in[2];
  const float* w_kv   = (const float*)d_in[3];
  const float* b_kv   = (const float*)d_in[4];
  const float* w_q    = (const float*)d_in[5];
  const float* b_q    = (const float*)d_in[6];
  const float* w_proj = (const float*)d_in[7];
  const float* b_proj = (const float*)d_in[8];
  const float* w_dw   = (const float*)d_in[9];
  const float* b_dw   = (const float*)d_in[10];
  const float* w_pw   = (const float*)d_in[11];
  const float* b_pw   = (const float*)d_in[12];
  float* out = (float*)d_out;

  const size_t MB = 1024 * 1024;
  char* ws = (char*)d_ws;
  unsigned short* xkv_t = (unsigned short*)(ws);                 // 4 MB (b,n,c) bf16
  unsigned short* xq_t  = (unsigned short*)(ws + 4 * MB);        // 4 MB
  unsigned short* v_nc  = (unsigned short*)(ws + 8 * MB);        // 4 MB (b,n,c) bf16
  unsigned short* qh    = (unsigned short*)(ws + 12 * MB);       // 4 MB (b,h,n,8) bf16
  unsigned short* aoydw = (unsigned short*)(ws + 16 * MB);       // 8 MB (b,n,512) bf16
  unsigned short* kg    = (unsigned short*)(ws + 24 * MB);       // 512 KB (bh,512,8) bf16 pre-scaled
  unsigned short* vt    = (unsigned short*)(ws + 24 * MB + 512 * 1024);  // 1 MB (bh,16,512) bf16
  unsigned short* wv_t  = (unsigned short*)(ws + 26 * MB);               // 128 KB
  unsigned short* wq_t  = (unsigned short*)(ws + 26 * MB + 131072);      // 128 KB
  unsigned short* wcat  = (unsigned short*)(ws + 26 * MB + 262144);      // 256 KB
  float*          avgmx = (float*)(ws + 27 * MB);                        //  64 KB
  float*          scores= (float*)(ws + 27 * MB + 65536);               //  32 KB
  int*            idx   = (int*)  (ws + 27 * MB + 98304);               //   4 KB

  k_tcast2<<<dim3(64, 4, 4), 256, 0, stream>>>(x_kv, x_q, xkv_t, xq_t);
  k_wprep<<<dim3(4, 4, 4), 256, 0, stream>>>(w_kv, w_q, w_proj, w_pw, wv_t, wq_t, wcat);
  k_reduce<<<256, 256, 0, stream>>>(x_kv, avgmx);
  k_spa<<<64, 256, 0, stream>>>(avgmx, w_spa, scores);
  k_topk<<<2, 1024, 0, stream>>>(scores, idx);
  k_qv<<<dim3(32, 2, 4), 256, 0, stream>>>(xkv_t, xq_t, wv_t, wq_t, b_kv, b_q, v_nc, qh);
  k_projg<<<dim3(16, 4, 2), 256, 0, stream>>>(x_kv, w_kv, 512, b_kv, idx, kg);
  k_vt<<<64, 256, 0, stream>>>(v_nc, idx, vt);
  k_fattn<<<dim3(64, 32), 256, 0, stream>>>(qh, kg, vt, aoydw);
  k_dw<<<dim3(1024, 2), 256, 0, stream>>>(v_nc, w_dw, b_dw, aoydw);
  k_final<<<dim3(64, 2, 2), 256, 0, stream>>>(aoydw, wcat, b_proj, b_pw, out);
}

// Round 2
// 215.287 us; speedup vs baseline: 1.2112x; 1.1239x over previous
//
#include <hip/hip_runtime.h>
#include <hip/hip_bf16.h>

typedef short bf16x8 __attribute__((ext_vector_type(8)));
typedef float f32x4 __attribute__((ext_vector_type(4)));

constexpr int CN = 256, NV = 4096, KTOP = 512;

static __device__ __forceinline__ unsigned short f2bf(float f) {
  __hip_bfloat16 h = __float2bfloat16(f);
  return *(unsigned short*)&h;
}
static __device__ __forceinline__ unsigned pack2(float a, float b) {
  return (unsigned)f2bf(a) | ((unsigned)f2bf(b) << 16);
}
static __device__ __forceinline__ float bf2f(unsigned short u) {
  return __uint_as_float(((unsigned)u) << 16);
}
// truncated-bf16 pack: lo16 = bf16(a), hi16 = bf16(b)  (2 VALU, no cvt)
static __device__ __forceinline__ unsigned packtrunc(float a, float b) {
  return (__float_as_uint(a) >> 16) | (__float_as_uint(b) & 0xFFFF0000u);
}

// ---------------------------------------------------------------- K0: transpose-cast f32 (c,n) -> bf16 (n,c)
// z = 0,1: x_kv batches; z = 2,3: x_q batches (merged launch)
__global__ void __launch_bounds__(256) k_tcast2(const float* __restrict__ srcA,
                                                const float* __restrict__ srcB,
                                                unsigned short* __restrict__ dstA,
                                                unsigned short* __restrict__ dstB) {
  __shared__ float tile[64 * 65];
  int z = blockIdx.z, b = z & 1;
  const float* s = (z < 2 ? srcA : srcB) + (size_t)b * CN * NV;
  unsigned short* d = (z < 2 ? dstA : dstB) + (size_t)b * NV * 256;
  int c0 = blockIdx.y * 64, n0 = blockIdx.x * 64;
  int t = threadIdx.x;
  for (int i = 0; i < 16; ++i) {
    int id = i * 256 + t, c = id >> 6, n = id & 63;
    tile[c * 65 + n] = s[(size_t)(c0 + c) * NV + n0 + n];
  }
  __syncthreads();
  int n = t & 63, part = t >> 6;
  unsigned w[8];
#pragma unroll
  for (int k = 0; k < 8; ++k)
    w[k] = pack2(tile[(part * 16 + 2 * k) * 65 + n], tile[(part * 16 + 2 * k + 1) * 65 + n]);
  uint4* p = (uint4*)&d[(size_t)(n0 + n) * 256 + c0 + part * 16];
  p[0] = make_uint4(w[0], w[1], w[2], w[3]);
  p[1] = make_uint4(w[4], w[5], w[6], w[7]);
}

// ---------------------------------------------------------------- K0b: weight prep -> bf16 (j, c) layouts
// role 0: wkv cols 256..512 -> wv_t ; role 1: wq -> wq_t ; role 2: wproj -> wcat[:,0:256]
// role 3: wpw (j,c) -> wcat[:,256:512] ; role 4: wkv cols 0..256 -> wk_t (K half)
__global__ void __launch_bounds__(256) k_wprep(const float* __restrict__ wkv,
                                               const float* __restrict__ wq,
                                               const float* __restrict__ wproj,
                                               const float* __restrict__ wpw,
                                               unsigned short* __restrict__ wv_t,
                                               unsigned short* __restrict__ wq_t,
                                               unsigned short* __restrict__ wcat,
                                               unsigned short* __restrict__ wk_t) {
  __shared__ float tile[64 * 65];
  int role = blockIdx.z;
  int j0 = blockIdx.x * 64, c0 = blockIdx.y * 64;
  int t = threadIdx.x;
  if (role == 3) {  // wpw (j,c) straight cast into wcat cols 256..512
    int j = t >> 2, part = t & 3;
    const float* s = &wpw[(size_t)(j0 + j) * 256 + c0 + part * 16];
    unsigned w[8];
#pragma unroll
    for (int k = 0; k < 8; ++k) w[k] = pack2(s[2 * k], s[2 * k + 1]);
    uint4* p = (uint4*)&wcat[(size_t)(j0 + j) * 512 + 256 + c0 + part * 16];
    p[0] = make_uint4(w[0], w[1], w[2], w[3]);
    p[1] = make_uint4(w[4], w[5], w[6], w[7]);
    return;
  }
  const float* src; int srcLD, srcOff; unsigned short* dst; int dstLD;
  if (role == 0)      { src = wkv;   srcLD = 512; srcOff = 256; dst = wv_t; dstLD = 256; }
  else if (role == 1) { src = wq;    srcLD = 256; srcOff = 0;   dst = wq_t; dstLD = 256; }
  else if (role == 4) { src = wkv;   srcLD = 512; srcOff = 0;   dst = wk_t; dstLD = 256; }
  else                { src = wproj; srcLD = 256; srcOff = 0;   dst = wcat; dstLD = 512; }
  for (int i = 0; i < 16; ++i) {
    int id = i * 256 + t, c = id >> 6, j = id & 63;
    tile[c * 65 + j] = src[(size_t)(c0 + c) * srcLD + srcOff + j0 + j];
  }
  __syncthreads();
  int j = t & 63, part = t >> 6;
  unsigned w[8];
#pragma unroll
  for (int k = 0; k < 8; ++k)
    w[k] = pack2(tile[(part * 16 + 2 * k) * 65 + j], tile[(part * 16 + 2 * k + 1) * 65 + j]);
  uint4* p = (uint4*)&dst[(size_t)(j0 + j) * dstLD + c0 + part * 16];
  p[0] = make_uint4(w[0], w[1], w[2], w[3]);
  p[1] = make_uint4(w[4], w[5], w[6], w[7]);
}

// ---------------------------------------------------------------- K1: channel mean/max
__global__ void __launch_bounds__(256) k_reduce(const float* __restrict__ xkv,
                                                float* __restrict__ avgmx) {
  __shared__ float ssum[256], smax[256];
  int blk = blockIdx.x;
  int b = blk >> 7, n0 = (blk & 127) * 32;
  int t = threadIdx.x, cg = t >> 5, nl = t & 31;
  int n = n0 + nl;
  const float* p = xkv + (size_t)b * CN * NV + (size_t)cg * 32 * NV + n;
  float s = 0.f, m = -1e30f;
  for (int i = 0; i < 32; ++i) {
    float v = p[(size_t)i * NV];
    s += v; m = fmaxf(m, v);
  }
  ssum[t] = s; smax[t] = m;
  __syncthreads();
  if (cg == 0) {
    for (int g = 1; g < 8; ++g) { s += ssum[g * 32 + nl]; m = fmaxf(m, smax[g * 32 + nl]); }
    avgmx[(b * 2 + 0) * NV + n] = s * (1.0f / 256.0f);
    avgmx[(b * 2 + 1) * NV + n] = m;
  }
}

// ---------------------------------------------------------------- K2: 7x7x7 conv + sigmoid
__global__ void __launch_bounds__(256) k_spa(const float* __restrict__ avgmx,
                                             const float* __restrict__ wspa,
                                             float* __restrict__ scores) {
  __shared__ float vol[2 * 4096];
  __shared__ float ws[686];
  int b = blockIdx.x >> 5, chunk = blockIdx.x & 31;
  int tid = threadIdx.x;
  for (int t = tid; t < 8192; t += 256) vol[t] = avgmx[b * 8192 + t];
  for (int t = tid; t < 686; t += 256) ws[t] = wspa[t];
  __syncthreads();
  int ci = tid & 1;
  int n = chunk * 128 + (tid >> 1);
  int d = n >> 8, h = (n >> 4) & 15, w = n & 15;
  const float* vb = vol + ci * 4096;
  const float* wb = ws + ci * 343;
  float acc = 0.f;
  for (int kd = 0; kd < 7; ++kd) {
    int zd = d - 3 + kd; if ((unsigned)zd >= 16u) continue;
    for (int kh = 0; kh < 7; ++kh) {
      int zh = h - 3 + kh; if ((unsigned)zh >= 16u) continue;
      const float* row = vb + zd * 256 + zh * 16;
      const float* wr = wb + kd * 49 + kh * 7;
#pragma unroll
      for (int kw = 0; kw < 7; ++kw) {
        int zw = w - 3 + kw;
        if ((unsigned)zw < 16u) acc += row[zw] * wr[kw];
      }
    }
  }
  acc += __shfl_xor(acc, 1);
  if (ci == 0) scores[b * NV + n] = 1.0f / (1.0f + expf(-acc));
}

// ---------------------------------------------------------------- K3: top-512 radix-select (wave-scan, fewer barriers)
__global__ void __launch_bounds__(1024) k_topk(const float* __restrict__ scores,
                                               int* __restrict__ idx) {
  __shared__ unsigned sv[4096];
  __shared__ int sB;
  __shared__ unsigned sSub, scnt;
  __shared__ unsigned hist[256];
  __shared__ int wsum[16];
  int b = blockIdx.x, tid = threadIdx.x;
  for (int t = tid; t < 4096; t += 1024) sv[t] = __float_as_uint(scores[b * NV + t]);
  if (tid == 0) scnt = 0;
  unsigned prefix = 0;
  int r = 512;
  for (int shift = 24; shift >= 0; shift -= 8) {
    if (tid < 256) hist[tid] = 0;
    __syncthreads();
    unsigned maskhi = (shift == 24) ? 0u : (0xFFFFFFFFu << (shift + 8));
    for (int i = 0; i < 4; ++i) {
      unsigned v = sv[tid + i * 1024];
      if ((v & maskhi) == prefix) atomicAdd(&hist[(v >> shift) & 255], 1u);
    }
    __syncthreads();
    if (tid < 64) {  // single wave: 4 bins/lane, shfl suffix scan, no barriers
      int lane = tid;
      unsigned h0 = hist[lane * 4 + 0], h1 = hist[lane * 4 + 1];
      unsigned h2 = hist[lane * 4 + 2], h3 = hist[lane * 4 + 3];
      unsigned s = h0 + h1 + h2 + h3;
      for (int off = 1; off < 64; off <<= 1) {
        unsigned y = __shfl_down(s, off);
        if (lane + off < 64) s += y;
      }
      unsigned tail = __shfl_down(s, 1);
      if (lane == 63) tail = 0;
      unsigned s3 = tail + h3, s2 = s3 + h2, s1 = s2 + h1, s0 = s1 + h0;
      unsigned sx[5] = {s0, s1, s2, s3, tail};
#pragma unroll
      for (int i = 0; i < 4; ++i)
        if (sx[i] >= (unsigned)r && sx[i + 1] < (unsigned)r) { sB = lane * 4 + i; sSub = sx[i + 1]; }
    }
    __syncthreads();
    prefix |= ((unsigned)sB) << shift;
    r -= (int)sSub;
    __syncthreads();
  }
  unsigned vstar = prefix;
  for (int i = 0; i < 4; ++i) {
    int t = tid * 4 + i;
    if (sv[t] > vstar) { unsigned p = atomicAdd(&scnt, 1u); idx[b * KTOP + p] = t; }
  }
  __syncthreads();
  int base = (int)scnt;
  int loc = 0;
  for (int i = 0; i < 4; ++i) loc += (sv[tid * 4 + i] == vstar);
  int lane = tid & 63, w = tid >> 6;
  int x = loc;
  for (int off = 1; off < 64; off <<= 1) {
    int y = __shfl_up(x, off);
    if (lane >= off) x += y;
  }
  if (lane == 63) wsum[w] = x;
  __syncthreads();
  int wbase = 0;
  for (int i = 0; i < w; ++i) wbase += wsum[i];
  int excl = wbase + x - loc;
  for (int i = 0; i < 4; ++i) {
    int t = tid * 4 + i;
    if (sv[t] == vstar) {
      if (excl < r) idx[b * KTOP + base + excl] = t;
      ++excl;
    }
  }
}

// ---------------------------------------------------------------- K4: fused V+Q projection, MFMA bf16 -> bf16 outs
__global__ void __launch_bounds__(256) k_qv(const unsigned short* __restrict__ xkv_t,
                                            const unsigned short* __restrict__ xq_t,
                                            const unsigned short* __restrict__ wv_t,
                                            const unsigned short* __restrict__ wq_t,
                                            const float* __restrict__ bkv,
                                            const float* __restrict__ bq,
                                            unsigned short* __restrict__ v_nc,
                                            unsigned short* __restrict__ qh) {
  __shared__ unsigned short Als[128 * 40];
  __shared__ unsigned short Bls[128 * 40];
  int role = blockIdx.z;
  int b = role & 1;
  bool isQ = role >= 2;
  const unsigned short* A = isQ ? wq_t : wv_t;                              // (j=256, c=256)
  const unsigned short* B = (isQ ? xq_t : xkv_t) + (size_t)b * NV * 256;    // (n, c)
  const float* bias = isQ ? bq : (bkv + 256);
  int n0 = blockIdx.x * 128, j0 = blockIdx.y * 128;
  int t = threadIdx.x;
  int wave = t >> 6, lane = t & 63;
  int l15 = lane & 15, q = lane >> 4, q8 = q * 8;
  int wj = (wave >> 1) * 64, wn = (wave & 1) * 64;
  f32x4 acc[4][4] = {};
  int ar = t >> 1, ah = t & 1;
  for (int c0 = 0; c0 < 256; c0 += 32) {
    __syncthreads();
    {
      const unsigned short* sa = &A[(size_t)(j0 + ar) * 256 + c0 + ah * 16];
      *(uint4*)&Als[ar * 40 + ah * 16]     = *(const uint4*)&sa[0];
      *(uint4*)&Als[ar * 40 + ah * 16 + 8] = *(const uint4*)&sa[8];
      const unsigned short* sb = &B[(size_t)(n0 + ar) * 256 + c0 + ah * 16];
      *(uint4*)&Bls[ar * 40 + ah * 16]     = *(const uint4*)&sb[0];
      *(uint4*)&Bls[ar * 40 + ah * 16 + 8] = *(const uint4*)&sb[8];
    }
    __syncthreads();
    bf16x8 af[4], bf[4];
#pragma unroll
    for (int mt = 0; mt < 4; ++mt)
      af[mt] = *(const bf16x8*)&Als[(wj + mt * 16 + l15) * 40 + q8];
#pragma unroll
    for (int nt = 0; nt < 4; ++nt)
      bf[nt] = *(const bf16x8*)&Bls[(wn + nt * 16 + l15) * 40 + q8];
#pragma unroll
    for (int mt = 0; mt < 4; ++mt)
#pragma unroll
      for (int nt = 0; nt < 4; ++nt)
        acc[mt][nt] = __builtin_amdgcn_mfma_f32_16x16x32_bf16(af[mt], bf[nt], acc[mt][nt], 0, 0, 0);
  }
#pragma unroll
  for (int mt = 0; mt < 4; ++mt) {
    int jb = j0 + wj + mt * 16 + q * 4;          // 4 consecutive j
    float4 b4 = *(const float4*)&bias[jb];
#pragma unroll
    for (int nt = 0; nt < 4; ++nt) {
      int n = n0 + wn + nt * 16 + l15;
      float v0 = acc[mt][nt][0] + b4.x;
      float v1 = acc[mt][nt][1] + b4.y;
      float v2 = acc[mt][nt][2] + b4.z;
      float v3 = acc[mt][nt][3] + b4.w;
      uint2 pk = make_uint2(pack2(v0, v1), pack2(v2, v3));
      if (isQ) {
        int h = jb >> 3, d0 = jb & 7;            // jb%4==0 -> within one head
        *(uint2*)&qh[((size_t)(b * 32 + h) * NV + n) * 8 + d0] = pk;
      } else {
        *(uint2*)&v_nc[((size_t)b * NV + n) * 256 + jb] = pk;
      }
    }
  }
}

// ---------------------------------------------------------------- K5: gathered K projection, MFMA bf16
// round-14: replaces scalar-FMA k_projg (46 us, MfmaUtil 0, Occ 5%). Gathered
// key rows are contiguous 512B rows of xkv_t (n,c) -> coalesced uint4 staging;
// weights from wk_t (j,c) bf16. f32 bias + kscale in epilogue, bf16 out in the
// same (bh, key, 8) kg layout as before.
__global__ void __launch_bounds__(256) k_kg(const unsigned short* __restrict__ xkv_t,
                                            const unsigned short* __restrict__ wk_t,
                                            const float* __restrict__ bkv,
                                            const int* __restrict__ map,
                                            unsigned short* __restrict__ kg) {
  __shared__ unsigned short Als[128 * 40];
  __shared__ unsigned short Bls[128 * 40];
  const float kscale = 0.35355339059327373f * 1.4426950408889634f;  // 1/sqrt(8)*log2(e)
  int b = blockIdx.z;
  int m0 = blockIdx.x * 128, j0 = blockIdx.y * 128;
  int t = threadIdx.x;
  int wave = t >> 6, lane = t & 63;
  int l15 = lane & 15, q = lane >> 4, q8 = q * 8;
  int wj = (wave >> 1) * 64, wn = (wave & 1) * 64;
  int ar = t >> 1, ah = t & 1;
  int nrow = map[b * KTOP + m0 + ar];            // this thread's gathered key row
  const unsigned short* Bbase = xkv_t + (size_t)b * NV * 256;
  f32x4 acc[4][4] = {};
  for (int c0 = 0; c0 < 256; c0 += 32) {
    __syncthreads();
    {
      const unsigned short* sa = &wk_t[(size_t)(j0 + ar) * 256 + c0 + ah * 16];
      *(uint4*)&Als[ar * 40 + ah * 16]     = *(const uint4*)&sa[0];
      *(uint4*)&Als[ar * 40 + ah * 16 + 8] = *(const uint4*)&sa[8];
      const unsigned short* sb = &Bbase[(size_t)nrow * 256 + c0 + ah * 16];
      *(uint4*)&Bls[ar * 40 + ah * 16]     = *(const uint4*)&sb[0];
      *(uint4*)&Bls[ar * 40 + ah * 16 + 8] = *(const uint4*)&sb[8];
    }
    __syncthreads();
    bf16x8 af[4], bfr[4];
#pragma unroll
    for (int mt = 0; mt < 4; ++mt)
      af[mt] = *(const bf16x8*)&Als[(wj + mt * 16 + l15) * 40 + q8];
#pragma unroll
    for (int nt = 0; nt < 4; ++nt)
      bfr[nt] = *(const bf16x8*)&Bls[(wn + nt * 16 + l15) * 40 + q8];
#pragma unroll
    for (int mt = 0; mt < 4; ++mt)
#pragma unroll
      for (int nt = 0; nt < 4; ++nt)
        acc[mt][nt] = __builtin_amdgcn_mfma_f32_16x16x32_bf16(af[mt], bfr[nt], acc[mt][nt], 0, 0, 0);
  }
#pragma unroll
  for (int mt = 0; mt < 4; ++mt) {
    int jb = j0 + wj + mt * 16 + q * 4;          // 4 consecutive j within one head
    int h = jb >> 3, d0 = jb & 7;
    float4 b4 = *(const float4*)&bkv[jb];
#pragma unroll
    for (int nt = 0; nt < 4; ++nt) {
      int m = m0 + wn + nt * 16 + l15;
      float v0 = (acc[mt][nt][0] + b4.x) * kscale;
      float v1 = (acc[mt][nt][1] + b4.y) * kscale;
      float v2 = (acc[mt][nt][2] + b4.z) * kscale;
      float v3 = (acc[mt][nt][3] + b4.w) * kscale;
      uint2 pk = make_uint2(pack2(v0, v1), pack2(v2, v3));
      *(uint2*)&kg[((size_t)(b * 32 + h) * KTOP + m) * 8 + d0] = pk;
    }
  }
}

// ---------------------------------------------------------------- K5b: build V^T (+ones row) per bh
// Keys within each 32-group are stored PERMUTED to match the PV A-fragment
// k-slot order produced by the swapped-QK layout in k_fattn:
//   slot s (=quad*8+j) holds key kappa = (j<4) ? quad*4+j : 16+quad*4+(j-4)
// Inverse (key ka -> slot s):
//   ka<16 : s = (ka>>2)*8 + (ka&3)
//   ka>=16: s = ((ka-16)>>2)*8 + (ka&3) + 4
__global__ void __launch_bounds__(256) k_vt(const unsigned short* __restrict__ v_nc,
                                            const int* __restrict__ idx,
                                            unsigned short* __restrict__ vt) {
  int bh = blockIdx.x;
  int b = bh >> 5, h = bh & 31;
  int t = threadIdx.x;
  unsigned short* dst = vt + (size_t)bh * 16 * 512;
  for (int i = t; i < 512; i += 256) dst[8 * 512 + i] = 0x3F80;       // 1.0 bf16 (perm-invariant)
  for (int i = t; i < 512 * 7; i += 256) dst[9 * 512 + i] = 0;
  const int* ib = idx + b * KTOP;
  for (int kk = t; kk < 512; kk += 256) {
    uint4 v = *(const uint4*)&v_nc[((size_t)b * NV + ib[kk]) * 256 + h * 8];
    unsigned short tmp[8];
    *(uint4*)tmp = v;
    int kc = kk >> 5, ka = kk & 31;
    int s = (ka < 16) ? ((ka >> 2) * 8 + (ka & 3))
                      : (((ka - 16) >> 2) * 8 + (ka & 3) + 4);
    int col = kc * 32 + s;
#pragma unroll
    for (int d = 0; d < 8; ++d) dst[d * 512 + col] = tmp[d];
  }
}

// ---------------------------------------------------------------- K6: MFMA flash attention, swapped-QK, LDS-free
// round-13: compute mfma(K,Q) so P lands lane-local in the exact PV A-frag
// layout (lane l15 = query row, k-slots = keys via kappa; V^T pre-permuted in
// k_vt). Removes the P LDS round-trip (8 ds_write_u16 + ds_read_b128 / 32 keys)
// and the serial QK->LDS->PV chain. 32 queries/wave (2 tiles) amortizes K loads.
__global__ void __launch_bounds__(256) k_fattn(const unsigned short* __restrict__ qh,
                                               const unsigned short* __restrict__ kg,
                                               const unsigned short* __restrict__ vt,
                                               unsigned short* __restrict__ aoydw) {
  int bh = blockIdx.x;
  int b = bh >> 5, h = bh & 31;
  int t = threadIdx.x, wave = t >> 6, lane = t & 63;
  int l15 = lane & 15, quad = lane >> 4;
  int n0 = blockIdx.y * 128 + wave * 32;       // 32 queries per wave
  bf16x8 q0 = {}, q1 = {};                     // B-operand: n=query, k=dim (quad 0 only)
  if (quad == 0) {
    q0 = *(const bf16x8*)&qh[((size_t)bh * NV + n0 + l15) * 8];
    q1 = *(const bf16x8*)&qh[((size_t)bh * NV + n0 + 16 + l15) * 8];
  }
  const unsigned short* kbase = kg + (size_t)bh * KTOP * 8;
  const unsigned short* vbase = vt + (size_t)bh * 16 * 512;
  f32x4 acc0 = {0.f, 0.f, 0.f, 0.f}, acc1 = {0.f, 0.f, 0.f, 0.f};
  bf16x8 kA0 = {}, kA1 = {};                   // A-operand: m=key, k=dim (quad 0 only)
  if (quad == 0) {
    kA0 = *(const bf16x8*)&kbase[(size_t)l15 * 8];
    kA1 = *(const bf16x8*)&kbase[(size_t)(16 + l15) * 8];
  }
  for (int kc = 0; kc < 16; ++kc) {            // 32 keys per iteration
    bf16x8 nA0 = {}, nA1 = {};                 // prefetch next K chunk
    if (quad == 0 && kc < 15) {
      nA0 = *(const bf16x8*)&kbase[(size_t)(kc * 32 + 32 + l15) * 8];
      nA1 = *(const bf16x8*)&kbase[(size_t)(kc * 32 + 48 + l15) * 8];
    }
    bf16x8 bV = *(const bf16x8*)&vbase[(size_t)l15 * 512 + kc * 32 + quad * 8];
    f32x4 z = {0.f, 0.f, 0.f, 0.f};
    // D: col=query=l15, row=key=quad*4+r  -> P already in PV A-frag layout
    f32x4 s00 = __builtin_amdgcn_mfma_f32_16x16x32_bf16(kA0, q0, z, 0, 0, 0);
    f32x4 s01 = __builtin_amdgcn_mfma_f32_16x16x32_bf16(kA1, q0, z, 0, 0, 0);
    f32x4 s10 = __builtin_amdgcn_mfma_f32_16x16x32_bf16(kA0, q1, z, 0, 0, 0);
    f32x4 s11 = __builtin_amdgcn_mfma_f32_16x16x32_bf16(kA1, q1, z, 0, 0, 0);
    uint4 P0, P1;
    P0.x = packtrunc(__builtin_amdgcn_exp2f(s00[0]), __builtin_amdgcn_exp2f(s00[1]));
    P0.y = packtrunc(__builtin_amdgcn_exp2f(s00[2]), __builtin_amdgcn_exp2f(s00[3]));
    P0.z = packtrunc(__builtin_amdgcn_exp2f(s01[0]), __builtin_amdgcn_exp2f(s01[1]));
    P0.w = packtrunc(__builtin_amdgcn_exp2f(s01[2]), __builtin_amdgcn_exp2f(s01[3]));
    P1.x = packtrunc(__builtin_amdgcn_exp2f(s10[0]), __builtin_amdgcn_exp2f(s10[1]));
    P1.y = packtrunc(__builtin_amdgcn_exp2f(s10[2]), __builtin_amdgcn_exp2f(s10[3]));
    P1.z = packtrunc(__builtin_amdgcn_exp2f(s11[0]), __builtin_amdgcn_exp2f(s11[1]));
    P1.w = packtrunc(__builtin_amdgcn_exp2f(s11[2]), __builtin_amdgcn_exp2f(s11[3]));
    acc0 = __builtin_amdgcn_mfma_f32_16x16x32_bf16(*(bf16x8*)&P0, bV, acc0, 0, 0, 0);
    acc1 = __builtin_amdgcn_mfma_f32_16x16x32_bf16(*(bf16x8*)&P1, bV, acc1, 0, 0, 0);
    kA0 = nA0; kA1 = nA1;
  }
#pragma unroll
  for (int tq = 0; tq < 2; ++tq) {
    f32x4 a = tq ? acc1 : acc0;
#pragma unroll
    for (int r = 0; r < 4; ++r) {
      float se = __shfl(a[r], quad * 16 + 8);  // denominator from ones-row col (l15=8)
      float o = a[r] * (1.0f / se);
      if (l15 < 8) {
        int n = n0 + tq * 16 + quad * 4 + r;
        aoydw[((size_t)b * NV + n) * 512 + h * 8 + l15] = f2bf(o);
      }
    }
  }
}

// ---------------------------------------------------------------- K7: depthwise conv, v_nc (n,c) bf16 -> aoydw cols 256+
__global__ void __launch_bounds__(256) k_dw(const unsigned short* __restrict__ v_nc,
                                            const float* __restrict__ wdw,
                                            const float* __restrict__ bdw,
                                            unsigned short* __restrict__ aoydw) {
  int c = threadIdx.x;
  int b = blockIdx.y;
  float wr[27];
#pragma unroll
  for (int i = 0; i < 27; ++i) wr[i] = wdw[c * 27 + i];
  float bias = bdw[c];
  const unsigned short* src = v_nc + (size_t)b * NV * 256 + c;
  unsigned short* dst = aoydw + (size_t)b * NV * 512 + 256 + c;
  int n = blockIdx.x * 4;                    // 4 consecutive n (same h-row) share taps
  int d = n >> 8, h = (n >> 4) & 15, w = n & 15;
  float a0 = bias, a1 = bias, a2 = bias, a3 = bias;
#pragma unroll
  for (int kd = 0; kd < 3; ++kd) {
    int zd = d - 1 + kd; bool okd = (unsigned)zd < 16u;
#pragma unroll
    for (int kh = 0; kh < 3; ++kh) {
      int zh = h - 1 + kh; bool okh = okd && ((unsigned)zh < 16u);
      int rowb = zd * 256 + zh * 16;
      float v[6];
#pragma unroll
      for (int i = 0; i < 6; ++i) {
        int zw = w - 1 + i;
        bool ok = okh && ((unsigned)zw < 16u);   // wave-uniform mask
        v[i] = ok ? bf2f(src[(size_t)(rowb + zw) * 256]) : 0.f;
      }
      const float* wp = &wr[kd * 9 + kh * 3];
      a0 = fmaf(v[0], wp[0], fmaf(v[1], wp[1], fmaf(v[2], wp[2], a0)));
      a1 = fmaf(v[1], wp[0], fmaf(v[2], wp[1], fmaf(v[3], wp[2], a1)));
      a2 = fmaf(v[2], wp[0], fmaf(v[3], wp[1], fmaf(v[4], wp[2], a2)));
      a3 = fmaf(v[3], wp[0], fmaf(v[4], wp[1], fmaf(v[5], wp[2], a3)));
    }
  }
  dst[(size_t)(n + 0) * 512] = f2bf(a0);
  dst[(size_t)(n + 1) * 512] = f2bf(a1);
  dst[(size_t)(n + 2) * 512] = f2bf(a2);
  dst[(size_t)(n + 3) * 512] = f2bf(a3);
}

// ---------------------------------------------------------------- K8: final GEMM K=512, MFMA bf16
__global__ void __launch_bounds__(256) k_final(const unsigned short* __restrict__ aoydw,
                                               const unsigned short* __restrict__ wcat,
                                               const float* __restrict__ bproj,
                                               const float* __restrict__ bpw,
                                               float* __restrict__ out) {
  __shared__ unsigned short Als[64 * 40];
  __shared__ unsigned short Bls[128 * 40];
  int n0 = blockIdx.x * 64, j0 = blockIdx.y * 128, b = blockIdx.z;
  int t = threadIdx.x;
  int wave = t >> 6, lane = t & 63;
  int l15 = lane & 15, q = lane >> 4, q8 = q * 8;
  int wn = (wave >> 1) * 32, wjj = (wave & 1) * 64;
  f32x4 acc[2][4] = {};
  const unsigned short* Abase = aoydw + (size_t)b * NV * 512;
  int ar = t >> 2, aq = t & 3;
  int br = t >> 1, bhh = t & 1;
  for (int c0 = 0; c0 < 512; c0 += 32) {
    __syncthreads();
    *(uint4*)&Als[ar * 40 + aq * 8] =
        *(const uint4*)&Abase[(size_t)(n0 + ar) * 512 + c0 + aq * 8];
    const unsigned short* sb = &wcat[(size_t)(j0 + br) * 512 + c0 + bhh * 16];
    *(uint4*)&Bls[br * 40 + bhh * 16]     = *(const uint4*)&sb[0];
    *(uint4*)&Bls[br * 40 + bhh * 16 + 8] = *(const uint4*)&sb[8];
    __syncthreads();
    bf16x8 af[2], bf[4];
#pragma unroll
    for (int mt = 0; mt < 2; ++mt)
      af[mt] = *(const bf16x8*)&Als[(wn + mt * 16 + l15) * 40 + q8];
#pragma unroll
    for (int nt = 0; nt < 4; ++nt)
      bf[nt] = *(const bf16x8*)&Bls[(wjj + nt * 16 + l15) * 40 + q8];
#pragma unroll
    for (int mt = 0; mt < 2; ++mt)
#pragma unroll
      for (int nt = 0; nt < 4; ++nt)
        acc[mt][nt] = __builtin_amdgcn_mfma_f32_16x16x32_bf16(af[mt], bf[nt], acc[mt][nt], 0, 0, 0);
  }
#pragma unroll
  for (int nt = 0; nt < 4; ++nt) {
    int j = j0 + wjj + nt * 16 + l15;
    float bl = bproj[j] + bpw[j];
#pragma unroll
    for (int mt = 0; mt < 2; ++mt) {
      int n = n0 + wn + mt * 16 + q * 4;
      float4 r = make_float4(acc[mt][nt][0] + bl, acc[mt][nt][1] + bl,
                             acc[mt][nt][2] + bl, acc[mt][nt][3] + bl);
      *(float4*)&out[(size_t)(b * 256 + j) * NV + n] = r;
    }
  }
}

// ---------------------------------------------------------------- launch
extern "C" void kernel_launch(void* const* d_in, const int* in_sizes, int n_in,
                              void* d_out, int out_size, void* d_ws, size_t ws_size,
                              hipStream_t stream) {
  const float* x_kv   = (const float*)d_in[0];
  const float* x_q    = (const float*)d_in[1];
  const float* w_spa  = (const float*)d_in[2];
  const float* w_kv   = (const float*)d_in[3];
  const float* b_kv   = (const float*)d_in[4];
  const float* w_q    = (const float*)d_in[5];
  const float* b_q    = (const float*)d_in[6];
  const float* w_proj = (const float*)d_in[7];
  const float* b_proj = (const float*)d_in[8];
  const float* w_dw   = (const float*)d_in[9];
  const float* b_dw   = (const float*)d_in[10];
  const float* w_pw   = (const float*)d_in[11];
  const float* b_pw   = (const float*)d_in[12];
  float* out = (float*)d_out;

  const size_t MB = 1024 * 1024;
  char* ws = (char*)d_ws;
  unsigned short* xkv_t = (unsigned short*)(ws);                 // 4 MB (b,n,c) bf16
  unsigned short* xq_t  = (unsigned short*)(ws + 4 * MB);        // 4 MB
  unsigned short* v_nc  = (unsigned short*)(ws + 8 * MB);        // 4 MB (b,n,c) bf16
  unsigned short* qh    = (unsigned short*)(ws + 12 * MB);       // 4 MB (b,h,n,8) bf16
  unsigned short* aoydw = (unsigned short*)(ws + 16 * MB);       // 8 MB (b,n,512) bf16
  unsigned short* kg    = (unsigned short*)(ws + 24 * MB);       // 512 KB (bh,512,8) bf16 pre-scaled
  unsigned short* vt    = (unsigned short*)(ws + 24 * MB + 512 * 1024);  // 1 MB (bh,16,512) bf16
  unsigned short* wv_t  = (unsigned short*)(ws + 26 * MB);               // 128 KB
  unsigned short* wq_t  = (unsigned short*)(ws + 26 * MB + 131072);      // 128 KB
  unsigned short* wcat  = (unsigned short*)(ws + 26 * MB + 262144);      // 256 KB
  unsigned short* wk_t  = (unsigned short*)(ws + 26 * MB + 524288);      // 128 KB
  float*          avgmx = (float*)(ws + 27 * MB);                        //  64 KB
  float*          scores= (float*)(ws + 27 * MB + 65536);               //  32 KB
  int*            idx   = (int*)  (ws + 27 * MB + 98304);               //   4 KB

  k_tcast2<<<dim3(64, 4, 4), 256, 0, stream>>>(x_kv, x_q, xkv_t, xq_t);
  k_wprep<<<dim3(4, 4, 5), 256, 0, stream>>>(w_kv, w_q, w_proj, w_pw, wv_t, wq_t, wcat, wk_t);
  k_reduce<<<256, 256, 0, stream>>>(x_kv, avgmx);
  k_spa<<<64, 256, 0, stream>>>(avgmx, w_spa, scores);
  k_topk<<<2, 1024, 0, stream>>>(scores, idx);
  k_qv<<<dim3(32, 2, 4), 256, 0, stream>>>(xkv_t, xq_t, wv_t, wq_t, b_kv, b_q, v_nc, qh);
  k_kg<<<dim3(4, 2, 2), 256, 0, stream>>>(xkv_t, wk_t, b_kv, idx, kg);
  k_vt<<<64, 256, 0, stream>>>(v_nc, idx, vt);
  k_fattn<<<dim3(64, 32), 256, 0, stream>>>(qh, kg, vt, aoydw);
  k_dw<<<dim3(1024, 2), 256, 0, stream>>>(v_nc, w_dw, b_dw, aoydw);
  k_final<<<dim3(64, 2, 2), 256, 0, stream>>>(aoydw, wcat, b_proj, b_pw, out);
}

// Round 3
// 205.236 us; speedup vs baseline: 1.2705x; 1.0490x over previous
//
#include <hip/hip_runtime.h>
#include <hip/hip_bf16.h>

typedef short bf16x8 __attribute__((ext_vector_type(8)));
typedef float f32x4 __attribute__((ext_vector_type(4)));

constexpr int CN = 256, NV = 4096, KTOP = 512;

static __device__ __forceinline__ unsigned short f2bf(float f) {
  __hip_bfloat16 h = __float2bfloat16(f);
  return *(unsigned short*)&h;
}
static __device__ __forceinline__ unsigned pack2(float a, float b) {
  return (unsigned)f2bf(a) | ((unsigned)f2bf(b) << 16);
}
static __device__ __forceinline__ float bf2f(unsigned short u) {
  return __uint_as_float(((unsigned)u) << 16);
}
// truncated-bf16 pack: lo16 = bf16(a), hi16 = bf16(b)  (2 VALU, no cvt)
static __device__ __forceinline__ unsigned packtrunc(float a, float b) {
  return (__float_as_uint(a) >> 16) | (__float_as_uint(b) & 0xFFFF0000u);
}

// ---------------------------------------------------------------- K0: transpose-cast f32 (c,n) -> bf16 (n,c)
// z = 0,1: x_kv batches; z = 2,3: x_q batches; z = 4: fused channel mean/max (was k_reduce)
__global__ void __launch_bounds__(256) k_tcast2(const float* __restrict__ srcA,
                                                const float* __restrict__ srcB,
                                                unsigned short* __restrict__ dstA,
                                                unsigned short* __restrict__ dstB,
                                                float* __restrict__ avgmx) {
  __shared__ float tile[64 * 65];
  int z = blockIdx.z;
  int t = threadIdx.x;
  if (z == 4) {  // channel mean/max role, f32 precision preserved for top-k stability
    __shared__ float ssum[256], smax[256];
    int blk = blockIdx.y * 64 + blockIdx.x;
    int b = blk >> 7, n0 = (blk & 127) * 32;
    int cg = t >> 5, nl = t & 31;
    int n = n0 + nl;
    const float* p = srcA + (size_t)b * CN * NV + (size_t)cg * 32 * NV + n;
    float s = 0.f, m = -1e30f;
    for (int i = 0; i < 32; ++i) {
      float v = p[(size_t)i * NV];
      s += v; m = fmaxf(m, v);
    }
    ssum[t] = s; smax[t] = m;
    __syncthreads();
    if (cg == 0) {
      for (int g = 1; g < 8; ++g) { s += ssum[g * 32 + nl]; m = fmaxf(m, smax[g * 32 + nl]); }
      avgmx[(b * 2 + 0) * NV + n] = s * (1.0f / 256.0f);
      avgmx[(b * 2 + 1) * NV + n] = m;
    }
    return;
  }
  int b = z & 1;
  const float* s = (z < 2 ? srcA : srcB) + (size_t)b * CN * NV;
  unsigned short* d = (z < 2 ? dstA : dstB) + (size_t)b * NV * 256;
  int c0 = blockIdx.y * 64, n0 = blockIdx.x * 64;
  for (int i = 0; i < 16; ++i) {
    int id = i * 256 + t, c = id >> 6, n = id & 63;
    tile[c * 65 + n] = s[(size_t)(c0 + c) * NV + n0 + n];
  }
  __syncthreads();
  int n = t & 63, part = t >> 6;
  unsigned w[8];
#pragma unroll
  for (int k = 0; k < 8; ++k)
    w[k] = pack2(tile[(part * 16 + 2 * k) * 65 + n], tile[(part * 16 + 2 * k + 1) * 65 + n]);
  uint4* p = (uint4*)&d[(size_t)(n0 + n) * 256 + c0 + part * 16];
  p[0] = make_uint4(w[0], w[1], w[2], w[3]);
  p[1] = make_uint4(w[4], w[5], w[6], w[7]);
}

// ---------------------------------------------------------------- K0b: weight prep -> bf16 (j, c) layouts
// role 0: wkv cols 256..512 -> wv_t ; role 1: wq -> wq_t ; role 2: wproj -> wcat[:,0:256]
// role 3: wpw (j,c) -> wcat[:,256:512] ; role 4: wkv cols 0..256 -> wk_t (K half)
__global__ void __launch_bounds__(256) k_wprep(const float* __restrict__ wkv,
                                               const float* __restrict__ wq,
                                               const float* __restrict__ wproj,
                                               const float* __restrict__ wpw,
                                               unsigned short* __restrict__ wv_t,
                                               unsigned short* __restrict__ wq_t,
                                               unsigned short* __restrict__ wcat,
                                               unsigned short* __restrict__ wk_t) {
  __shared__ float tile[64 * 65];
  int role = blockIdx.z;
  int j0 = blockIdx.x * 64, c0 = blockIdx.y * 64;
  int t = threadIdx.x;
  if (role == 3) {  // wpw (j,c) straight cast into wcat cols 256..512
    int j = t >> 2, part = t & 3;
    const float* s = &wpw[(size_t)(j0 + j) * 256 + c0 + part * 16];
    unsigned w[8];
#pragma unroll
    for (int k = 0; k < 8; ++k) w[k] = pack2(s[2 * k], s[2 * k + 1]);
    uint4* p = (uint4*)&wcat[(size_t)(j0 + j) * 512 + 256 + c0 + part * 16];
    p[0] = make_uint4(w[0], w[1], w[2], w[3]);
    p[1] = make_uint4(w[4], w[5], w[6], w[7]);
    return;
  }
  const float* src; int srcLD, srcOff; unsigned short* dst; int dstLD;
  if (role == 0)      { src = wkv;   srcLD = 512; srcOff = 256; dst = wv_t; dstLD = 256; }
  else if (role == 1) { src = wq;    srcLD = 256; srcOff = 0;   dst = wq_t; dstLD = 256; }
  else if (role == 4) { src = wkv;   srcLD = 512; srcOff = 0;   dst = wk_t; dstLD = 256; }
  else                { src = wproj; srcLD = 256; srcOff = 0;   dst = wcat; dstLD = 512; }
  for (int i = 0; i < 16; ++i) {
    int id = i * 256 + t, c = id >> 6, j = id & 63;
    tile[c * 65 + j] = src[(size_t)(c0 + c) * srcLD + srcOff + j0 + j];
  }
  __syncthreads();
  int j = t & 63, part = t >> 6;
  unsigned w[8];
#pragma unroll
  for (int k = 0; k < 8; ++k)
    w[k] = pack2(tile[(part * 16 + 2 * k) * 65 + j], tile[(part * 16 + 2 * k + 1) * 65 + j]);
  uint4* p = (uint4*)&dst[(size_t)(j0 + j) * dstLD + c0 + part * 16];
  p[0] = make_uint4(w[0], w[1], w[2], w[3]);
  p[1] = make_uint4(w[4], w[5], w[6], w[7]);
}

// ---------------------------------------------------------------- K2: 7x7x7 conv + sigmoid
__global__ void __launch_bounds__(256) k_spa(const float* __restrict__ avgmx,
                                             const float* __restrict__ wspa,
                                             float* __restrict__ scores) {
  __shared__ float vol[2 * 4096];
  __shared__ float ws[686];
  int b = blockIdx.x >> 5, chunk = blockIdx.x & 31;
  int tid = threadIdx.x;
  for (int t = tid; t < 8192; t += 256) vol[t] = avgmx[b * 8192 + t];
  for (int t = tid; t < 686; t += 256) ws[t] = wspa[t];
  __syncthreads();
  int ci = tid & 1;
  int n = chunk * 128 + (tid >> 1);
  int d = n >> 8, h = (n >> 4) & 15, w = n & 15;
  const float* vb = vol + ci * 4096;
  const float* wb = ws + ci * 343;
  float acc = 0.f;
  for (int kd = 0; kd < 7; ++kd) {
    int zd = d - 3 + kd; if ((unsigned)zd >= 16u) continue;
    for (int kh = 0; kh < 7; ++kh) {
      int zh = h - 3 + kh; if ((unsigned)zh >= 16u) continue;
      const float* row = vb + zd * 256 + zh * 16;
      const float* wr = wb + kd * 49 + kh * 7;
#pragma unroll
      for (int kw = 0; kw < 7; ++kw) {
        int zw = w - 3 + kw;
        if ((unsigned)zw < 16u) acc += row[zw] * wr[kw];
      }
    }
  }
  acc += __shfl_xor(acc, 1);
  if (ci == 0) scores[b * NV + n] = 1.0f / (1.0f + expf(-acc));
}

// ---------------------------------------------------------------- K3: top-512 radix-select (wave-scan, fewer barriers)
__global__ void __launch_bounds__(1024) k_topk(const float* __restrict__ scores,
                                               int* __restrict__ idx) {
  __shared__ unsigned sv[4096];
  __shared__ int sB;
  __shared__ unsigned sSub, scnt;
  __shared__ unsigned hist[256];
  __shared__ int wsum[16];
  int b = blockIdx.x, tid = threadIdx.x;
  for (int t = tid; t < 4096; t += 1024) sv[t] = __float_as_uint(scores[b * NV + t]);
  if (tid == 0) scnt = 0;
  unsigned prefix = 0;
  int r = 512;
  for (int shift = 24; shift >= 0; shift -= 8) {
    if (tid < 256) hist[tid] = 0;
    __syncthreads();
    unsigned maskhi = (shift == 24) ? 0u : (0xFFFFFFFFu << (shift + 8));
    for (int i = 0; i < 4; ++i) {
      unsigned v = sv[tid + i * 1024];
      if ((v & maskhi) == prefix) atomicAdd(&hist[(v >> shift) & 255], 1u);
    }
    __syncthreads();
    if (tid < 64) {  // single wave: 4 bins/lane, shfl suffix scan, no barriers
      int lane = tid;
      unsigned h0 = hist[lane * 4 + 0], h1 = hist[lane * 4 + 1];
      unsigned h2 = hist[lane * 4 + 2], h3 = hist[lane * 4 + 3];
      unsigned s = h0 + h1 + h2 + h3;
      for (int off = 1; off < 64; off <<= 1) {
        unsigned y = __shfl_down(s, off);
        if (lane + off < 64) s += y;
      }
      unsigned tail = __shfl_down(s, 1);
      if (lane == 63) tail = 0;
      unsigned s3 = tail + h3, s2 = s3 + h2, s1 = s2 + h1, s0 = s1 + h0;
      unsigned sx[5] = {s0, s1, s2, s3, tail};
#pragma unroll
      for (int i = 0; i < 4; ++i)
        if (sx[i] >= (unsigned)r && sx[i + 1] < (unsigned)r) { sB = lane * 4 + i; sSub = sx[i + 1]; }
    }
    __syncthreads();
    prefix |= ((unsigned)sB) << shift;
    r -= (int)sSub;
    __syncthreads();
  }
  unsigned vstar = prefix;
  for (int i = 0; i < 4; ++i) {
    int t = tid * 4 + i;
    if (sv[t] > vstar) { unsigned p = atomicAdd(&scnt, 1u); idx[b * KTOP + p] = t; }
  }
  __syncthreads();
  int base = (int)scnt;
  int loc = 0;
  for (int i = 0; i < 4; ++i) loc += (sv[tid * 4 + i] == vstar);
  int lane = tid & 63, w = tid >> 6;
  int x = loc;
  for (int off = 1; off < 64; off <<= 1) {
    int y = __shfl_up(x, off);
    if (lane >= off) x += y;
  }
  if (lane == 63) wsum[w] = x;
  __syncthreads();
  int wbase = 0;
  for (int i = 0; i < w; ++i) wbase += wsum[i];
  int excl = wbase + x - loc;
  for (int i = 0; i < 4; ++i) {
    int t = tid * 4 + i;
    if (sv[t] == vstar) {
      if (excl < r) idx[b * KTOP + base + excl] = t;
      ++excl;
    }
  }
}

// ---------------------------------------------------------------- K4: fused V+Q projection, MFMA bf16 -> bf16 outs
__global__ void __launch_bounds__(256) k_qv(const unsigned short* __restrict__ xkv_t,
                                            const unsigned short* __restrict__ xq_t,
                                            const unsigned short* __restrict__ wv_t,
                                            const unsigned short* __restrict__ wq_t,
                                            const float* __restrict__ bkv,
                                            const float* __restrict__ bq,
                                            unsigned short* __restrict__ v_nc,
                                            unsigned short* __restrict__ qh) {
  __shared__ unsigned short Als[128 * 40];
  __shared__ unsigned short Bls[128 * 40];
  int role = blockIdx.z;
  int b = role & 1;
  bool isQ = role >= 2;
  const unsigned short* A = isQ ? wq_t : wv_t;                              // (j=256, c=256)
  const unsigned short* B = (isQ ? xq_t : xkv_t) + (size_t)b * NV * 256;    // (n, c)
  const float* bias = isQ ? bq : (bkv + 256);
  int n0 = blockIdx.x * 128, j0 = blockIdx.y * 128;
  int t = threadIdx.x;
  int wave = t >> 6, lane = t & 63;
  int l15 = lane & 15, q = lane >> 4, q8 = q * 8;
  int wj = (wave >> 1) * 64, wn = (wave & 1) * 64;
  f32x4 acc[4][4] = {};
  int ar = t >> 1, ah = t & 1;
  for (int c0 = 0; c0 < 256; c0 += 32) {
    __syncthreads();
    {
      const unsigned short* sa = &A[(size_t)(j0 + ar) * 256 + c0 + ah * 16];
      *(uint4*)&Als[ar * 40 + ah * 16]     = *(const uint4*)&sa[0];
      *(uint4*)&Als[ar * 40 + ah * 16 + 8] = *(const uint4*)&sa[8];
      const unsigned short* sb = &B[(size_t)(n0 + ar) * 256 + c0 + ah * 16];
      *(uint4*)&Bls[ar * 40 + ah * 16]     = *(const uint4*)&sb[0];
      *(uint4*)&Bls[ar * 40 + ah * 16 + 8] = *(const uint4*)&sb[8];
    }
    __syncthreads();
    bf16x8 af[4], bf[4];
#pragma unroll
    for (int mt = 0; mt < 4; ++mt)
      af[mt] = *(const bf16x8*)&Als[(wj + mt * 16 + l15) * 40 + q8];
#pragma unroll
    for (int nt = 0; nt < 4; ++nt)
      bf[nt] = *(const bf16x8*)&Bls[(wn + nt * 16 + l15) * 40 + q8];
#pragma unroll
    for (int mt = 0; mt < 4; ++mt)
#pragma unroll
      for (int nt = 0; nt < 4; ++nt)
        acc[mt][nt] = __builtin_amdgcn_mfma_f32_16x16x32_bf16(af[mt], bf[nt], acc[mt][nt], 0, 0, 0);
  }
#pragma unroll
  for (int mt = 0; mt < 4; ++mt) {
    int jb = j0 + wj + mt * 16 + q * 4;          // 4 consecutive j
    float4 b4 = *(const float4*)&bias[jb];
#pragma unroll
    for (int nt = 0; nt < 4; ++nt) {
      int n = n0 + wn + nt * 16 + l15;
      float v0 = acc[mt][nt][0] + b4.x;
      float v1 = acc[mt][nt][1] + b4.y;
      float v2 = acc[mt][nt][2] + b4.z;
      float v3 = acc[mt][nt][3] + b4.w;
      uint2 pk = make_uint2(pack2(v0, v1), pack2(v2, v3));
      if (isQ) {
        int h = jb >> 3, d0 = jb & 7;            // jb%4==0 -> within one head
        *(uint2*)&qh[((size_t)(b * 32 + h) * NV + n) * 8 + d0] = pk;
      } else {
        *(uint2*)&v_nc[((size_t)b * NV + n) * 256 + jb] = pk;
      }
    }
  }
}

// ---------------------------------------------------------------- K5: fused gathered-K projection + V^T build
// round-15: kg role is one 16(key)x16(j) MFMA tile PER WAVE, operands straight
// from global (gathered key rows = contiguous 512B rows of xkv_t, L2-hot;
// wk_t 128KB L2-resident). No LDS, no barriers, 8 unrolled K-steps. 512
// tiles/batch = 128 blocks/batch (was 16 blocks total, Occ 5%). c0 ascending
// K=32 chunks -> bitwise-identical accumulation to the old k_kg.
// bx >= 128: V^T build role (was k_vt), bh = z*32 + (bx-128).
__global__ void __launch_bounds__(256) k_kgvt(const unsigned short* __restrict__ xkv_t,
                                              const unsigned short* __restrict__ wk_t,
                                              const float* __restrict__ bkv,
                                              const int* __restrict__ map,
                                              const unsigned short* __restrict__ v_nc,
                                              unsigned short* __restrict__ kg,
                                              unsigned short* __restrict__ vt) {
  int b = blockIdx.z;
  int bx = blockIdx.x;
  int t = threadIdx.x;
  if (bx >= 128) {  // ---- V^T (+ones row), keys permuted by kappa for PV A-frag
    int h = bx - 128;
    int bh = b * 32 + h;
    unsigned short* dst = vt + (size_t)bh * 16 * 512;
    for (int i = t; i < 512; i += 256) dst[8 * 512 + i] = 0x3F80;     // 1.0 bf16
    for (int i = t; i < 512 * 7; i += 256) dst[9 * 512 + i] = 0;
    const int* ib = map + b * KTOP;
    for (int kk = t; kk < 512; kk += 256) {
      uint4 v = *(const uint4*)&v_nc[((size_t)b * NV + ib[kk]) * 256 + h * 8];
      unsigned short tmp[8];
      *(uint4*)tmp = v;
      int kc = kk >> 5, ka = kk & 31;
      int s = (ka < 16) ? ((ka >> 2) * 8 + (ka & 3))
                        : (((ka - 16) >> 2) * 8 + (ka & 3) + 4);
      int col = kc * 32 + s;
#pragma unroll
      for (int d = 0; d < 8; ++d) dst[d * 512 + col] = tmp[d];
    }
    return;
  }
  // ---- gathered K projection, one MFMA tile per wave
  const float kscale = 0.35355339059327373f * 1.4426950408889634f;  // 1/sqrt(8)*log2(e)
  int wave = t >> 6, lane = t & 63;
  int l15 = lane & 15, quad = lane >> 4;
  int tile_id = bx * 4 + wave;                 // 0..511
  int kt = tile_id & 31, jt = tile_id >> 5;    // 32 key-tiles x 16 j-tiles
  int m0 = kt * 16, j0 = jt * 16;
  int nrow = map[b * KTOP + m0 + l15];         // gathered key row for this lane
  const unsigned short* Arow = wk_t + (size_t)(j0 + l15) * 256 + quad * 8;
  const unsigned short* Brow = xkv_t + (size_t)b * NV * 256 + (size_t)nrow * 256 + quad * 8;
  f32x4 acc = {0.f, 0.f, 0.f, 0.f};
#pragma unroll
  for (int s = 0; s < 8; ++s) {
    bf16x8 af = *(const bf16x8*)&Arow[s * 32];
    bf16x8 bf = *(const bf16x8*)&Brow[s * 32];
    acc = __builtin_amdgcn_mfma_f32_16x16x32_bf16(af, bf, acc, 0, 0, 0);
  }
  // D: row = j = j0 + quad*4 + r, col = key = m0 + l15
  int h = (j0 >> 3) + (quad >> 1), d0b = (quad & 1) * 4;
  int jb = j0 + quad * 4;
  float4 b4 = *(const float4*)&bkv[jb];
  int m = m0 + l15;
  float v0 = (acc[0] + b4.x) * kscale;
  float v1 = (acc[1] + b4.y) * kscale;
  float v2 = (acc[2] + b4.z) * kscale;
  float v3 = (acc[3] + b4.w) * kscale;
  *(uint2*)&kg[((size_t)(b * 32 + h) * KTOP + m) * 8 + d0b] =
      make_uint2(pack2(v0, v1), pack2(v2, v3));
}

// ---------------------------------------------------------------- K6: MFMA flash attention, swapped-QK, LDS-free
__global__ void __launch_bounds__(256) k_fattn(const unsigned short* __restrict__ qh,
                                               const unsigned short* __restrict__ kg,
                                               const unsigned short* __restrict__ vt,
                                               unsigned short* __restrict__ aoydw) {
  int bh = blockIdx.x;
  int b = bh >> 5, h = bh & 31;
  int t = threadIdx.x, wave = t >> 6, lane = t & 63;
  int l15 = lane & 15, quad = lane >> 4;
  int n0 = blockIdx.y * 128 + wave * 32;       // 32 queries per wave
  bf16x8 q0 = {}, q1 = {};                     // B-operand: n=query, k=dim (quad 0 only)
  if (quad == 0) {
    q0 = *(const bf16x8*)&qh[((size_t)bh * NV + n0 + l15) * 8];
    q1 = *(const bf16x8*)&qh[((size_t)bh * NV + n0 + 16 + l15) * 8];
  }
  const unsigned short* kbase = kg + (size_t)bh * KTOP * 8;
  const unsigned short* vbase = vt + (size_t)bh * 16 * 512;
  f32x4 acc0 = {0.f, 0.f, 0.f, 0.f}, acc1 = {0.f, 0.f, 0.f, 0.f};
  bf16x8 kA0 = {}, kA1 = {};                   // A-operand: m=key, k=dim (quad 0 only)
  if (quad == 0) {
    kA0 = *(const bf16x8*)&kbase[(size_t)l15 * 8];
    kA1 = *(const bf16x8*)&kbase[(size_t)(16 + l15) * 8];
  }
  for (int kc = 0; kc < 16; ++kc) {            // 32 keys per iteration
    bf16x8 nA0 = {}, nA1 = {};                 // prefetch next K chunk
    if (quad == 0 && kc < 15) {
      nA0 = *(const bf16x8*)&kbase[(size_t)(kc * 32 + 32 + l15) * 8];
      nA1 = *(const bf16x8*)&kbase[(size_t)(kc * 32 + 48 + l15) * 8];
    }
    bf16x8 bV = *(const bf16x8*)&vbase[(size_t)l15 * 512 + kc * 32 + quad * 8];
    f32x4 z = {0.f, 0.f, 0.f, 0.f};
    // D: col=query=l15, row=key=quad*4+r  -> P already in PV A-frag layout
    f32x4 s00 = __builtin_amdgcn_mfma_f32_16x16x32_bf16(kA0, q0, z, 0, 0, 0);
    f32x4 s01 = __builtin_amdgcn_mfma_f32_16x16x32_bf16(kA1, q0, z, 0, 0, 0);
    f32x4 s10 = __builtin_amdgcn_mfma_f32_16x16x32_bf16(kA0, q1, z, 0, 0, 0);
    f32x4 s11 = __builtin_amdgcn_mfma_f32_16x16x32_bf16(kA1, q1, z, 0, 0, 0);
    uint4 P0, P1;
    P0.x = packtrunc(__builtin_amdgcn_exp2f(s00[0]), __builtin_amdgcn_exp2f(s00[1]));
    P0.y = packtrunc(__builtin_amdgcn_exp2f(s00[2]), __builtin_amdgcn_exp2f(s00[3]));
    P0.z = packtrunc(__builtin_amdgcn_exp2f(s01[0]), __builtin_amdgcn_exp2f(s01[1]));
    P0.w = packtrunc(__builtin_amdgcn_exp2f(s01[2]), __builtin_amdgcn_exp2f(s01[3]));
    P1.x = packtrunc(__builtin_amdgcn_exp2f(s10[0]), __builtin_amdgcn_exp2f(s10[1]));
    P1.y = packtrunc(__builtin_amdgcn_exp2f(s10[2]), __builtin_amdgcn_exp2f(s10[3]));
    P1.z = packtrunc(__builtin_amdgcn_exp2f(s11[0]), __builtin_amdgcn_exp2f(s11[1]));
    P1.w = packtrunc(__builtin_amdgcn_exp2f(s11[2]), __builtin_amdgcn_exp2f(s11[3]));
    acc0 = __builtin_amdgcn_mfma_f32_16x16x32_bf16(*(bf16x8*)&P0, bV, acc0, 0, 0, 0);
    acc1 = __builtin_amdgcn_mfma_f32_16x16x32_bf16(*(bf16x8*)&P1, bV, acc1, 0, 0, 0);
    kA0 = nA0; kA1 = nA1;
  }
#pragma unroll
  for (int tq = 0; tq < 2; ++tq) {
    f32x4 a = tq ? acc1 : acc0;
#pragma unroll
    for (int r = 0; r < 4; ++r) {
      float se = __shfl(a[r], quad * 16 + 8);  // denominator from ones-row col (l15=8)
      float o = a[r] * (1.0f / se);
      if (l15 < 8) {
        int n = n0 + tq * 16 + quad * 4 + r;
        aoydw[((size_t)b * NV + n) * 512 + h * 8 + l15] = f2bf(o);
      }
    }
  }
}

// ---------------------------------------------------------------- K7: depthwise conv, v_nc (n,c) bf16 -> aoydw cols 256+
__global__ void __launch_bounds__(256) k_dw(const unsigned short* __restrict__ v_nc,
                                            const float* __restrict__ wdw,
                                            const float* __restrict__ bdw,
                                            unsigned short* __restrict__ aoydw) {
  int c = threadIdx.x;
  int b = blockIdx.y;
  float wr[27];
#pragma unroll
  for (int i = 0; i < 27; ++i) wr[i] = wdw[c * 27 + i];
  float bias = bdw[c];
  const unsigned short* src = v_nc + (size_t)b * NV * 256 + c;
  unsigned short* dst = aoydw + (size_t)b * NV * 512 + 256 + c;
  int n = blockIdx.x * 4;                    // 4 consecutive n (same h-row) share taps
  int d = n >> 8, h = (n >> 4) & 15, w = n & 15;
  float a0 = bias, a1 = bias, a2 = bias, a3 = bias;
#pragma unroll
  for (int kd = 0; kd < 3; ++kd) {
    int zd = d - 1 + kd; bool okd = (unsigned)zd < 16u;
#pragma unroll
    for (int kh = 0; kh < 3; ++kh) {
      int zh = h - 1 + kh; bool okh = okd && ((unsigned)zh < 16u);
      int rowb = zd * 256 + zh * 16;
      float v[6];
#pragma unroll
      for (int i = 0; i < 6; ++i) {
        int zw = w - 1 + i;
        bool ok = okh && ((unsigned)zw < 16u);   // wave-uniform mask
        v[i] = ok ? bf2f(src[(size_t)(rowb + zw) * 256]) : 0.f;
      }
      const float* wp = &wr[kd * 9 + kh * 3];
      a0 = fmaf(v[0], wp[0], fmaf(v[1], wp[1], fmaf(v[2], wp[2], a0)));
      a1 = fmaf(v[1], wp[0], fmaf(v[2], wp[1], fmaf(v[3], wp[2], a1)));
      a2 = fmaf(v[2], wp[0], fmaf(v[3], wp[1], fmaf(v[4], wp[2], a2)));
      a3 = fmaf(v[3], wp[0], fmaf(v[4], wp[1], fmaf(v[5], wp[2], a3)));
    }
  }
  dst[(size_t)(n + 0) * 512] = f2bf(a0);
  dst[(size_t)(n + 1) * 512] = f2bf(a1);
  dst[(size_t)(n + 2) * 512] = f2bf(a2);
  dst[(size_t)(n + 3) * 512] = f2bf(a3);
}

// ---------------------------------------------------------------- K8: final GEMM K=512, MFMA bf16
__global__ void __launch_bounds__(256) k_final(const unsigned short* __restrict__ aoydw,
                                               const unsigned short* __restrict__ wcat,
                                               const float* __restrict__ bproj,
                                               const float* __restrict__ bpw,
                                               float* __restrict__ out) {
  __shared__ unsigned short Als[64 * 40];
  __shared__ unsigned short Bls[128 * 40];
  int n0 = blockIdx.x * 64, j0 = blockIdx.y * 128, b = blockIdx.z;
  int t = threadIdx.x;
  int wave = t >> 6, lane = t & 63;
  int l15 = lane & 15, q = lane >> 4, q8 = q * 8;
  int wn = (wave >> 1) * 32, wjj = (wave & 1) * 64;
  f32x4 acc[2][4] = {};
  const unsigned short* Abase = aoydw + (size_t)b * NV * 512;
  int ar = t >> 2, aq = t & 3;
  int br = t >> 1, bhh = t & 1;
  for (int c0 = 0; c0 < 512; c0 += 32) {
    __syncthreads();
    *(uint4*)&Als[ar * 40 + aq * 8] =
        *(const uint4*)&Abase[(size_t)(n0 + ar) * 512 + c0 + aq * 8];
    const unsigned short* sb = &wcat[(size_t)(j0 + br) * 512 + c0 + bhh * 16];
    *(uint4*)&Bls[br * 40 + bhh * 16]     = *(const uint4*)&sb[0];
    *(uint4*)&Bls[br * 40 + bhh * 16 + 8] = *(const uint4*)&sb[8];
    __syncthreads();
    bf16x8 af[2], bf[4];
#pragma unroll
    for (int mt = 0; mt < 2; ++mt)
      af[mt] = *(const bf16x8*)&Als[(wn + mt * 16 + l15) * 40 + q8];
#pragma unroll
    for (int nt = 0; nt < 4; ++nt)
      bf[nt] = *(const bf16x8*)&Bls[(wjj + nt * 16 + l15) * 40 + q8];
#pragma unroll
    for (int mt = 0; mt < 2; ++mt)
#pragma unroll
      for (int nt = 0; nt < 4; ++nt)
        acc[mt][nt] = __builtin_amdgcn_mfma_f32_16x16x32_bf16(af[mt], bf[nt], acc[mt][nt], 0, 0, 0);
  }
#pragma unroll
  for (int nt = 0; nt < 4; ++nt) {
    int j = j0 + wjj + nt * 16 + l15;
    float bl = bproj[j] + bpw[j];
#pragma unroll
    for (int mt = 0; mt < 2; ++mt) {
      int n = n0 + wn + mt * 16 + q * 4;
      float4 r = make_float4(acc[mt][nt][0] + bl, acc[mt][nt][1] + bl,
                             acc[mt][nt][2] + bl, acc[mt][nt][3] + bl);
      *(float4*)&out[(size_t)(b * 256 + j) * NV + n] = r;
    }
  }
}

// ---------------------------------------------------------------- launch
extern "C" void kernel_launch(void* const* d_in, const int* in_sizes, int n_in,
                              void* d_out, int out_size, void* d_ws, size_t ws_size,
                              hipStream_t stream) {
  const float* x_kv   = (const float*)d_in[0];
  const float* x_q    = (const float*)d_in[1];
  const float* w_spa  = (const float*)d_in[2];
  const float* w_kv   = (const float*)d_in[3];
  const float* b_kv   = (const float*)d_in[4];
  const float* w_q    = (const float*)d_in[5];
  const float* b_q    = (const float*)d_in[6];
  const float* w_proj = (const float*)d_in[7];
  const float* b_proj = (const float*)d_in[8];
  const float* w_dw   = (const float*)d_in[9];
  const float* b_dw   = (const float*)d_in[10];
  const float* w_pw   = (const float*)d_in[11];
  const float* b_pw   = (const float*)d_in[12];
  float* out = (float*)d_out;

  const size_t MB = 1024 * 1024;
  char* ws = (char*)d_ws;
  unsigned short* xkv_t = (unsigned short*)(ws);                 // 4 MB (b,n,c) bf16
  unsigned short* xq_t  = (unsigned short*)(ws + 4 * MB);        // 4 MB
  unsigned short* v_nc  = (unsigned short*)(ws + 8 * MB);        // 4 MB (b,n,c) bf16
  unsigned short* qh    = (unsigned short*)(ws + 12 * MB);       // 4 MB (b,h,n,8) bf16
  unsigned short* aoydw = (unsigned short*)(ws + 16 * MB);       // 8 MB (b,n,512) bf16
  unsigned short* kg    = (unsigned short*)(ws + 24 * MB);       // 512 KB (bh,512,8) bf16 pre-scaled
  unsigned short* vt    = (unsigned short*)(ws + 24 * MB + 512 * 1024);  // 1 MB (bh,16,512) bf16
  unsigned short* wv_t  = (unsigned short*)(ws + 26 * MB);               // 128 KB
  unsigned short* wq_t  = (unsigned short*)(ws + 26 * MB + 131072);      // 128 KB
  unsigned short* wcat  = (unsigned short*)(ws + 26 * MB + 262144);      // 256 KB
  unsigned short* wk_t  = (unsigned short*)(ws + 26 * MB + 524288);      // 128 KB
  float*          avgmx = (float*)(ws + 27 * MB);                        //  64 KB
  float*          scores= (float*)(ws + 27 * MB + 65536);               //  32 KB
  int*            idx   = (int*)  (ws + 27 * MB + 98304);               //   4 KB

  k_tcast2<<<dim3(64, 4, 5), 256, 0, stream>>>(x_kv, x_q, xkv_t, xq_t, avgmx);
  k_wprep<<<dim3(4, 4, 5), 256, 0, stream>>>(w_kv, w_q, w_proj, w_pw, wv_t, wq_t, wcat, wk_t);
  k_spa<<<64, 256, 0, stream>>>(avgmx, w_spa, scores);
  k_topk<<<2, 1024, 0, stream>>>(scores, idx);
  k_qv<<<dim3(32, 2, 4), 256, 0, stream>>>(xkv_t, xq_t, wv_t, wq_t, b_kv, b_q, v_nc, qh);
  k_kgvt<<<dim3(160, 1, 2), 256, 0, stream>>>(xkv_t, wk_t, b_kv, idx, v_nc, kg, vt);
  k_fattn<<<dim3(64, 32), 256, 0, stream>>>(qh, kg, vt, aoydw);
  k_dw<<<dim3(1024, 2), 256, 0, stream>>>(v_nc, w_dw, b_dw, aoydw);
  k_final<<<dim3(64, 2, 2), 256, 0, stream>>>(aoydw, wcat, b_proj, b_pw, out);
}

// Round 4
// 188.082 us; speedup vs baseline: 1.3864x; 1.0912x over previous
//
#include <hip/hip_runtime.h>
#include <hip/hip_bf16.h>

typedef short bf16x8 __attribute__((ext_vector_type(8)));
typedef float f32x4 __attribute__((ext_vector_type(4)));

constexpr int CN = 256, NV = 4096, KTOP = 512;

static __device__ __forceinline__ unsigned short f2bf(float f) {
  __hip_bfloat16 h = __float2bfloat16(f);
  return *(unsigned short*)&h;
}
static __device__ __forceinline__ unsigned pack2(float a, float b) {
  return (unsigned)f2bf(a) | ((unsigned)f2bf(b) << 16);
}
static __device__ __forceinline__ float bf2f(unsigned short u) {
  return __uint_as_float(((unsigned)u) << 16);
}
// truncated-bf16 pack: lo16 = bf16(a), hi16 = bf16(b)  (2 VALU, no cvt)
static __device__ __forceinline__ unsigned packtrunc(float a, float b) {
  return (__float_as_uint(a) >> 16) | (__float_as_uint(b) & 0xFFFF0000u);
}

// ---------------------------------------------------------------- L1: transpose-cast + channel-reduce + weight-prep
// z = 0,1: x_kv batches -> xkv_t ; z = 2,3: x_q batches -> xq_t
// z = 4: channel mean/max (f32, preserved for top-k stability)
// z = 5..9: weight prep roles 0..4 (only bx<4 && by<4 active)
__global__ void __launch_bounds__(256) k_stage1(const float* __restrict__ xkv,
                                                const float* __restrict__ xq,
                                                const float* __restrict__ wkv,
                                                const float* __restrict__ wq,
                                                const float* __restrict__ wproj,
                                                const float* __restrict__ wpw,
                                                unsigned short* __restrict__ xkv_t,
                                                unsigned short* __restrict__ xq_t,
                                                float* __restrict__ avgmx,
                                                unsigned short* __restrict__ wv_t,
                                                unsigned short* __restrict__ wq_t,
                                                unsigned short* __restrict__ wcat,
                                                unsigned short* __restrict__ wk_t) {
  __shared__ float tile[64 * 65];
  int z = blockIdx.z;
  int t = threadIdx.x;
  if (z == 4) {  // channel mean/max role
    __shared__ float ssum[256], smax[256];
    int blk = blockIdx.y * 64 + blockIdx.x;
    int b = blk >> 7, n0 = (blk & 127) * 32;
    int cg = t >> 5, nl = t & 31;
    int n = n0 + nl;
    const float* p = xkv + (size_t)b * CN * NV + (size_t)cg * 32 * NV + n;
    float s = 0.f, m = -1e30f;
    for (int i = 0; i < 32; ++i) {
      float v = p[(size_t)i * NV];
      s += v; m = fmaxf(m, v);
    }
    ssum[t] = s; smax[t] = m;
    __syncthreads();
    if (cg == 0) {
      for (int g = 1; g < 8; ++g) { s += ssum[g * 32 + nl]; m = fmaxf(m, smax[g * 32 + nl]); }
      avgmx[(b * 2 + 0) * NV + n] = s * (1.0f / 256.0f);
      avgmx[(b * 2 + 1) * NV + n] = m;
    }
    return;
  }
  if (z >= 5) {  // weight-prep roles
    if (blockIdx.x >= 4 || blockIdx.y >= 4) return;
    int role = z - 5;
    int j0 = blockIdx.x * 64, c0 = blockIdx.y * 64;
    if (role == 3) {  // wpw (j,c) straight cast into wcat cols 256..512
      int j = t >> 2, part = t & 3;
      const float* s = &wpw[(size_t)(j0 + j) * 256 + c0 + part * 16];
      unsigned w[8];
#pragma unroll
      for (int k = 0; k < 8; ++k) w[k] = pack2(s[2 * k], s[2 * k + 1]);
      uint4* p = (uint4*)&wcat[(size_t)(j0 + j) * 512 + 256 + c0 + part * 16];
      p[0] = make_uint4(w[0], w[1], w[2], w[3]);
      p[1] = make_uint4(w[4], w[5], w[6], w[7]);
      return;
    }
    const float* src; int srcLD, srcOff; unsigned short* dst; int dstLD;
    if (role == 0)      { src = wkv;   srcLD = 512; srcOff = 256; dst = wv_t; dstLD = 256; }
    else if (role == 1) { src = wq;    srcLD = 256; srcOff = 0;   dst = wq_t; dstLD = 256; }
    else if (role == 4) { src = wkv;   srcLD = 512; srcOff = 0;   dst = wk_t; dstLD = 256; }
    else                { src = wproj; srcLD = 256; srcOff = 0;   dst = wcat; dstLD = 512; }
    for (int i = 0; i < 16; ++i) {
      int id = i * 256 + t, c = id >> 6, j = id & 63;
      tile[c * 65 + j] = src[(size_t)(c0 + c) * srcLD + srcOff + j0 + j];
    }
    __syncthreads();
    int j = t & 63, part = t >> 6;
    unsigned w[8];
#pragma unroll
    for (int k = 0; k < 8; ++k)
      w[k] = pack2(tile[(part * 16 + 2 * k) * 65 + j], tile[(part * 16 + 2 * k + 1) * 65 + j]);
    uint4* p = (uint4*)&dst[(size_t)(j0 + j) * dstLD + c0 + part * 16];
    p[0] = make_uint4(w[0], w[1], w[2], w[3]);
    p[1] = make_uint4(w[4], w[5], w[6], w[7]);
    return;
  }
  // transpose-cast roles
  int b = z & 1;
  const float* s = (z < 2 ? xkv : xq) + (size_t)b * CN * NV;
  unsigned short* d = (z < 2 ? xkv_t : xq_t) + (size_t)b * NV * 256;
  int c0 = blockIdx.y * 64, n0 = blockIdx.x * 64;
  for (int i = 0; i < 16; ++i) {
    int id = i * 256 + t, c = id >> 6, n = id & 63;
    tile[c * 65 + n] = s[(size_t)(c0 + c) * NV + n0 + n];
  }
  __syncthreads();
  int n = t & 63, part = t >> 6;
  unsigned w[8];
#pragma unroll
  for (int k = 0; k < 8; ++k)
    w[k] = pack2(tile[(part * 16 + 2 * k) * 65 + n], tile[(part * 16 + 2 * k + 1) * 65 + n]);
  uint4* p = (uint4*)&d[(size_t)(n0 + n) * 256 + c0 + part * 16];
  p[0] = make_uint4(w[0], w[1], w[2], w[3]);
  p[1] = make_uint4(w[4], w[5], w[6], w[7]);
}

// ---------------------------------------------------------------- L2: fused V+Q projection (MFMA) + spa conv
// z = 0..3: qv roles ; z = 4: 7x7x7 conv + sigmoid (block id = by*32+bx, 64 blocks)
__global__ void __launch_bounds__(256) k_stage2(const unsigned short* __restrict__ xkv_t,
                                                const unsigned short* __restrict__ xq_t,
                                                const unsigned short* __restrict__ wv_t,
                                                const unsigned short* __restrict__ wq_t,
                                                const float* __restrict__ bkv,
                                                const float* __restrict__ bq,
                                                const float* __restrict__ avgmx,
                                                const float* __restrict__ wspa,
                                                unsigned short* __restrict__ v_nc,
                                                unsigned short* __restrict__ qh,
                                                float* __restrict__ scores) {
  __shared__ alignas(16) char smem[35520];   // max(qv 20480, spa 32768+2744)
  int z = blockIdx.z;
  int t = threadIdx.x;
  if (z == 4) {  // ---- spa role
    float* vol = (float*)smem;
    float* ws = (float*)(smem + 32768);
    int id = blockIdx.y * 32 + blockIdx.x;
    int b = id >> 5, chunk = id & 31;
    for (int i = t; i < 8192; i += 256) vol[i] = avgmx[b * 8192 + i];
    for (int i = t; i < 686; i += 256) ws[i] = wspa[i];
    __syncthreads();
    int ci = t & 1;
    int n = chunk * 128 + (t >> 1);
    int d = n >> 8, h = (n >> 4) & 15, w = n & 15;
    const float* vb = vol + ci * 4096;
    const float* wb = ws + ci * 343;
    float acc = 0.f;
    for (int kd = 0; kd < 7; ++kd) {
      int zd = d - 3 + kd; if ((unsigned)zd >= 16u) continue;
      for (int kh = 0; kh < 7; ++kh) {
        int zh = h - 3 + kh; if ((unsigned)zh >= 16u) continue;
        const float* row = vb + zd * 256 + zh * 16;
        const float* wr = wb + kd * 49 + kh * 7;
#pragma unroll
        for (int kw = 0; kw < 7; ++kw) {
          int zw = w - 3 + kw;
          if ((unsigned)zw < 16u) acc += row[zw] * wr[kw];
        }
      }
    }
    acc += __shfl_xor(acc, 1);
    if (ci == 0) scores[b * NV + n] = 1.0f / (1.0f + expf(-acc));
    return;
  }
  // ---- qv role
  unsigned short* Als = (unsigned short*)smem;
  unsigned short* Bls = Als + 128 * 40;
  int role = z;
  int b = role & 1;
  bool isQ = role >= 2;
  const unsigned short* A = isQ ? wq_t : wv_t;                              // (j=256, c=256)
  const unsigned short* B = (isQ ? xq_t : xkv_t) + (size_t)b * NV * 256;    // (n, c)
  const float* bias = isQ ? bq : (bkv + 256);
  int n0 = blockIdx.x * 128, j0 = blockIdx.y * 128;
  int wave = t >> 6, lane = t & 63;
  int l15 = lane & 15, q = lane >> 4, q8 = q * 8;
  int wj = (wave >> 1) * 64, wn = (wave & 1) * 64;
  f32x4 acc[4][4] = {};
  int ar = t >> 1, ah = t & 1;
  for (int c0 = 0; c0 < 256; c0 += 32) {
    __syncthreads();
    {
      const unsigned short* sa = &A[(size_t)(j0 + ar) * 256 + c0 + ah * 16];
      *(uint4*)&Als[ar * 40 + ah * 16]     = *(const uint4*)&sa[0];
      *(uint4*)&Als[ar * 40 + ah * 16 + 8] = *(const uint4*)&sa[8];
      const unsigned short* sb = &B[(size_t)(n0 + ar) * 256 + c0 + ah * 16];
      *(uint4*)&Bls[ar * 40 + ah * 16]     = *(const uint4*)&sb[0];
      *(uint4*)&Bls[ar * 40 + ah * 16 + 8] = *(const uint4*)&sb[8];
    }
    __syncthreads();
    bf16x8 af[4], bf[4];
#pragma unroll
    for (int mt = 0; mt < 4; ++mt)
      af[mt] = *(const bf16x8*)&Als[(wj + mt * 16 + l15) * 40 + q8];
#pragma unroll
    for (int nt = 0; nt < 4; ++nt)
      bf[nt] = *(const bf16x8*)&Bls[(wn + nt * 16 + l15) * 40 + q8];
#pragma unroll
    for (int mt = 0; mt < 4; ++mt)
#pragma unroll
      for (int nt = 0; nt < 4; ++nt)
        acc[mt][nt] = __builtin_amdgcn_mfma_f32_16x16x32_bf16(af[mt], bf[nt], acc[mt][nt], 0, 0, 0);
  }
#pragma unroll
  for (int mt = 0; mt < 4; ++mt) {
    int jb = j0 + wj + mt * 16 + q * 4;          // 4 consecutive j
    float4 b4 = *(const float4*)&bias[jb];
#pragma unroll
    for (int nt = 0; nt < 4; ++nt) {
      int n = n0 + wn + nt * 16 + l15;
      float v0 = acc[mt][nt][0] + b4.x;
      float v1 = acc[mt][nt][1] + b4.y;
      float v2 = acc[mt][nt][2] + b4.z;
      float v3 = acc[mt][nt][3] + b4.w;
      uint2 pk = make_uint2(pack2(v0, v1), pack2(v2, v3));
      if (isQ) {
        int h = jb >> 3, d0 = jb & 7;            // jb%4==0 -> within one head
        *(uint2*)&qh[((size_t)(b * 32 + h) * NV + n) * 8 + d0] = pk;
      } else {
        *(uint2*)&v_nc[((size_t)b * NV + n) * 256 + jb] = pk;
      }
    }
  }
}

// ---------------------------------------------------------------- L3: depthwise conv + top-512 radix select
// bx < 256: dw role (16 n x 256 c per block, 1024 thr) ; bx == 256: topk for batch z
__global__ void __launch_bounds__(1024) k_stage3(const float* __restrict__ scores,
                                                 int* __restrict__ idx,
                                                 const unsigned short* __restrict__ v_nc,
                                                 const float* __restrict__ wdw,
                                                 const float* __restrict__ bdw,
                                                 unsigned short* __restrict__ aoydw) {
  int b = blockIdx.z;
  int bx = blockIdx.x;
  int tid = threadIdx.x;
  if (bx == 256) {  // ---- topk role (unchanged radix-select, 1024 thr)
    __shared__ unsigned sv[4096];
    __shared__ int sB;
    __shared__ unsigned sSub, scnt;
    __shared__ unsigned hist[256];
    __shared__ int wsum[16];
    for (int t = tid; t < 4096; t += 1024) sv[t] = __float_as_uint(scores[b * NV + t]);
    if (tid == 0) scnt = 0;
    unsigned prefix = 0;
    int r = 512;
    for (int shift = 24; shift >= 0; shift -= 8) {
      if (tid < 256) hist[tid] = 0;
      __syncthreads();
      unsigned maskhi = (shift == 24) ? 0u : (0xFFFFFFFFu << (shift + 8));
      for (int i = 0; i < 4; ++i) {
        unsigned v = sv[tid + i * 1024];
        if ((v & maskhi) == prefix) atomicAdd(&hist[(v >> shift) & 255], 1u);
      }
      __syncthreads();
      if (tid < 64) {
        int lane = tid;
        unsigned h0 = hist[lane * 4 + 0], h1 = hist[lane * 4 + 1];
        unsigned h2 = hist[lane * 4 + 2], h3 = hist[lane * 4 + 3];
        unsigned s = h0 + h1 + h2 + h3;
        for (int off = 1; off < 64; off <<= 1) {
          unsigned y = __shfl_down(s, off);
          if (lane + off < 64) s += y;
        }
        unsigned tail = __shfl_down(s, 1);
        if (lane == 63) tail = 0;
        unsigned s3 = tail + h3, s2 = s3 + h2, s1 = s2 + h1, s0 = s1 + h0;
        unsigned sx[5] = {s0, s1, s2, s3, tail};
#pragma unroll
        for (int i = 0; i < 4; ++i)
          if (sx[i] >= (unsigned)r && sx[i + 1] < (unsigned)r) { sB = lane * 4 + i; sSub = sx[i + 1]; }
      }
      __syncthreads();
      prefix |= ((unsigned)sB) << shift;
      r -= (int)sSub;
      __syncthreads();
    }
    unsigned vstar = prefix;
    for (int i = 0; i < 4; ++i) {
      int t = tid * 4 + i;
      if (sv[t] > vstar) { unsigned p = atomicAdd(&scnt, 1u); idx[b * KTOP + p] = t; }
    }
    __syncthreads();
    int base = (int)scnt;
    int loc = 0;
    for (int i = 0; i < 4; ++i) loc += (sv[tid * 4 + i] == vstar);
    int lane = tid & 63, w = tid >> 6;
    int x = loc;
    for (int off = 1; off < 64; off <<= 1) {
      int y = __shfl_up(x, off);
      if (lane >= off) x += y;
    }
    if (lane == 63) wsum[w] = x;
    __syncthreads();
    int wbase = 0;
    for (int i = 0; i < w; ++i) wbase += wsum[i];
    int excl = wbase + x - loc;
    for (int i = 0; i < 4; ++i) {
      int t = tid * 4 + i;
      if (sv[t] == vstar) {
        if (excl < r) idx[b * KTOP + base + excl] = t;
        ++excl;
      }
    }
    return;
  }
  // ---- dw role: 16 consecutive n x 256 c per block
  int c = tid & 255;
  float wr[27];
#pragma unroll
  for (int i = 0; i < 27; ++i) wr[i] = wdw[c * 27 + i];
  float bias = bdw[c];
  const unsigned short* src = v_nc + (size_t)b * NV * 256 + c;
  unsigned short* dst = aoydw + (size_t)b * NV * 512 + 256 + c;
  int n = bx * 16 + (tid >> 8) * 4;          // 4 consecutive n (same h-row) share taps
  int d = n >> 8, h = (n >> 4) & 15, w = n & 15;
  float a0 = bias, a1 = bias, a2 = bias, a3 = bias;
#pragma unroll
  for (int kd = 0; kd < 3; ++kd) {
    int zd = d - 1 + kd; bool okd = (unsigned)zd < 16u;
#pragma unroll
    for (int kh = 0; kh < 3; ++kh) {
      int zh = h - 1 + kh; bool okh = okd && ((unsigned)zh < 16u);
      int rowb = zd * 256 + zh * 16;
      float v[6];
#pragma unroll
      for (int i = 0; i < 6; ++i) {
        int zw = w - 1 + i;
        bool ok = okh && ((unsigned)zw < 16u);   // wave-uniform mask
        v[i] = ok ? bf2f(src[(size_t)(rowb + zw) * 256]) : 0.f;
      }
      const float* wp = &wr[kd * 9 + kh * 3];
      a0 = fmaf(v[0], wp[0], fmaf(v[1], wp[1], fmaf(v[2], wp[2], a0)));
      a1 = fmaf(v[1], wp[0], fmaf(v[2], wp[1], fmaf(v[3], wp[2], a1)));
      a2 = fmaf(v[2], wp[0], fmaf(v[3], wp[1], fmaf(v[4], wp[2], a2)));
      a3 = fmaf(v[3], wp[0], fmaf(v[4], wp[1], fmaf(v[5], wp[2], a3)));
    }
  }
  dst[(size_t)(n + 0) * 512] = f2bf(a0);
  dst[(size_t)(n + 1) * 512] = f2bf(a1);
  dst[(size_t)(n + 2) * 512] = f2bf(a2);
  dst[(size_t)(n + 3) * 512] = f2bf(a3);
}

// ---------------------------------------------------------------- L4: fused gathered-K projection + V^T build
// bx < 128: one 16(key)x16(j) MFMA tile per wave, operands straight from global.
// bx >= 128: V^T (+ones row), keys permuted by kappa for the PV A-fragment.
__global__ void __launch_bounds__(256) k_kgvt(const unsigned short* __restrict__ xkv_t,
                                              const unsigned short* __restrict__ wk_t,
                                              const float* __restrict__ bkv,
                                              const int* __restrict__ map,
                                              const unsigned short* __restrict__ v_nc,
                                              unsigned short* __restrict__ kg,
                                              unsigned short* __restrict__ vt) {
  int b = blockIdx.z;
  int bx = blockIdx.x;
  int t = threadIdx.x;
  if (bx >= 128) {
    int h = bx - 128;
    int bh = b * 32 + h;
    unsigned short* dst = vt + (size_t)bh * 16 * 512;
    for (int i = t; i < 512; i += 256) dst[8 * 512 + i] = 0x3F80;     // 1.0 bf16
    for (int i = t; i < 512 * 7; i += 256) dst[9 * 512 + i] = 0;
    const int* ib = map + b * KTOP;
    for (int kk = t; kk < 512; kk += 256) {
      uint4 v = *(const uint4*)&v_nc[((size_t)b * NV + ib[kk]) * 256 + h * 8];
      unsigned short tmp[8];
      *(uint4*)tmp = v;
      int kc = kk >> 5, ka = kk & 31;
      int s = (ka < 16) ? ((ka >> 2) * 8 + (ka & 3))
                        : (((ka - 16) >> 2) * 8 + (ka & 3) + 4);
      int col = kc * 32 + s;
#pragma unroll
      for (int d = 0; d < 8; ++d) dst[d * 512 + col] = tmp[d];
    }
    return;
  }
  const float kscale = 0.35355339059327373f * 1.4426950408889634f;  // 1/sqrt(8)*log2(e)
  int wave = t >> 6, lane = t & 63;
  int l15 = lane & 15, quad = lane >> 4;
  int tile_id = bx * 4 + wave;                 // 0..511
  int kt = tile_id & 31, jt = tile_id >> 5;    // 32 key-tiles x 16 j-tiles
  int m0 = kt * 16, j0 = jt * 16;
  int nrow = map[b * KTOP + m0 + l15];         // gathered key row for this lane
  const unsigned short* Arow = wk_t + (size_t)(j0 + l15) * 256 + quad * 8;
  const unsigned short* Brow = xkv_t + (size_t)b * NV * 256 + (size_t)nrow * 256 + quad * 8;
  f32x4 acc = {0.f, 0.f, 0.f, 0.f};
#pragma unroll
  for (int s = 0; s < 8; ++s) {
    bf16x8 af = *(const bf16x8*)&Arow[s * 32];
    bf16x8 bf = *(const bf16x8*)&Brow[s * 32];
    acc = __builtin_amdgcn_mfma_f32_16x16x32_bf16(af, bf, acc, 0, 0, 0);
  }
  int h = (j0 >> 3) + (quad >> 1), d0b = (quad & 1) * 4;
  int jb = j0 + quad * 4;
  float4 b4 = *(const float4*)&bkv[jb];
  int m = m0 + l15;
  float v0 = (acc[0] + b4.x) * kscale;
  float v1 = (acc[1] + b4.y) * kscale;
  float v2 = (acc[2] + b4.z) * kscale;
  float v3 = (acc[3] + b4.w) * kscale;
  *(uint2*)&kg[((size_t)(b * 32 + h) * KTOP + m) * 8 + d0b] =
      make_uint2(pack2(v0, v1), pack2(v2, v3));
}

// ---------------------------------------------------------------- L5: MFMA flash attention, swapped-QK, LDS-free
__global__ void __launch_bounds__(256) k_fattn(const unsigned short* __restrict__ qh,
                                               const unsigned short* __restrict__ kg,
                                               const unsigned short* __restrict__ vt,
                                               unsigned short* __restrict__ aoydw) {
  int bh = blockIdx.x;
  int b = bh >> 5, h = bh & 31;
  int t = threadIdx.x, wave = t >> 6, lane = t & 63;
  int l15 = lane & 15, quad = lane >> 4;
  int n0 = blockIdx.y * 128 + wave * 32;       // 32 queries per wave
  bf16x8 q0 = {}, q1 = {};                     // B-operand: n=query, k=dim (quad 0 only)
  if (quad == 0) {
    q0 = *(const bf16x8*)&qh[((size_t)bh * NV + n0 + l15) * 8];
    q1 = *(const bf16x8*)&qh[((size_t)bh * NV + n0 + 16 + l15) * 8];
  }
  const unsigned short* kbase = kg + (size_t)bh * KTOP * 8;
  const unsigned short* vbase = vt + (size_t)bh * 16 * 512;
  f32x4 acc0 = {0.f, 0.f, 0.f, 0.f}, acc1 = {0.f, 0.f, 0.f, 0.f};
  bf16x8 kA0 = {}, kA1 = {};                   // A-operand: m=key, k=dim (quad 0 only)
  if (quad == 0) {
    kA0 = *(const bf16x8*)&kbase[(size_t)l15 * 8];
    kA1 = *(const bf16x8*)&kbase[(size_t)(16 + l15) * 8];
  }
  for (int kc = 0; kc < 16; ++kc) {            // 32 keys per iteration
    bf16x8 nA0 = {}, nA1 = {};                 // prefetch next K chunk
    if (quad == 0 && kc < 15) {
      nA0 = *(const bf16x8*)&kbase[(size_t)(kc * 32 + 32 + l15) * 8];
      nA1 = *(const bf16x8*)&kbase[(size_t)(kc * 32 + 48 + l15) * 8];
    }
    bf16x8 bV = *(const bf16x8*)&vbase[(size_t)l15 * 512 + kc * 32 + quad * 8];
    f32x4 z = {0.f, 0.f, 0.f, 0.f};
    // D: col=query=l15, row=key=quad*4+r  -> P already in PV A-frag layout
    f32x4 s00 = __builtin_amdgcn_mfma_f32_16x16x32_bf16(kA0, q0, z, 0, 0, 0);
    f32x4 s01 = __builtin_amdgcn_mfma_f32_16x16x32_bf16(kA1, q0, z, 0, 0, 0);
    f32x4 s10 = __builtin_amdgcn_mfma_f32_16x16x32_bf16(kA0, q1, z, 0, 0, 0);
    f32x4 s11 = __builtin_amdgcn_mfma_f32_16x16x32_bf16(kA1, q1, z, 0, 0, 0);
    uint4 P0, P1;
    P0.x = packtrunc(__builtin_amdgcn_exp2f(s00[0]), __builtin_amdgcn_exp2f(s00[1]));
    P0.y = packtrunc(__builtin_amdgcn_exp2f(s00[2]), __builtin_amdgcn_exp2f(s00[3]));
    P0.z = packtrunc(__builtin_amdgcn_exp2f(s01[0]), __builtin_amdgcn_exp2f(s01[1]));
    P0.w = packtrunc(__builtin_amdgcn_exp2f(s01[2]), __builtin_amdgcn_exp2f(s01[3]));
    P1.x = packtrunc(__builtin_amdgcn_exp2f(s10[0]), __builtin_amdgcn_exp2f(s10[1]));
    P1.y = packtrunc(__builtin_amdgcn_exp2f(s10[2]), __builtin_amdgcn_exp2f(s10[3]));
    P1.z = packtrunc(__builtin_amdgcn_exp2f(s11[0]), __builtin_amdgcn_exp2f(s11[1]));
    P1.w = packtrunc(__builtin_amdgcn_exp2f(s11[2]), __builtin_amdgcn_exp2f(s11[3]));
    acc0 = __builtin_amdgcn_mfma_f32_16x16x32_bf16(*(bf16x8*)&P0, bV, acc0, 0, 0, 0);
    acc1 = __builtin_amdgcn_mfma_f32_16x16x32_bf16(*(bf16x8*)&P1, bV, acc1, 0, 0, 0);
    kA0 = nA0; kA1 = nA1;
  }
#pragma unroll
  for (int tq = 0; tq < 2; ++tq) {
    f32x4 a = tq ? acc1 : acc0;
#pragma unroll
    for (int r = 0; r < 4; ++r) {
      float se = __shfl(a[r], quad * 16 + 8);  // denominator from ones-row col (l15=8)
      float o = a[r] * (1.0f / se);
      if (l15 < 8) {
        int n = n0 + tq * 16 + quad * 4 + r;
        aoydw[((size_t)b * NV + n) * 512 + h * 8 + l15] = f2bf(o);
      }
    }
  }
}

// ---------------------------------------------------------------- L6: final GEMM K=512, MFMA bf16
__global__ void __launch_bounds__(256) k_final(const unsigned short* __restrict__ aoydw,
                                               const unsigned short* __restrict__ wcat,
                                               const float* __restrict__ bproj,
                                               const float* __restrict__ bpw,
                                               float* __restrict__ out) {
  __shared__ unsigned short Als[64 * 40];
  __shared__ unsigned short Bls[128 * 40];
  int n0 = blockIdx.x * 64, j0 = blockIdx.y * 128, b = blockIdx.z;
  int t = threadIdx.x;
  int wave = t >> 6, lane = t & 63;
  int l15 = lane & 15, q = lane >> 4, q8 = q * 8;
  int wn = (wave >> 1) * 32, wjj = (wave & 1) * 64;
  f32x4 acc[2][4] = {};
  const unsigned short* Abase = aoydw + (size_t)b * NV * 512;
  int ar = t >> 2, aq = t & 3;
  int br = t >> 1, bhh = t & 1;
  for (int c0 = 0; c0 < 512; c0 += 32) {
    __syncthreads();
    *(uint4*)&Als[ar * 40 + aq * 8] =
        *(const uint4*)&Abase[(size_t)(n0 + ar) * 512 + c0 + aq * 8];
    const unsigned short* sb = &wcat[(size_t)(j0 + br) * 512 + c0 + bhh * 16];
    *(uint4*)&Bls[br * 40 + bhh * 16]     = *(const uint4*)&sb[0];
    *(uint4*)&Bls[br * 40 + bhh * 16 + 8] = *(const uint4*)&sb[8];
    __syncthreads();
    bf16x8 af[2], bf[4];
#pragma unroll
    for (int mt = 0; mt < 2; ++mt)
      af[mt] = *(const bf16x8*)&Als[(wn + mt * 16 + l15) * 40 + q8];
#pragma unroll
    for (int nt = 0; nt < 4; ++nt)
      bf[nt] = *(const bf16x8*)&Bls[(wjj + nt * 16 + l15) * 40 + q8];
#pragma unroll
    for (int mt = 0; mt < 2; ++mt)
#pragma unroll
      for (int nt = 0; nt < 4; ++nt)
        acc[mt][nt] = __builtin_amdgcn_mfma_f32_16x16x32_bf16(af[mt], bf[nt], acc[mt][nt], 0, 0, 0);
  }
#pragma unroll
  for (int nt = 0; nt < 4; ++nt) {
    int j = j0 + wjj + nt * 16 + l15;
    float bl = bproj[j] + bpw[j];
#pragma unroll
    for (int mt = 0; mt < 2; ++mt) {
      int n = n0 + wn + mt * 16 + q * 4;
      float4 r = make_float4(acc[mt][nt][0] + bl, acc[mt][nt][1] + bl,
                             acc[mt][nt][2] + bl, acc[mt][nt][3] + bl);
      *(float4*)&out[(size_t)(b * 256 + j) * NV + n] = r;
    }
  }
}

// ---------------------------------------------------------------- launch
extern "C" void kernel_launch(void* const* d_in, const int* in_sizes, int n_in,
                              void* d_out, int out_size, void* d_ws, size_t ws_size,
                              hipStream_t stream) {
  const float* x_kv   = (const float*)d_in[0];
  const float* x_q    = (const float*)d_in[1];
  const float* w_spa  = (const float*)d_in[2];
  const float* w_kv   = (const float*)d_in[3];
  const float* b_kv   = (const float*)d_in[4];
  const float* w_q    = (const float*)d_in[5];
  const float* b_q    = (const float*)d_in[6];
  const float* w_proj = (const float*)d_in[7];
  const float* b_proj = (const float*)d_in[8];
  const float* w_dw   = (const float*)d_in[9];
  const float* b_dw   = (const float*)d_in[10];
  const float* w_pw   = (const float*)d_in[11];
  const float* b_pw   = (const float*)d_in[12];
  float* out = (float*)d_out;

  const size_t MB = 1024 * 1024;
  char* ws = (char*)d_ws;
  unsigned short* xkv_t = (unsigned short*)(ws);                 // 4 MB (b,n,c) bf16
  unsigned short* xq_t  = (unsigned short*)(ws + 4 * MB);        // 4 MB
  unsigned short* v_nc  = (unsigned short*)(ws + 8 * MB);        // 4 MB (b,n,c) bf16
  unsigned short* qh    = (unsigned short*)(ws + 12 * MB);       // 4 MB (b,h,n,8) bf16
  unsigned short* aoydw = (unsigned short*)(ws + 16 * MB);       // 8 MB (b,n,512) bf16
  unsigned short* kg    = (unsigned short*)(ws + 24 * MB);       // 512 KB (bh,512,8) bf16 pre-scaled
  unsigned short* vt    = (unsigned short*)(ws + 24 * MB + 512 * 1024);  // 1 MB (bh,16,512) bf16
  unsigned short* wv_t  = (unsigned short*)(ws + 26 * MB);               // 128 KB
  unsigned short* wq_t  = (unsigned short*)(ws + 26 * MB + 131072);      // 128 KB
  unsigned short* wcat  = (unsigned short*)(ws + 26 * MB + 262144);      // 256 KB
  unsigned short* wk_t  = (unsigned short*)(ws + 26 * MB + 524288);      // 128 KB
  float*          avgmx = (float*)(ws + 27 * MB);                        //  64 KB
  float*          scores= (float*)(ws + 27 * MB + 65536);               //  32 KB
  int*            idx   = (int*)  (ws + 27 * MB + 98304);               //   4 KB

  k_stage1<<<dim3(64, 4, 10), 256, 0, stream>>>(x_kv, x_q, w_kv, w_q, w_proj, w_pw,
                                                xkv_t, xq_t, avgmx, wv_t, wq_t, wcat, wk_t);
  k_stage2<<<dim3(32, 2, 5), 256, 0, stream>>>(xkv_t, xq_t, wv_t, wq_t, b_kv, b_q,
                                               avgmx, w_spa, v_nc, qh, scores);
  k_stage3<<<dim3(257, 1, 2), 1024, 0, stream>>>(scores, idx, v_nc, w_dw, b_dw, aoydw);
  k_kgvt<<<dim3(160, 1, 2), 256, 0, stream>>>(xkv_t, wk_t, b_kv, idx, v_nc, kg, vt);
  k_fattn<<<dim3(64, 32), 256, 0, stream>>>(qh, kg, vt, aoydw);
  k_final<<<dim3(64, 2, 2), 256, 0, stream>>>(aoydw, wcat, b_proj, b_pw, out);
}

// Round 5
// 182.427 us; speedup vs baseline: 1.4294x; 1.0310x over previous
//
#include <hip/hip_runtime.h>
#include <hip/hip_bf16.h>

typedef short bf16x8 __attribute__((ext_vector_type(8)));
typedef float f32x4 __attribute__((ext_vector_type(4)));

constexpr int CN = 256, NV = 4096, KTOP = 512;

static __device__ __forceinline__ unsigned short f2bf(float f) {
  __hip_bfloat16 h = __float2bfloat16(f);
  return *(unsigned short*)&h;
}
static __device__ __forceinline__ unsigned pack2(float a, float b) {
  return (unsigned)f2bf(a) | ((unsigned)f2bf(b) << 16);
}
static __device__ __forceinline__ float bf2f(unsigned short u) {
  return __uint_as_float(((unsigned)u) << 16);
}
// truncated-bf16 pack: lo16 = bf16(a), hi16 = bf16(b)  (2 VALU, no cvt)
static __device__ __forceinline__ unsigned packtrunc(float a, float b) {
  return (__float_as_uint(a) >> 16) | (__float_as_uint(b) & 0xFFFF0000u);
}

// ---------------------------------------------------------------- L1: transpose-cast + channel-reduce + weight-prep
// z = 0,1: x_kv batches -> xkv_t ; z = 2,3: x_q batches -> xq_t  (float4 loads)
// z = 4: channel mean/max, 4 columns/thread via float4 (per-column order unchanged)
// z = 5..9: weight prep roles 0..4 (only bx<4 && by<4 active)
__global__ void __launch_bounds__(256) k_stage1(const float* __restrict__ xkv,
                                                const float* __restrict__ xq,
                                                const float* __restrict__ wkv,
                                                const float* __restrict__ wq,
                                                const float* __restrict__ wproj,
                                                const float* __restrict__ wpw,
                                                unsigned short* __restrict__ xkv_t,
                                                unsigned short* __restrict__ xq_t,
                                                float* __restrict__ avgmx,
                                                unsigned short* __restrict__ wv_t,
                                                unsigned short* __restrict__ wq_t,
                                                unsigned short* __restrict__ wcat,
                                                unsigned short* __restrict__ wk_t) {
  __shared__ float tile[64 * 68];
  int z = blockIdx.z;
  int t = threadIdx.x;
  if (z == 4) {  // channel mean/max role: 128 n per block, float4 lanes
    __shared__ float4 ssum4[256], smax4[256];
    int blk = blockIdx.y * 64 + blockIdx.x;
    if (blk >= 64) return;
    int b = blk >> 5, n0r = (blk & 31) * 128;
    int cg = t >> 5, nl = t & 31;
    int n = n0r + nl * 4;
    const float* p = xkv + (size_t)b * CN * NV + (size_t)cg * 32 * NV + n;
    float4 s4 = make_float4(0.f, 0.f, 0.f, 0.f);
    float4 m4 = make_float4(-1e30f, -1e30f, -1e30f, -1e30f);
    for (int i = 0; i < 32; ++i) {
      float4 v = *(const float4*)&p[(size_t)i * NV];
      s4.x += v.x; s4.y += v.y; s4.z += v.z; s4.w += v.w;
      m4.x = fmaxf(m4.x, v.x); m4.y = fmaxf(m4.y, v.y);
      m4.z = fmaxf(m4.z, v.z); m4.w = fmaxf(m4.w, v.w);
    }
    ssum4[t] = s4; smax4[t] = m4;
    __syncthreads();
    if (cg == 0) {
      for (int g = 1; g < 8; ++g) {
        float4 o = ssum4[g * 32 + nl], x = smax4[g * 32 + nl];
        s4.x += o.x; s4.y += o.y; s4.z += o.z; s4.w += o.w;
        m4.x = fmaxf(m4.x, x.x); m4.y = fmaxf(m4.y, x.y);
        m4.z = fmaxf(m4.z, x.z); m4.w = fmaxf(m4.w, x.w);
      }
      float4 a4 = make_float4(s4.x * (1.0f / 256.0f), s4.y * (1.0f / 256.0f),
                              s4.z * (1.0f / 256.0f), s4.w * (1.0f / 256.0f));
      *(float4*)&avgmx[(size_t)(b * 2 + 0) * NV + n] = a4;
      *(float4*)&avgmx[(size_t)(b * 2 + 1) * NV + n] = m4;
    }
    return;
  }
  if (z >= 5) {  // weight-prep roles
    if (blockIdx.x >= 4 || blockIdx.y >= 4) return;
    int role = z - 5;
    int j0 = blockIdx.x * 64, c0 = blockIdx.y * 64;
    if (role == 3) {  // wpw (j,c) straight cast into wcat cols 256..512
      int j = t >> 2, part = t & 3;
      const float* s = &wpw[(size_t)(j0 + j) * 256 + c0 + part * 16];
      unsigned w[8];
#pragma unroll
      for (int k = 0; k < 8; ++k) w[k] = pack2(s[2 * k], s[2 * k + 1]);
      uint4* p = (uint4*)&wcat[(size_t)(j0 + j) * 512 + 256 + c0 + part * 16];
      p[0] = make_uint4(w[0], w[1], w[2], w[3]);
      p[1] = make_uint4(w[4], w[5], w[6], w[7]);
      return;
    }
    const float* src; int srcLD, srcOff; unsigned short* dst; int dstLD;
    if (role == 0)      { src = wkv;   srcLD = 512; srcOff = 256; dst = wv_t; dstLD = 256; }
    else if (role == 1) { src = wq;    srcLD = 256; srcOff = 0;   dst = wq_t; dstLD = 256; }
    else if (role == 4) { src = wkv;   srcLD = 512; srcOff = 0;   dst = wk_t; dstLD = 256; }
    else                { src = wproj; srcLD = 256; srcOff = 0;   dst = wcat; dstLD = 512; }
    for (int i = 0; i < 16; ++i) {
      int id = i * 256 + t, c = id >> 6, j = id & 63;
      tile[c * 65 + j] = src[(size_t)(c0 + c) * srcLD + srcOff + j0 + j];
    }
    __syncthreads();
    int j = t & 63, part = t >> 6;
    unsigned w[8];
#pragma unroll
    for (int k = 0; k < 8; ++k)
      w[k] = pack2(tile[(part * 16 + 2 * k) * 65 + j], tile[(part * 16 + 2 * k + 1) * 65 + j]);
    uint4* p = (uint4*)&dst[(size_t)(j0 + j) * dstLD + c0 + part * 16];
    p[0] = make_uint4(w[0], w[1], w[2], w[3]);
    p[1] = make_uint4(w[4], w[5], w[6], w[7]);
    return;
  }
  // transpose-cast roles: float4 loads (16B/lane), LDS stride 68 keeps stores aligned
  int b = z & 1;
  const float* s = (z < 2 ? xkv : xq) + (size_t)b * CN * NV;
  unsigned short* d = (z < 2 ? xkv_t : xq_t) + (size_t)b * NV * 256;
  int c0 = blockIdx.y * 64, n0 = blockIdx.x * 64;
#pragma unroll
  for (int i = 0; i < 4; ++i) {
    int id = i * 256 + t, c = id >> 4, nq = (id & 15) * 4;
    *(float4*)&tile[c * 68 + nq] = *(const float4*)&s[(size_t)(c0 + c) * NV + n0 + nq];
  }
  __syncthreads();
  int n = t & 63, part = t >> 6;
  unsigned w[8];
#pragma unroll
  for (int k = 0; k < 8; ++k)
    w[k] = pack2(tile[(part * 16 + 2 * k) * 68 + n], tile[(part * 16 + 2 * k + 1) * 68 + n]);
  uint4* p = (uint4*)&d[(size_t)(n0 + n) * 256 + c0 + part * 16];
  p[0] = make_uint4(w[0], w[1], w[2], w[3]);
  p[1] = make_uint4(w[4], w[5], w[6], w[7]);
}

// ---------------------------------------------------------------- L2: fused V+Q projection (MFMA) + spa conv
// round-16: qv tile 128n x 64j -> grid (32,4,4roles) = 512 blocks = 2/CU
// (was 256 = 1/CU, all staging latency exposed). Same c0-ascending K=32
// accumulation -> bitwise-identical outputs. z=4 (first 64 ids): spa conv.
__global__ void __launch_bounds__(256) k_stage2(const unsigned short* __restrict__ xkv_t,
                                                const unsigned short* __restrict__ xq_t,
                                                const unsigned short* __restrict__ wv_t,
                                                const unsigned short* __restrict__ wq_t,
                                                const float* __restrict__ bkv,
                                                const float* __restrict__ bq,
                                                const float* __restrict__ avgmx,
                                                const float* __restrict__ wspa,
                                                unsigned short* __restrict__ v_nc,
                                                unsigned short* __restrict__ qh,
                                                float* __restrict__ scores) {
  __shared__ alignas(16) char smem[35520];   // max(qv 15360, spa 32768+2744)
  int z = blockIdx.z;
  int t = threadIdx.x;
  if (z == 4) {  // ---- spa role
    int id = blockIdx.y * 32 + blockIdx.x;
    if (id >= 64) return;
    float* vol = (float*)smem;
    float* ws = (float*)(smem + 32768);
    int b = id >> 5, chunk = id & 31;
    for (int i = t; i < 8192; i += 256) vol[i] = avgmx[b * 8192 + i];
    for (int i = t; i < 686; i += 256) ws[i] = wspa[i];
    __syncthreads();
    int ci = t & 1;
    int n = chunk * 128 + (t >> 1);
    int d = n >> 8, h = (n >> 4) & 15, w = n & 15;
    const float* vb = vol + ci * 4096;
    const float* wb = ws + ci * 343;
    float acc = 0.f;
    for (int kd = 0; kd < 7; ++kd) {
      int zd = d - 3 + kd; if ((unsigned)zd >= 16u) continue;
      for (int kh = 0; kh < 7; ++kh) {
        int zh = h - 3 + kh; if ((unsigned)zh >= 16u) continue;
        const float* row = vb + zd * 256 + zh * 16;
        const float* wr = wb + kd * 49 + kh * 7;
#pragma unroll
        for (int kw = 0; kw < 7; ++kw) {
          int zw = w - 3 + kw;
          if ((unsigned)zw < 16u) acc += row[zw] * wr[kw];
        }
      }
    }
    acc += __shfl_xor(acc, 1);
    if (ci == 0) scores[b * NV + n] = 1.0f / (1.0f + expf(-acc));
    return;
  }
  // ---- qv role: 128n x 64j per block
  unsigned short* Als = (unsigned short*)smem;     // 64 x 40
  unsigned short* Bls = Als + 64 * 40;             // 128 x 40
  int role = z;
  int b = role & 1;
  bool isQ = role >= 2;
  const unsigned short* A = isQ ? wq_t : wv_t;                              // (j=256, c=256)
  const unsigned short* B = (isQ ? xq_t : xkv_t) + (size_t)b * NV * 256;    // (n, c)
  const float* bias = isQ ? bq : (bkv + 256);
  int n0 = blockIdx.x * 128, j0 = blockIdx.y * 64;
  int wave = t >> 6, lane = t & 63;
  int l15 = lane & 15, q = lane >> 4, q8 = q * 8;
  int wj = (wave >> 1) * 32, wn = (wave & 1) * 64;
  f32x4 acc[2][4] = {};
  int arA = t >> 2, ahA = t & 3;
  int brB = t >> 1, bhB = t & 1;
  for (int c0 = 0; c0 < 256; c0 += 32) {
    __syncthreads();
    *(uint4*)&Als[arA * 40 + ahA * 8] =
        *(const uint4*)&A[(size_t)(j0 + arA) * 256 + c0 + ahA * 8];
    const unsigned short* sb = &B[(size_t)(n0 + brB) * 256 + c0 + bhB * 16];
    *(uint4*)&Bls[brB * 40 + bhB * 16]     = *(const uint4*)&sb[0];
    *(uint4*)&Bls[brB * 40 + bhB * 16 + 8] = *(const uint4*)&sb[8];
    __syncthreads();
    bf16x8 af[2], bf[4];
#pragma unroll
    for (int mt = 0; mt < 2; ++mt)
      af[mt] = *(const bf16x8*)&Als[(wj + mt * 16 + l15) * 40 + q8];
#pragma unroll
    for (int nt = 0; nt < 4; ++nt)
      bf[nt] = *(const bf16x8*)&Bls[(wn + nt * 16 + l15) * 40 + q8];
#pragma unroll
    for (int mt = 0; mt < 2; ++mt)
#pragma unroll
      for (int nt = 0; nt < 4; ++nt)
        acc[mt][nt] = __builtin_amdgcn_mfma_f32_16x16x32_bf16(af[mt], bf[nt], acc[mt][nt], 0, 0, 0);
  }
#pragma unroll
  for (int mt = 0; mt < 2; ++mt) {
    int jb = j0 + wj + mt * 16 + q * 4;          // 4 consecutive j
    float4 b4 = *(const float4*)&bias[jb];
#pragma unroll
    for (int nt = 0; nt < 4; ++nt) {
      int n = n0 + wn + nt * 16 + l15;
      float v0 = acc[mt][nt][0] + b4.x;
      float v1 = acc[mt][nt][1] + b4.y;
      float v2 = acc[mt][nt][2] + b4.z;
      float v3 = acc[mt][nt][3] + b4.w;
      uint2 pk = make_uint2(pack2(v0, v1), pack2(v2, v3));
      if (isQ) {
        int h = jb >> 3, d0 = jb & 7;            // jb%4==0 -> within one head
        *(uint2*)&qh[((size_t)(b * 32 + h) * NV + n) * 8 + d0] = pk;
      } else {
        *(uint2*)&v_nc[((size_t)b * NV + n) * 256 + jb] = pk;
      }
    }
  }
}

// ---------------------------------------------------------------- L3: depthwise conv + top-512 radix select
// bx < 256: dw role (16 n x 256 c per block, 1024 thr) ; bx == 256: topk for batch z
__global__ void __launch_bounds__(1024) k_stage3(const float* __restrict__ scores,
                                                 int* __restrict__ idx,
                                                 const unsigned short* __restrict__ v_nc,
                                                 const float* __restrict__ wdw,
                                                 const float* __restrict__ bdw,
                                                 unsigned short* __restrict__ aoydw) {
  int b = blockIdx.z;
  int bx = blockIdx.x;
  int tid = threadIdx.x;
  if (bx == 256) {  // ---- topk role (unchanged radix-select, 1024 thr)
    __shared__ unsigned sv[4096];
    __shared__ int sB;
    __shared__ unsigned sSub, scnt;
    __shared__ unsigned hist[256];
    __shared__ int wsum[16];
    for (int t = tid; t < 4096; t += 1024) sv[t] = __float_as_uint(scores[b * NV + t]);
    if (tid == 0) scnt = 0;
    unsigned prefix = 0;
    int r = 512;
    for (int shift = 24; shift >= 0; shift -= 8) {
      if (tid < 256) hist[tid] = 0;
      __syncthreads();
      unsigned maskhi = (shift == 24) ? 0u : (0xFFFFFFFFu << (shift + 8));
      for (int i = 0; i < 4; ++i) {
        unsigned v = sv[tid + i * 1024];
        if ((v & maskhi) == prefix) atomicAdd(&hist[(v >> shift) & 255], 1u);
      }
      __syncthreads();
      if (tid < 64) {
        int lane = tid;
        unsigned h0 = hist[lane * 4 + 0], h1 = hist[lane * 4 + 1];
        unsigned h2 = hist[lane * 4 + 2], h3 = hist[lane * 4 + 3];
        unsigned s = h0 + h1 + h2 + h3;
        for (int off = 1; off < 64; off <<= 1) {
          unsigned y = __shfl_down(s, off);
          if (lane + off < 64) s += y;
        }
        unsigned tail = __shfl_down(s, 1);
        if (lane == 63) tail = 0;
        unsigned s3 = tail + h3, s2 = s3 + h2, s1 = s2 + h1, s0 = s1 + h0;
        unsigned sx[5] = {s0, s1, s2, s3, tail};
#pragma unroll
        for (int i = 0; i < 4; ++i)
          if (sx[i] >= (unsigned)r && sx[i + 1] < (unsigned)r) { sB = lane * 4 + i; sSub = sx[i + 1]; }
      }
      __syncthreads();
      prefix |= ((unsigned)sB) << shift;
      r -= (int)sSub;
      __syncthreads();
    }
    unsigned vstar = prefix;
    for (int i = 0; i < 4; ++i) {
      int t = tid * 4 + i;
      if (sv[t] > vstar) { unsigned p = atomicAdd(&scnt, 1u); idx[b * KTOP + p] = t; }
    }
    __syncthreads();
    int base = (int)scnt;
    int loc = 0;
    for (int i = 0; i < 4; ++i) loc += (sv[tid * 4 + i] == vstar);
    int lane = tid & 63, w = tid >> 6;
    int x = loc;
    for (int off = 1; off < 64; off <<= 1) {
      int y = __shfl_up(x, off);
      if (lane >= off) x += y;
    }
    if (lane == 63) wsum[w] = x;
    __syncthreads();
    int wbase = 0;
    for (int i = 0; i < w; ++i) wbase += wsum[i];
    int excl = wbase + x - loc;
    for (int i = 0; i < 4; ++i) {
      int t = tid * 4 + i;
      if (sv[t] == vstar) {
        if (excl < r) idx[b * KTOP + base + excl] = t;
        ++excl;
      }
    }
    return;
  }
  // ---- dw role: 16 consecutive n x 256 c per block
  int c = tid & 255;
  float wr[27];
#pragma unroll
  for (int i = 0; i < 27; ++i) wr[i] = wdw[c * 27 + i];
  float bias = bdw[c];
  const unsigned short* src = v_nc + (size_t)b * NV * 256 + c;
  unsigned short* dst = aoydw + (size_t)b * NV * 512 + 256 + c;
  int n = bx * 16 + (tid >> 8) * 4;          // 4 consecutive n (same h-row) share taps
  int d = n >> 8, h = (n >> 4) & 15, w = n & 15;
  float a0 = bias, a1 = bias, a2 = bias, a3 = bias;
#pragma unroll
  for (int kd = 0; kd < 3; ++kd) {
    int zd = d - 1 + kd; bool okd = (unsigned)zd < 16u;
#pragma unroll
    for (int kh = 0; kh < 3; ++kh) {
      int zh = h - 1 + kh; bool okh = okd && ((unsigned)zh < 16u);
      int rowb = zd * 256 + zh * 16;
      float v[6];
#pragma unroll
      for (int i = 0; i < 6; ++i) {
        int zw = w - 1 + i;
        bool ok = okh && ((unsigned)zw < 16u);   // wave-uniform mask
        v[i] = ok ? bf2f(src[(size_t)(rowb + zw) * 256]) : 0.f;
      }
      const float* wp = &wr[kd * 9 + kh * 3];
      a0 = fmaf(v[0], wp[0], fmaf(v[1], wp[1], fmaf(v[2], wp[2], a0)));
      a1 = fmaf(v[1], wp[0], fmaf(v[2], wp[1], fmaf(v[3], wp[2], a1)));
      a2 = fmaf(v[2], wp[0], fmaf(v[3], wp[1], fmaf(v[4], wp[2], a2)));
      a3 = fmaf(v[3], wp[0], fmaf(v[4], wp[1], fmaf(v[5], wp[2], a3)));
    }
  }
  dst[(size_t)(n + 0) * 512] = f2bf(a0);
  dst[(size_t)(n + 1) * 512] = f2bf(a1);
  dst[(size_t)(n + 2) * 512] = f2bf(a2);
  dst[(size_t)(n + 3) * 512] = f2bf(a3);
}

// ---------------------------------------------------------------- L4: fused gathered-K projection + V^T build
// bx < 128: one 16(key)x16(j) MFMA tile per wave, operands straight from global.
// bx >= 128: V^T (+ones row), keys permuted by kappa for the PV A-fragment.
__global__ void __launch_bounds__(256) k_kgvt(const unsigned short* __restrict__ xkv_t,
                                              const unsigned short* __restrict__ wk_t,
                                              const float* __restrict__ bkv,
                                              const int* __restrict__ map,
                                              const unsigned short* __restrict__ v_nc,
                                              unsigned short* __restrict__ kg,
                                              unsigned short* __restrict__ vt) {
  int b = blockIdx.z;
  int bx = blockIdx.x;
  int t = threadIdx.x;
  if (bx >= 128) {
    int h = bx - 128;
    int bh = b * 32 + h;
    unsigned short* dst = vt + (size_t)bh * 16 * 512;
    for (int i = t; i < 512; i += 256) dst[8 * 512 + i] = 0x3F80;     // 1.0 bf16
    for (int i = t; i < 512 * 7; i += 256) dst[9 * 512 + i] = 0;
    const int* ib = map + b * KTOP;
    for (int kk = t; kk < 512; kk += 256) {
      uint4 v = *(const uint4*)&v_nc[((size_t)b * NV + ib[kk]) * 256 + h * 8];
      unsigned short tmp[8];
      *(uint4*)tmp = v;
      int kc = kk >> 5, ka = kk & 31;
      int s = (ka < 16) ? ((ka >> 2) * 8 + (ka & 3))
                        : (((ka - 16) >> 2) * 8 + (ka & 3) + 4);
      int col = kc * 32 + s;
#pragma unroll
      for (int d = 0; d < 8; ++d) dst[d * 512 + col] = tmp[d];
    }
    return;
  }
  const float kscale = 0.35355339059327373f * 1.4426950408889634f;  // 1/sqrt(8)*log2(e)
  int wave = t >> 6, lane = t & 63;
  int l15 = lane & 15, quad = lane >> 4;
  int tile_id = bx * 4 + wave;                 // 0..511
  int kt = tile_id & 31, jt = tile_id >> 5;    // 32 key-tiles x 16 j-tiles
  int m0 = kt * 16, j0 = jt * 16;
  int nrow = map[b * KTOP + m0 + l15];         // gathered key row for this lane
  const unsigned short* Arow = wk_t + (size_t)(j0 + l15) * 256 + quad * 8;
  const unsigned short* Brow = xkv_t + (size_t)b * NV * 256 + (size_t)nrow * 256 + quad * 8;
  f32x4 acc = {0.f, 0.f, 0.f, 0.f};
#pragma unroll
  for (int s = 0; s < 8; ++s) {
    bf16x8 af = *(const bf16x8*)&Arow[s * 32];
    bf16x8 bf = *(const bf16x8*)&Brow[s * 32];
    acc = __builtin_amdgcn_mfma_f32_16x16x32_bf16(af, bf, acc, 0, 0, 0);
  }
  int h = (j0 >> 3) + (quad >> 1), d0b = (quad & 1) * 4;
  int jb = j0 + quad * 4;
  float4 b4 = *(const float4*)&bkv[jb];
  int m = m0 + l15;
  float v0 = (acc[0] + b4.x) * kscale;
  float v1 = (acc[1] + b4.y) * kscale;
  float v2 = (acc[2] + b4.z) * kscale;
  float v3 = (acc[3] + b4.w) * kscale;
  *(uint2*)&kg[((size_t)(b * 32 + h) * KTOP + m) * 8 + d0b] =
      make_uint2(pack2(v0, v1), pack2(v2, v3));
}

// ---------------------------------------------------------------- L5: MFMA flash attention, swapped-QK, LDS-free
__global__ void __launch_bounds__(256) k_fattn(const unsigned short* __restrict__ qh,
                                               const unsigned short* __restrict__ kg,
                                               const unsigned short* __restrict__ vt,
                                               unsigned short* __restrict__ aoydw) {
  int bh = blockIdx.x;
  int b = bh >> 5, h = bh & 31;
  int t = threadIdx.x, wave = t >> 6, lane = t & 63;
  int l15 = lane & 15, quad = lane >> 4;
  int n0 = blockIdx.y * 128 + wave * 32;       // 32 queries per wave
  bf16x8 q0 = {}, q1 = {};                     // B-operand: n=query, k=dim (quad 0 only)
  if (quad == 0) {
    q0 = *(const bf16x8*)&qh[((size_t)bh * NV + n0 + l15) * 8];
    q1 = *(const bf16x8*)&qh[((size_t)bh * NV + n0 + 16 + l15) * 8];
  }
  const unsigned short* kbase = kg + (size_t)bh * KTOP * 8;
  const unsigned short* vbase = vt + (size_t)bh * 16 * 512;
  f32x4 acc0 = {0.f, 0.f, 0.f, 0.f}, acc1 = {0.f, 0.f, 0.f, 0.f};
  bf16x8 kA0 = {}, kA1 = {};                   // A-operand: m=key, k=dim (quad 0 only)
  if (quad == 0) {
    kA0 = *(const bf16x8*)&kbase[(size_t)l15 * 8];
    kA1 = *(const bf16x8*)&kbase[(size_t)(16 + l15) * 8];
  }
  for (int kc = 0; kc < 16; ++kc) {            // 32 keys per iteration
    bf16x8 nA0 = {}, nA1 = {};                 // prefetch next K chunk
    if (quad == 0 && kc < 15) {
      nA0 = *(const bf16x8*)&kbase[(size_t)(kc * 32 + 32 + l15) * 8];
      nA1 = *(const bf16x8*)&kbase[(size_t)(kc * 32 + 48 + l15) * 8];
    }
    bf16x8 bV = *(const bf16x8*)&vbase[(size_t)l15 * 512 + kc * 32 + quad * 8];
    f32x4 z = {0.f, 0.f, 0.f, 0.f};
    // D: col=query=l15, row=key=quad*4+r  -> P already in PV A-frag layout
    f32x4 s00 = __builtin_amdgcn_mfma_f32_16x16x32_bf16(kA0, q0, z, 0, 0, 0);
    f32x4 s01 = __builtin_amdgcn_mfma_f32_16x16x32_bf16(kA1, q0, z, 0, 0, 0);
    f32x4 s10 = __builtin_amdgcn_mfma_f32_16x16x32_bf16(kA0, q1, z, 0, 0, 0);
    f32x4 s11 = __builtin_amdgcn_mfma_f32_16x16x32_bf16(kA1, q1, z, 0, 0, 0);
    uint4 P0, P1;
    P0.x = packtrunc(__builtin_amdgcn_exp2f(s00[0]), __builtin_amdgcn_exp2f(s00[1]));
    P0.y = packtrunc(__builtin_amdgcn_exp2f(s00[2]), __builtin_amdgcn_exp2f(s00[3]));
    P0.z = packtrunc(__builtin_amdgcn_exp2f(s01[0]), __builtin_amdgcn_exp2f(s01[1]));
    P0.w = packtrunc(__builtin_amdgcn_exp2f(s01[2]), __builtin_amdgcn_exp2f(s01[3]));
    P1.x = packtrunc(__builtin_amdgcn_exp2f(s10[0]), __builtin_amdgcn_exp2f(s10[1]));
    P1.y = packtrunc(__builtin_amdgcn_exp2f(s10[2]), __builtin_amdgcn_exp2f(s10[3]));
    P1.z = packtrunc(__builtin_amdgcn_exp2f(s11[0]), __builtin_amdgcn_exp2f(s11[1]));
    P1.w = packtrunc(__builtin_amdgcn_exp2f(s11[2]), __builtin_amdgcn_exp2f(s11[3]));
    acc0 = __builtin_amdgcn_mfma_f32_16x16x32_bf16(*(bf16x8*)&P0, bV, acc0, 0, 0, 0);
    acc1 = __builtin_amdgcn_mfma_f32_16x16x32_bf16(*(bf16x8*)&P1, bV, acc1, 0, 0, 0);
    kA0 = nA0; kA1 = nA1;
  }
#pragma unroll
  for (int tq = 0; tq < 2; ++tq) {
    f32x4 a = tq ? acc1 : acc0;
#pragma unroll
    for (int r = 0; r < 4; ++r) {
      float se = __shfl(a[r], quad * 16 + 8);  // denominator from ones-row col (l15=8)
      float o = a[r] * (1.0f / se);
      if (l15 < 8) {
        int n = n0 + tq * 16 + quad * 4 + r;
        aoydw[((size_t)b * NV + n) * 512 + h * 8 + l15] = f2bf(o);
      }
    }
  }
}

// ---------------------------------------------------------------- L6: final GEMM K=512, MFMA bf16
// round-16: tile 64n x 64j, BK=64 -> grid (64,4,2) = 512 blocks = 2/CU
// (was 256 = 1/CU) and 8 staging rounds (was 16). kk=0,1 sub-steps keep the
// old 32-c accumulation order -> bitwise identical.
__global__ void __launch_bounds__(256) k_final(const unsigned short* __restrict__ aoydw,
                                               const unsigned short* __restrict__ wcat,
                                               const float* __restrict__ bproj,
                                               const float* __restrict__ bpw,
                                               float* __restrict__ out) {
  __shared__ unsigned short Als[64 * 72];
  __shared__ unsigned short Bls[64 * 72];
  int n0 = blockIdx.x * 64, j0 = blockIdx.y * 64, b = blockIdx.z;
  int t = threadIdx.x;
  int wave = t >> 6, lane = t & 63;
  int l15 = lane & 15, q = lane >> 4, q8 = q * 8;
  int wn = (wave & 1) * 32, wjj = (wave >> 1) * 32;
  f32x4 acc[2][2] = {};
  const unsigned short* Abase = aoydw + (size_t)b * NV * 512;
  int ar = t >> 2, aq = t & 3;
  for (int c0 = 0; c0 < 512; c0 += 64) {
    __syncthreads();
    *(uint4*)&Als[ar * 72 + aq * 8] =
        *(const uint4*)&Abase[(size_t)(n0 + ar) * 512 + c0 + aq * 8];
    *(uint4*)&Als[ar * 72 + 32 + aq * 8] =
        *(const uint4*)&Abase[(size_t)(n0 + ar) * 512 + c0 + 32 + aq * 8];
    *(uint4*)&Bls[ar * 72 + aq * 8] =
        *(const uint4*)&wcat[(size_t)(j0 + ar) * 512 + c0 + aq * 8];
    *(uint4*)&Bls[ar * 72 + 32 + aq * 8] =
        *(const uint4*)&wcat[(size_t)(j0 + ar) * 512 + c0 + 32 + aq * 8];
    __syncthreads();
#pragma unroll
    for (int kk = 0; kk < 2; ++kk) {
      bf16x8 af[2], bf[2];
#pragma unroll
      for (int mt = 0; mt < 2; ++mt)
        af[mt] = *(const bf16x8*)&Als[(wn + mt * 16 + l15) * 72 + kk * 32 + q8];
#pragma unroll
      for (int nt = 0; nt < 2; ++nt)
        bf[nt] = *(const bf16x8*)&Bls[(wjj + nt * 16 + l15) * 72 + kk * 32 + q8];
#pragma unroll
      for (int mt = 0; mt < 2; ++mt)
#pragma unroll
        for (int nt = 0; nt < 2; ++nt)
          acc[mt][nt] = __builtin_amdgcn_mfma_f32_16x16x32_bf16(af[mt], bf[nt], acc[mt][nt], 0, 0, 0);
    }
  }
#pragma unroll
  for (int nt = 0; nt < 2; ++nt) {
    int j = j0 + wjj + nt * 16 + l15;
    float bl = bproj[j] + bpw[j];
#pragma unroll
    for (int mt = 0; mt < 2; ++mt) {
      int n = n0 + wn + mt * 16 + q * 4;
      float4 r = make_float4(acc[mt][nt][0] + bl, acc[mt][nt][1] + bl,
                             acc[mt][nt][2] + bl, acc[mt][nt][3] + bl);
      *(float4*)&out[(size_t)(b * 256 + j) * NV + n] = r;
    }
  }
}

// ---------------------------------------------------------------- launch
extern "C" void kernel_launch(void* const* d_in, const int* in_sizes, int n_in,
                              void* d_out, int out_size, void* d_ws, size_t ws_size,
                              hipStream_t stream) {
  const float* x_kv   = (const float*)d_in[0];
  const float* x_q    = (const float*)d_in[1];
  const float* w_spa  = (const float*)d_in[2];
  const float* w_kv   = (const float*)d_in[3];
  const float* b_kv   = (const float*)d_in[4];
  const float* w_q    = (const float*)d_in[5];
  const float* b_q    = (const float*)d_in[6];
  const float* w_proj = (const float*)d_in[7];
  const float* b_proj = (const float*)d_in[8];
  const float* w_dw   = (const float*)d_in[9];
  const float* b_dw   = (const float*)d_in[10];
  const float* w_pw   = (const float*)d_in[11];
  const float* b_pw   = (const float*)d_in[12];
  float* out = (float*)d_out;

  const size_t MB = 1024 * 1024;
  char* ws = (char*)d_ws;
  unsigned short* xkv_t = (unsigned short*)(ws);                 // 4 MB (b,n,c) bf16
  unsigned short* xq_t  = (unsigned short*)(ws + 4 * MB);        // 4 MB
  unsigned short* v_nc  = (unsigned short*)(ws + 8 * MB);        // 4 MB (b,n,c) bf16
  unsigned short* qh    = (unsigned short*)(ws + 12 * MB);       // 4 MB (b,h,n,8) bf16
  unsigned short* aoydw = (unsigned short*)(ws + 16 * MB);       // 8 MB (b,n,512) bf16
  unsigned short* kg    = (unsigned short*)(ws + 24 * MB);       // 512 KB (bh,512,8) bf16 pre-scaled
  unsigned short* vt    = (unsigned short*)(ws + 24 * MB + 512 * 1024);  // 1 MB (bh,16,512) bf16
  unsigned short* wv_t  = (unsigned short*)(ws + 26 * MB);               // 128 KB
  unsigned short* wq_t  = (unsigned short*)(ws + 26 * MB + 131072);      // 128 KB
  unsigned short* wcat  = (unsigned short*)(ws + 26 * MB + 262144);      // 256 KB
  unsigned short* wk_t  = (unsigned short*)(ws + 26 * MB + 524288);      // 128 KB
  float*          avgmx = (float*)(ws + 27 * MB);                        //  64 KB
  float*          scores= (float*)(ws + 27 * MB + 65536);               //  32 KB
  int*            idx   = (int*)  (ws + 27 * MB + 98304);               //   4 KB

  k_stage1<<<dim3(64, 4, 10), 256, 0, stream>>>(x_kv, x_q, w_kv, w_q, w_proj, w_pw,
                                                xkv_t, xq_t, avgmx, wv_t, wq_t, wcat, wk_t);
  k_stage2<<<dim3(32, 4, 5), 256, 0, stream>>>(xkv_t, xq_t, wv_t, wq_t, b_kv, b_q,
                                               avgmx, w_spa, v_nc, qh, scores);
  k_stage3<<<dim3(257, 1, 2), 1024, 0, stream>>>(scores, idx, v_nc, w_dw, b_dw, aoydw);
  k_kgvt<<<dim3(160, 1, 2), 256, 0, stream>>>(xkv_t, wk_t, b_kv, idx, v_nc, kg, vt);
  k_fattn<<<dim3(64, 32), 256, 0, stream>>>(qh, kg, vt, aoydw);
  k_final<<<dim3(64, 4, 2), 256, 0, stream>>>(aoydw, wcat, b_proj, b_pw, out);
}

// Round 6
// 177.992 us; speedup vs baseline: 1.4650x; 1.0249x over previous
//
#include <hip/hip_runtime.h>
#include <hip/hip_bf16.h>

typedef short bf16x8 __attribute__((ext_vector_type(8)));
typedef float f32x4 __attribute__((ext_vector_type(4)));

constexpr int CN = 256, NV = 4096, KTOP = 512;

static __device__ __forceinline__ unsigned short f2bf(float f) {
  __hip_bfloat16 h = __float2bfloat16(f);
  return *(unsigned short*)&h;
}
static __device__ __forceinline__ unsigned pack2(float a, float b) {
  return (unsigned)f2bf(a) | ((unsigned)f2bf(b) << 16);
}
static __device__ __forceinline__ float bf2f(unsigned short u) {
  return __uint_as_float(((unsigned)u) << 16);
}
// truncated-bf16 pack: lo16 = bf16(a), hi16 = bf16(b)  (2 VALU, no cvt)
static __device__ __forceinline__ unsigned packtrunc(float a, float b) {
  return (__float_as_uint(a) >> 16) | (__float_as_uint(b) & 0xFFFF0000u);
}

// ---------------------------------------------------------------- L1: transpose-cast + channel-reduce + weight-prep
// z = 0,1: x_kv batches -> xkv_t ; z = 2,3: x_q batches -> xq_t  (float4 loads)
// z = 4: channel mean/max, 4 columns/thread via float4 (per-column order unchanged)
// z = 5..9: weight prep roles 0..4 (only bx<4 && by<4 active)
__global__ void __launch_bounds__(256) k_stage1(const float* __restrict__ xkv,
                                                const float* __restrict__ xq,
                                                const float* __restrict__ wkv,
                                                const float* __restrict__ wq,
                                                const float* __restrict__ wproj,
                                                const float* __restrict__ wpw,
                                                unsigned short* __restrict__ xkv_t,
                                                unsigned short* __restrict__ xq_t,
                                                float* __restrict__ avgmx,
                                                unsigned short* __restrict__ wv_t,
                                                unsigned short* __restrict__ wq_t,
                                                unsigned short* __restrict__ wcat,
                                                unsigned short* __restrict__ wk_t) {
  __shared__ float tile[64 * 68];
  int z = blockIdx.z;
  int t = threadIdx.x;
  if (z == 4) {  // channel mean/max role: 128 n per block, float4 lanes
    __shared__ float4 ssum4[256], smax4[256];
    int blk = blockIdx.y * 64 + blockIdx.x;
    if (blk >= 64) return;
    int b = blk >> 5, n0r = (blk & 31) * 128;
    int cg = t >> 5, nl = t & 31;
    int n = n0r + nl * 4;
    const float* p = xkv + (size_t)b * CN * NV + (size_t)cg * 32 * NV + n;
    float4 s4 = make_float4(0.f, 0.f, 0.f, 0.f);
    float4 m4 = make_float4(-1e30f, -1e30f, -1e30f, -1e30f);
    for (int i = 0; i < 32; ++i) {
      float4 v = *(const float4*)&p[(size_t)i * NV];
      s4.x += v.x; s4.y += v.y; s4.z += v.z; s4.w += v.w;
      m4.x = fmaxf(m4.x, v.x); m4.y = fmaxf(m4.y, v.y);
      m4.z = fmaxf(m4.z, v.z); m4.w = fmaxf(m4.w, v.w);
    }
    ssum4[t] = s4; smax4[t] = m4;
    __syncthreads();
    if (cg == 0) {
      for (int g = 1; g < 8; ++g) {
        float4 o = ssum4[g * 32 + nl], x = smax4[g * 32 + nl];
        s4.x += o.x; s4.y += o.y; s4.z += o.z; s4.w += o.w;
        m4.x = fmaxf(m4.x, x.x); m4.y = fmaxf(m4.y, x.y);
        m4.z = fmaxf(m4.z, x.z); m4.w = fmaxf(m4.w, x.w);
      }
      float4 a4 = make_float4(s4.x * (1.0f / 256.0f), s4.y * (1.0f / 256.0f),
                              s4.z * (1.0f / 256.0f), s4.w * (1.0f / 256.0f));
      *(float4*)&avgmx[(size_t)(b * 2 + 0) * NV + n] = a4;
      *(float4*)&avgmx[(size_t)(b * 2 + 1) * NV + n] = m4;
    }
    return;
  }
  if (z >= 5) {  // weight-prep roles
    if (blockIdx.x >= 4 || blockIdx.y >= 4) return;
    int role = z - 5;
    int j0 = blockIdx.x * 64, c0 = blockIdx.y * 64;
    if (role == 3) {  // wpw (j,c) straight cast into wcat cols 256..512
      int j = t >> 2, part = t & 3;
      const float* s = &wpw[(size_t)(j0 + j) * 256 + c0 + part * 16];
      unsigned w[8];
#pragma unroll
      for (int k = 0; k < 8; ++k) w[k] = pack2(s[2 * k], s[2 * k + 1]);
      uint4* p = (uint4*)&wcat[(size_t)(j0 + j) * 512 + 256 + c0 + part * 16];
      p[0] = make_uint4(w[0], w[1], w[2], w[3]);
      p[1] = make_uint4(w[4], w[5], w[6], w[7]);
      return;
    }
    const float* src; int srcLD, srcOff; unsigned short* dst; int dstLD;
    if (role == 0)      { src = wkv;   srcLD = 512; srcOff = 256; dst = wv_t; dstLD = 256; }
    else if (role == 1) { src = wq;    srcLD = 256; srcOff = 0;   dst = wq_t; dstLD = 256; }
    else if (role == 4) { src = wkv;   srcLD = 512; srcOff = 0;   dst = wk_t; dstLD = 256; }
    else                { src = wproj; srcLD = 256; srcOff = 0;   dst = wcat; dstLD = 512; }
    for (int i = 0; i < 16; ++i) {
      int id = i * 256 + t, c = id >> 6, j = id & 63;
      tile[c * 65 + j] = src[(size_t)(c0 + c) * srcLD + srcOff + j0 + j];
    }
    __syncthreads();
    int j = t & 63, part = t >> 6;
    unsigned w[8];
#pragma unroll
    for (int k = 0; k < 8; ++k)
      w[k] = pack2(tile[(part * 16 + 2 * k) * 65 + j], tile[(part * 16 + 2 * k + 1) * 65 + j]);
    uint4* p = (uint4*)&dst[(size_t)(j0 + j) * dstLD + c0 + part * 16];
    p[0] = make_uint4(w[0], w[1], w[2], w[3]);
    p[1] = make_uint4(w[4], w[5], w[6], w[7]);
    return;
  }
  // transpose-cast roles: float4 loads (16B/lane), LDS stride 68 keeps stores aligned
  int b = z & 1;
  const float* s = (z < 2 ? xkv : xq) + (size_t)b * CN * NV;
  unsigned short* d = (z < 2 ? xkv_t : xq_t) + (size_t)b * NV * 256;
  int c0 = blockIdx.y * 64, n0 = blockIdx.x * 64;
#pragma unroll
  for (int i = 0; i < 4; ++i) {
    int id = i * 256 + t, c = id >> 4, nq = (id & 15) * 4;
    *(float4*)&tile[c * 68 + nq] = *(const float4*)&s[(size_t)(c0 + c) * NV + n0 + nq];
  }
  __syncthreads();
  int n = t & 63, part = t >> 6;
  unsigned w[8];
#pragma unroll
  for (int k = 0; k < 8; ++k)
    w[k] = pack2(tile[(part * 16 + 2 * k) * 68 + n], tile[(part * 16 + 2 * k + 1) * 68 + n]);
  uint4* p = (uint4*)&d[(size_t)(n0 + n) * 256 + c0 + part * 16];
  p[0] = make_uint4(w[0], w[1], w[2], w[3]);
  p[1] = make_uint4(w[4], w[5], w[6], w[7]);
}

// ---------------------------------------------------------------- L2: fused V+Q+K projection (MFMA) + spa conv
// round-17: z = 2*kind + b, kind 0=V 1=Q 2=K; z=6: spa. K-projection computed
// for ALL n (k_nc, (b,n,c) bf16) so the kgvt launch can be deleted; the
// kscale*log2e factor folds onto Q (scores unchanged up to bf16 rounding).
__global__ void __launch_bounds__(256) k_stage2(const unsigned short* __restrict__ xkv_t,
                                                const unsigned short* __restrict__ xq_t,
                                                const unsigned short* __restrict__ wv_t,
                                                const unsigned short* __restrict__ wq_t,
                                                const unsigned short* __restrict__ wk_t,
                                                const float* __restrict__ bkv,
                                                const float* __restrict__ bq,
                                                const float* __restrict__ avgmx,
                                                const float* __restrict__ wspa,
                                                unsigned short* __restrict__ v_nc,
                                                unsigned short* __restrict__ qh,
                                                unsigned short* __restrict__ k_nc,
                                                float* __restrict__ scores) {
  __shared__ alignas(16) char smem[35520];   // max(qv 15360, spa 32768+2744)
  int z = blockIdx.z;
  int t = threadIdx.x;
  if (z == 6) {  // ---- spa role
    int id = blockIdx.y * 32 + blockIdx.x;
    if (id >= 64) return;
    float* vol = (float*)smem;
    float* ws = (float*)(smem + 32768);
    int b = id >> 5, chunk = id & 31;
    for (int i = t; i < 8192; i += 256) vol[i] = avgmx[b * 8192 + i];
    for (int i = t; i < 686; i += 256) ws[i] = wspa[i];
    __syncthreads();
    int ci = t & 1;
    int n = chunk * 128 + (t >> 1);
    int d = n >> 8, h = (n >> 4) & 15, w = n & 15;
    const float* vb = vol + ci * 4096;
    const float* wb = ws + ci * 343;
    float acc = 0.f;
    for (int kd = 0; kd < 7; ++kd) {
      int zd = d - 3 + kd; if ((unsigned)zd >= 16u) continue;
      for (int kh = 0; kh < 7; ++kh) {
        int zh = h - 3 + kh; if ((unsigned)zh >= 16u) continue;
        const float* row = vb + zd * 256 + zh * 16;
        const float* wr = wb + kd * 49 + kh * 7;
#pragma unroll
        for (int kw = 0; kw < 7; ++kw) {
          int zw = w - 3 + kw;
          if ((unsigned)zw < 16u) acc += row[zw] * wr[kw];
        }
      }
    }
    acc += __shfl_xor(acc, 1);
    if (ci == 0) scores[b * NV + n] = 1.0f / (1.0f + expf(-acc));
    return;
  }
  // ---- projection role: 128n x 64j per block
  const float kscale = 0.35355339059327373f * 1.4426950408889634f;  // 1/sqrt(8)*log2(e)
  unsigned short* Als = (unsigned short*)smem;     // 64 x 40
  unsigned short* Bls = Als + 64 * 40;             // 128 x 40
  int b = z & 1, kind = z >> 1;                    // 0=V, 1=Q, 2=K
  const unsigned short* A = kind == 0 ? wv_t : (kind == 1 ? wq_t : wk_t);
  const unsigned short* B = (kind == 1 ? xq_t : xkv_t) + (size_t)b * NV * 256;
  const float* bias = kind == 0 ? (bkv + 256) : (kind == 1 ? bq : bkv);
  float scl = (kind == 1) ? kscale : 1.0f;         // *1.0f is exact for V/K
  int n0 = blockIdx.x * 128, j0 = blockIdx.y * 64;
  int wave = t >> 6, lane = t & 63;
  int l15 = lane & 15, q = lane >> 4, q8 = q * 8;
  int wj = (wave >> 1) * 32, wn = (wave & 1) * 64;
  f32x4 acc[2][4] = {};
  int arA = t >> 2, ahA = t & 3;
  int brB = t >> 1, bhB = t & 1;
  for (int c0 = 0; c0 < 256; c0 += 32) {
    __syncthreads();
    *(uint4*)&Als[arA * 40 + ahA * 8] =
        *(const uint4*)&A[(size_t)(j0 + arA) * 256 + c0 + ahA * 8];
    const unsigned short* sb = &B[(size_t)(n0 + brB) * 256 + c0 + bhB * 16];
    *(uint4*)&Bls[brB * 40 + bhB * 16]     = *(const uint4*)&sb[0];
    *(uint4*)&Bls[brB * 40 + bhB * 16 + 8] = *(const uint4*)&sb[8];
    __syncthreads();
    bf16x8 af[2], bf[4];
#pragma unroll
    for (int mt = 0; mt < 2; ++mt)
      af[mt] = *(const bf16x8*)&Als[(wj + mt * 16 + l15) * 40 + q8];
#pragma unroll
    for (int nt = 0; nt < 4; ++nt)
      bf[nt] = *(const bf16x8*)&Bls[(wn + nt * 16 + l15) * 40 + q8];
#pragma unroll
    for (int mt = 0; mt < 2; ++mt)
#pragma unroll
      for (int nt = 0; nt < 4; ++nt)
        acc[mt][nt] = __builtin_amdgcn_mfma_f32_16x16x32_bf16(af[mt], bf[nt], acc[mt][nt], 0, 0, 0);
  }
#pragma unroll
  for (int mt = 0; mt < 2; ++mt) {
    int jb = j0 + wj + mt * 16 + q * 4;          // 4 consecutive j
    float4 b4 = *(const float4*)&bias[jb];
#pragma unroll
    for (int nt = 0; nt < 4; ++nt) {
      int n = n0 + wn + nt * 16 + l15;
      float v0 = (acc[mt][nt][0] + b4.x) * scl;
      float v1 = (acc[mt][nt][1] + b4.y) * scl;
      float v2 = (acc[mt][nt][2] + b4.z) * scl;
      float v3 = (acc[mt][nt][3] + b4.w) * scl;
      uint2 pk = make_uint2(pack2(v0, v1), pack2(v2, v3));
      if (kind == 1) {
        int h = jb >> 3, d0 = jb & 7;            // jb%4==0 -> within one head
        *(uint2*)&qh[((size_t)(b * 32 + h) * NV + n) * 8 + d0] = pk;
      } else if (kind == 0) {
        *(uint2*)&v_nc[((size_t)b * NV + n) * 256 + jb] = pk;
      } else {
        *(uint2*)&k_nc[((size_t)b * NV + n) * 256 + jb] = pk;
      }
    }
  }
}

// ---------------------------------------------------------------- L3: depthwise conv + top-512 radix select
// bx < 256: dw role (16 n x 256 c per block, 1024 thr) ; bx == 256: topk for batch z
__global__ void __launch_bounds__(1024) k_stage3(const float* __restrict__ scores,
                                                 int* __restrict__ idx,
                                                 const unsigned short* __restrict__ v_nc,
                                                 const float* __restrict__ wdw,
                                                 const float* __restrict__ bdw,
                                                 unsigned short* __restrict__ aoydw) {
  int b = blockIdx.z;
  int bx = blockIdx.x;
  int tid = threadIdx.x;
  if (bx == 256) {  // ---- topk role (unchanged radix-select, 1024 thr)
    __shared__ unsigned sv[4096];
    __shared__ int sB;
    __shared__ unsigned sSub, scnt;
    __shared__ unsigned hist[256];
    __shared__ int wsum[16];
    for (int t = tid; t < 4096; t += 1024) sv[t] = __float_as_uint(scores[b * NV + t]);
    if (tid == 0) scnt = 0;
    unsigned prefix = 0;
    int r = 512;
    for (int shift = 24; shift >= 0; shift -= 8) {
      if (tid < 256) hist[tid] = 0;
      __syncthreads();
      unsigned maskhi = (shift == 24) ? 0u : (0xFFFFFFFFu << (shift + 8));
      for (int i = 0; i < 4; ++i) {
        unsigned v = sv[tid + i * 1024];
        if ((v & maskhi) == prefix) atomicAdd(&hist[(v >> shift) & 255], 1u);
      }
      __syncthreads();
      if (tid < 64) {
        int lane = tid;
        unsigned h0 = hist[lane * 4 + 0], h1 = hist[lane * 4 + 1];
        unsigned h2 = hist[lane * 4 + 2], h3 = hist[lane * 4 + 3];
        unsigned s = h0 + h1 + h2 + h3;
        for (int off = 1; off < 64; off <<= 1) {
          unsigned y = __shfl_down(s, off);
          if (lane + off < 64) s += y;
        }
        unsigned tail = __shfl_down(s, 1);
        if (lane == 63) tail = 0;
        unsigned s3 = tail + h3, s2 = s3 + h2, s1 = s2 + h1, s0 = s1 + h0;
        unsigned sx[5] = {s0, s1, s2, s3, tail};
#pragma unroll
        for (int i = 0; i < 4; ++i)
          if (sx[i] >= (unsigned)r && sx[i + 1] < (unsigned)r) { sB = lane * 4 + i; sSub = sx[i + 1]; }
      }
      __syncthreads();
      prefix |= ((unsigned)sB) << shift;
      r -= (int)sSub;
      __syncthreads();
    }
    unsigned vstar = prefix;
    for (int i = 0; i < 4; ++i) {
      int t = tid * 4 + i;
      if (sv[t] > vstar) { unsigned p = atomicAdd(&scnt, 1u); idx[b * KTOP + p] = t; }
    }
    __syncthreads();
    int base = (int)scnt;
    int loc = 0;
    for (int i = 0; i < 4; ++i) loc += (sv[tid * 4 + i] == vstar);
    int lane = tid & 63, w = tid >> 6;
    int x = loc;
    for (int off = 1; off < 64; off <<= 1) {
      int y = __shfl_up(x, off);
      if (lane >= off) x += y;
    }
    if (lane == 63) wsum[w] = x;
    __syncthreads();
    int wbase = 0;
    for (int i = 0; i < w; ++i) wbase += wsum[i];
    int excl = wbase + x - loc;
    for (int i = 0; i < 4; ++i) {
      int t = tid * 4 + i;
      if (sv[t] == vstar) {
        if (excl < r) idx[b * KTOP + base + excl] = t;
        ++excl;
      }
    }
    return;
  }
  // ---- dw role: 16 consecutive n x 256 c per block
  int c = tid & 255;
  float wr[27];
#pragma unroll
  for (int i = 0; i < 27; ++i) wr[i] = wdw[c * 27 + i];
  float bias = bdw[c];
  const unsigned short* src = v_nc + (size_t)b * NV * 256 + c;
  unsigned short* dst = aoydw + (size_t)b * NV * 512 + 256 + c;
  int n = bx * 16 + (tid >> 8) * 4;          // 4 consecutive n (same h-row) share taps
  int d = n >> 8, h = (n >> 4) & 15, w = n & 15;
  float a0 = bias, a1 = bias, a2 = bias, a3 = bias;
#pragma unroll
  for (int kd = 0; kd < 3; ++kd) {
    int zd = d - 1 + kd; bool okd = (unsigned)zd < 16u;
#pragma unroll
    for (int kh = 0; kh < 3; ++kh) {
      int zh = h - 1 + kh; bool okh = okd && ((unsigned)zh < 16u);
      int rowb = zd * 256 + zh * 16;
      float v[6];
#pragma unroll
      for (int i = 0; i < 6; ++i) {
        int zw = w - 1 + i;
        bool ok = okh && ((unsigned)zw < 16u);   // wave-uniform mask
        v[i] = ok ? bf2f(src[(size_t)(rowb + zw) * 256]) : 0.f;
      }
      const float* wp = &wr[kd * 9 + kh * 3];
      a0 = fmaf(v[0], wp[0], fmaf(v[1], wp[1], fmaf(v[2], wp[2], a0)));
      a1 = fmaf(v[1], wp[0], fmaf(v[2], wp[1], fmaf(v[3], wp[2], a1)));
      a2 = fmaf(v[2], wp[0], fmaf(v[3], wp[1], fmaf(v[4], wp[2], a2)));
      a3 = fmaf(v[3], wp[0], fmaf(v[4], wp[1], fmaf(v[5], wp[2], a3)));
    }
  }
  dst[(size_t)(n + 0) * 512] = f2bf(a0);
  dst[(size_t)(n + 1) * 512] = f2bf(a1);
  dst[(size_t)(n + 2) * 512] = f2bf(a2);
  dst[(size_t)(n + 3) * 512] = f2bf(a3);
}

// ---------------------------------------------------------------- L4: MFMA flash attention, swapped-QK, self-built V^T in LDS
// round-17: phase A gathers idx + V^T (kappa-permuted, [16][520] pad: 16B
// alignment + balanced banks) into LDS; K rows gathered per-iteration from
// k_nc via idx (contiguous 16B rows, L2-hot). kg/vt buffers and the kgvt
// launch no longer exist.
__global__ void __launch_bounds__(256) k_fattn(const unsigned short* __restrict__ qh,
                                               const unsigned short* __restrict__ k_nc,
                                               const unsigned short* __restrict__ v_nc,
                                               const int* __restrict__ idx,
                                               unsigned short* __restrict__ aoydw) {
  __shared__ int idx_l[512];
  __shared__ unsigned short vt_l[16 * 520];
  int bh = blockIdx.x;
  int b = bh >> 5, h = bh & 31;
  int t = threadIdx.x, wave = t >> 6, lane = t & 63;
  int l15 = lane & 15, quad = lane >> 4;
  // ---- phase A: idx + V^T build
  const int* ib = idx + b * KTOP;
  for (int i = t; i < 512; i += 256) idx_l[i] = ib[i];
  for (int i = t; i < 512; i += 256) vt_l[8 * 520 + i] = 0x3F80;   // ones row
  for (int i = t; i < 7 * 520; i += 256) vt_l[9 * 520 + i] = 0;    // zero rows
  for (int kk = t; kk < 512; kk += 256) {
    uint4 v = *(const uint4*)&v_nc[((size_t)b * NV + ib[kk]) * 256 + h * 8];
    unsigned short tmp[8];
    *(uint4*)tmp = v;
    int kc = kk >> 5, ka = kk & 31;
    int s = (ka < 16) ? ((ka >> 2) * 8 + (ka & 3))
                      : (((ka - 16) >> 2) * 8 + (ka & 3) + 4);
    int col = kc * 32 + s;
#pragma unroll
    for (int d = 0; d < 8; ++d) vt_l[d * 520 + col] = tmp[d];
  }
  int n0 = blockIdx.y * 128 + wave * 32;       // 32 queries per wave
  bf16x8 q0 = {}, q1 = {};                     // B-operand: n=query, k=dim (quad 0 only)
  if (quad == 0) {
    q0 = *(const bf16x8*)&qh[((size_t)bh * NV + n0 + l15) * 8];
    q1 = *(const bf16x8*)&qh[((size_t)bh * NV + n0 + 16 + l15) * 8];
  }
  __syncthreads();
  // ---- phase B: attention
  const unsigned short* kbase = k_nc + (size_t)b * NV * 256 + h * 8;
  f32x4 acc0 = {0.f, 0.f, 0.f, 0.f}, acc1 = {0.f, 0.f, 0.f, 0.f};
  bf16x8 kA0 = {}, kA1 = {};                   // A-operand: m=key, k=dim (quad 0 only)
  if (quad == 0) {
    kA0 = *(const bf16x8*)&kbase[(size_t)idx_l[l15] * 256];
    kA1 = *(const bf16x8*)&kbase[(size_t)idx_l[16 + l15] * 256];
  }
  for (int kc = 0; kc < 16; ++kc) {            // 32 keys per iteration
    bf16x8 nA0 = {}, nA1 = {};                 // prefetch next K chunk
    if (quad == 0 && kc < 15) {
      nA0 = *(const bf16x8*)&kbase[(size_t)idx_l[kc * 32 + 32 + l15] * 256];
      nA1 = *(const bf16x8*)&kbase[(size_t)idx_l[kc * 32 + 48 + l15] * 256];
    }
    bf16x8 bV = *(const bf16x8*)&vt_l[l15 * 520 + kc * 32 + quad * 8];
    f32x4 z = {0.f, 0.f, 0.f, 0.f};
    // D: col=query=l15, row=key=quad*4+r  -> P already in PV A-frag layout
    f32x4 s00 = __builtin_amdgcn_mfma_f32_16x16x32_bf16(kA0, q0, z, 0, 0, 0);
    f32x4 s01 = __builtin_amdgcn_mfma_f32_16x16x32_bf16(kA1, q0, z, 0, 0, 0);
    f32x4 s10 = __builtin_amdgcn_mfma_f32_16x16x32_bf16(kA0, q1, z, 0, 0, 0);
    f32x4 s11 = __builtin_amdgcn_mfma_f32_16x16x32_bf16(kA1, q1, z, 0, 0, 0);
    uint4 P0, P1;
    P0.x = packtrunc(__builtin_amdgcn_exp2f(s00[0]), __builtin_amdgcn_exp2f(s00[1]));
    P0.y = packtrunc(__builtin_amdgcn_exp2f(s00[2]), __builtin_amdgcn_exp2f(s00[3]));
    P0.z = packtrunc(__builtin_amdgcn_exp2f(s01[0]), __builtin_amdgcn_exp2f(s01[1]));
    P0.w = packtrunc(__builtin_amdgcn_exp2f(s01[2]), __builtin_amdgcn_exp2f(s01[3]));
    P1.x = packtrunc(__builtin_amdgcn_exp2f(s10[0]), __builtin_amdgcn_exp2f(s10[1]));
    P1.y = packtrunc(__builtin_amdgcn_exp2f(s10[2]), __builtin_amdgcn_exp2f(s10[3]));
    P1.z = packtrunc(__builtin_amdgcn_exp2f(s11[0]), __builtin_amdgcn_exp2f(s11[1]));
    P1.w = packtrunc(__builtin_amdgcn_exp2f(s11[2]), __builtin_amdgcn_exp2f(s11[3]));
    acc0 = __builtin_amdgcn_mfma_f32_16x16x32_bf16(*(bf16x8*)&P0, bV, acc0, 0, 0, 0);
    acc1 = __builtin_amdgcn_mfma_f32_16x16x32_bf16(*(bf16x8*)&P1, bV, acc1, 0, 0, 0);
    kA0 = nA0; kA1 = nA1;
  }
#pragma unroll
  for (int tq = 0; tq < 2; ++tq) {
    f32x4 a = tq ? acc1 : acc0;
#pragma unroll
    for (int r = 0; r < 4; ++r) {
      float se = __shfl(a[r], quad * 16 + 8);  // denominator from ones-row col (l15=8)
      float o = a[r] * (1.0f / se);
      if (l15 < 8) {
        int n = n0 + tq * 16 + quad * 4 + r;
        aoydw[((size_t)b * NV + n) * 512 + h * 8 + l15] = f2bf(o);
      }
    }
  }
}

// ---------------------------------------------------------------- L5: final GEMM K=512, MFMA bf16
__global__ void __launch_bounds__(256) k_final(const unsigned short* __restrict__ aoydw,
                                               const unsigned short* __restrict__ wcat,
                                               const float* __restrict__ bproj,
                                               const float* __restrict__ bpw,
                                               float* __restrict__ out) {
  __shared__ unsigned short Als[64 * 72];
  __shared__ unsigned short Bls[64 * 72];
  int n0 = blockIdx.x * 64, j0 = blockIdx.y * 64, b = blockIdx.z;
  int t = threadIdx.x;
  int wave = t >> 6, lane = t & 63;
  int l15 = lane & 15, q = lane >> 4, q8 = q * 8;
  int wn = (wave & 1) * 32, wjj = (wave >> 1) * 32;
  f32x4 acc[2][2] = {};
  const unsigned short* Abase = aoydw + (size_t)b * NV * 512;
  int ar = t >> 2, aq = t & 3;
  for (int c0 = 0; c0 < 512; c0 += 64) {
    __syncthreads();
    *(uint4*)&Als[ar * 72 + aq * 8] =
        *(const uint4*)&Abase[(size_t)(n0 + ar) * 512 + c0 + aq * 8];
    *(uint4*)&Als[ar * 72 + 32 + aq * 8] =
        *(const uint4*)&Abase[(size_t)(n0 + ar) * 512 + c0 + 32 + aq * 8];
    *(uint4*)&Bls[ar * 72 + aq * 8] =
        *(const uint4*)&wcat[(size_t)(j0 + ar) * 512 + c0 + aq * 8];
    *(uint4*)&Bls[ar * 72 + 32 + aq * 8] =
        *(const uint4*)&wcat[(size_t)(j0 + ar) * 512 + c0 + 32 + aq * 8];
    __syncthreads();
#pragma unroll
    for (int kk = 0; kk < 2; ++kk) {
      bf16x8 af[2], bf[2];
#pragma unroll
      for (int mt = 0; mt < 2; ++mt)
        af[mt] = *(const bf16x8*)&Als[(wn + mt * 16 + l15) * 72 + kk * 32 + q8];
#pragma unroll
      for (int nt = 0; nt < 2; ++nt)
        bf[nt] = *(const bf16x8*)&Bls[(wjj + nt * 16 + l15) * 72 + kk * 32 + q8];
#pragma unroll
      for (int mt = 0; mt < 2; ++mt)
#pragma unroll
        for (int nt = 0; nt < 2; ++nt)
          acc[mt][nt] = __builtin_amdgcn_mfma_f32_16x16x32_bf16(af[mt], bf[nt], acc[mt][nt], 0, 0, 0);
    }
  }
#pragma unroll
  for (int nt = 0; nt < 2; ++nt) {
    int j = j0 + wjj + nt * 16 + l15;
    float bl = bproj[j] + bpw[j];
#pragma unroll
    for (int mt = 0; mt < 2; ++mt) {
      int n = n0 + wn + mt * 16 + q * 4;
      float4 r = make_float4(acc[mt][nt][0] + bl, acc[mt][nt][1] + bl,
                             acc[mt][nt][2] + bl, acc[mt][nt][3] + bl);
      *(float4*)&out[(size_t)(b * 256 + j) * NV + n] = r;
    }
  }
}

// ---------------------------------------------------------------- launch
extern "C" void kernel_launch(void* const* d_in, const int* in_sizes, int n_in,
                              void* d_out, int out_size, void* d_ws, size_t ws_size,
                              hipStream_t stream) {
  const float* x_kv   = (const float*)d_in[0];
  const float* x_q    = (const float*)d_in[1];
  const float* w_spa  = (const float*)d_in[2];
  const float* w_kv   = (const float*)d_in[3];
  const float* b_kv   = (const float*)d_in[4];
  const float* w_q    = (const float*)d_in[5];
  const float* b_q    = (const float*)d_in[6];
  const float* w_proj = (const float*)d_in[7];
  const float* b_proj = (const float*)d_in[8];
  const float* w_dw   = (const float*)d_in[9];
  const float* b_dw   = (const float*)d_in[10];
  const float* w_pw   = (const float*)d_in[11];
  const float* b_pw   = (const float*)d_in[12];
  float* out = (float*)d_out;

  const size_t MB = 1024 * 1024;
  char* ws = (char*)d_ws;
  unsigned short* xkv_t = (unsigned short*)(ws);                 // 4 MB (b,n,c) bf16
  unsigned short* xq_t  = (unsigned short*)(ws + 4 * MB);        // 4 MB
  unsigned short* v_nc  = (unsigned short*)(ws + 8 * MB);        // 4 MB (b,n,c) bf16
  unsigned short* qh    = (unsigned short*)(ws + 12 * MB);       // 4 MB (b,h,n,8) bf16, pre-scaled
  unsigned short* aoydw = (unsigned short*)(ws + 16 * MB);       // 8 MB (b,n,512) bf16
  unsigned short* k_nc  = (unsigned short*)(ws + 24 * MB);       // 4 MB (b,n,c) bf16
  unsigned short* wv_t  = (unsigned short*)(ws + 28 * MB);               // 128 KB
  unsigned short* wq_t  = (unsigned short*)(ws + 28 * MB + 131072);      // 128 KB
  unsigned short* wcat  = (unsigned short*)(ws + 28 * MB + 262144);      // 256 KB
  unsigned short* wk_t  = (unsigned short*)(ws + 28 * MB + 524288);      // 128 KB
  float*          avgmx = (float*)(ws + 29 * MB);                        //  64 KB
  float*          scores= (float*)(ws + 29 * MB + 65536);               //  32 KB
  int*            idx   = (int*)  (ws + 29 * MB + 98304);               //   4 KB

  k_stage1<<<dim3(64, 4, 10), 256, 0, stream>>>(x_kv, x_q, w_kv, w_q, w_proj, w_pw,
                                                xkv_t, xq_t, avgmx, wv_t, wq_t, wcat, wk_t);
  k_stage2<<<dim3(32, 4, 7), 256, 0, stream>>>(xkv_t, xq_t, wv_t, wq_t, wk_t, b_kv, b_q,
                                               avgmx, w_spa, v_nc, qh, k_nc, scores);
  k_stage3<<<dim3(257, 1, 2), 1024, 0, stream>>>(scores, idx, v_nc, w_dw, b_dw, aoydw);
  k_fattn<<<dim3(64, 32), 256, 0, stream>>>(qh, k_nc, v_nc, idx, aoydw);
  k_final<<<dim3(64, 4, 2), 256, 0, stream>>>(aoydw, wcat, b_proj, b_pw, out);
}